// Round 7
// baseline (590.311 us; speedup 1.0000x reference)
//
#include <hip/hip_runtime.h>
#include <math.h>

#define BN 8
#define NP 2048
#define KNN 16
#define NL 4
#define NH 8

typedef __attribute__((ext_vector_type(8))) short bf16x8;
typedef __attribute__((ext_vector_type(4))) float f32x4;

__device__ __forceinline__ unsigned short f2bf(float f) {
    unsigned u = __float_as_uint(f);
    unsigned r = (u + 0x7FFFu + ((u >> 16) & 1u)) >> 16;
    return (unsigned short)r;
}
__device__ __forceinline__ float bf2f(unsigned short s) {
    return __uint_as_float(((unsigned)s) << 16);
}
__device__ __forceinline__ unsigned fmono(float f) {
    unsigned u = __float_as_uint(f);
    return (u & 0x80000000u) ? ~u : (u | 0x80000000u);
}
__device__ __forceinline__ float funmono(unsigned k) {
    return (k & 0x80000000u) ? __uint_as_float(k ^ 0x80000000u) : __uint_as_float(~k);
}

// dot of one bf16 weight row (K8*8 elements) against fp32 vector in LDS.
// 4 independent accumulator chains so the compiler keeps >=4 loads in flight.
__device__ __forceinline__ float gemv_dot(const unsigned short* __restrict__ wrow, const float* sm, int K8) {
    const uint4* w8 = (const uint4*)wrow;
    const float4* r4 = (const float4*)sm;
    float a0 = 0.f, a1 = 0.f, a2 = 0.f, a3 = 0.f;
    #pragma unroll 8
    for (int c = 0; c < K8; ++c) {
        uint4 wv = w8[c];
        float4 x0 = r4[c * 2], x1 = r4[c * 2 + 1];
        a0 += x0.x * __uint_as_float(wv.x << 16) + x0.y * __uint_as_float(wv.x & 0xFFFF0000u);
        a1 += x0.z * __uint_as_float(wv.y << 16) + x0.w * __uint_as_float(wv.y & 0xFFFF0000u);
        a2 += x1.x * __uint_as_float(wv.z << 16) + x1.y * __uint_as_float(wv.z & 0xFFFF0000u);
        a3 += x1.z * __uint_as_float(wv.w << 16) + x1.w * __uint_as_float(wv.w & 0xFFFF0000u);
    }
    return (a0 + a1) + (a2 + a3);
}

// ---------------------------------------------------------------- knn v7: pivot-filter select (verified R2)
__device__ __forceinline__ unsigned long long shflx_u64(unsigned long long v, int j) {
    int lo = __shfl_xor((int)(unsigned)(v & 0xFFFFFFFFull), j);
    int hi = __shfl_xor((int)(unsigned)(v >> 32), j);
    return ((unsigned long long)(unsigned)hi << 32) | (unsigned)lo;
}

__device__ __forceinline__ unsigned sort64_u32(unsigned v, int lane) {
    #pragma unroll
    for (int k = 2; k <= 64; k <<= 1) {
        #pragma unroll
        for (int j = k >> 1; j > 0; j >>= 1) {
            unsigned o = (unsigned)__shfl_xor((int)v, j);
            bool up = ((lane & k) == 0);
            bool lower = ((lane & j) == 0);
            unsigned mn = v < o ? v : o;
            unsigned mx = v < o ? o : v;
            v = (up == lower) ? mn : mx;
        }
    }
    return v;
}

__device__ __forceinline__ unsigned long long sort64_u64(unsigned long long v, int lane) {
    #pragma unroll
    for (int k = 2; k <= 64; k <<= 1) {
        #pragma unroll
        for (int j = k >> 1; j > 0; j >>= 1) {
            unsigned long long o = shflx_u64(v, j);
            bool up = ((lane & k) == 0);
            bool lower = ((lane & j) == 0);
            unsigned long long mn = v < o ? v : o;
            unsigned long long mx = v < o ? o : v;
            v = (up == lower) ? mn : mx;
        }
    }
    return v;
}

__global__ __launch_bounds__(256) void knn_kernel(const float* __restrict__ x, int* __restrict__ idxout) {
    __shared__ unsigned long long cand[4][64];
    int tid = threadIdx.x;
    int wv = tid >> 6, lane = tid & 63;
    int p = blockIdx.x * 4 + wv;
    int b = p >> 11, n = p & 2047;
    const float* xb = x + (size_t)b * NP * 3;
    float cx = xb[n * 3 + 0], cy = xb[n * 3 + 1], cz = xb[n * 3 + 2];
    float xn = cx * cx + cy * cy + cz * cz;
    unsigned key[32];
    unsigned lmax = 0u;
    #pragma unroll
    for (int t = 0; t < 32; ++t) {
        int m = (t << 6) | lane;
        float mx = xb[m * 3 + 0], my = xb[m * 3 + 1], mz = xb[m * 3 + 2];
        float xxm = mx * mx + my * my + mz * mz;
        float inner = cx * mx + cy * my + cz * mz;
        float dd = 2.0f * inner - xn - xxm;
        unsigned u = __float_as_uint(dd);
        u = (u & 0x80000000u) ? ~u : (u | 0x80000000u);
        key[t] = u;
        lmax = lmax > u ? lmax : u;
    }
    unsigned sorted = sort64_u32(lmax, lane);
    unsigned S = (unsigned)__shfl((int)sorted, 48);
    int c = 0;
    #pragma unroll
    for (int t = 0; t < 32; ++t) c += (key[t] >= S) ? 1 : 0;
    int inc = c;
    #pragma unroll
    for (int d = 1; d < 64; d <<= 1) {
        int tsh = __shfl_up(inc, d);
        if (lane >= d) inc += tsh;
    }
    int C = __shfl(inc, 63);
    int* op = idxout + (size_t)p * KNN;
    if (C <= 64) {
        int off = inc - c;
        #pragma unroll
        for (int t = 0; t < 32; ++t) {
            if (key[t] >= S) {
                int m = (t << 6) | lane;
                cand[wv][off++] = ((unsigned long long)key[t] << 16) | (unsigned)(2047 - m);
            }
        }
        asm volatile("s_waitcnt lgkmcnt(0)" ::: "memory");
        unsigned long long ck = (lane < C) ? cand[wv][lane] : 0ull;
        ck = sort64_u64(ck, lane);
        if (lane >= 48) op[63 - lane] = 2047 - (int)(unsigned)(ck & 0xFFFFull);
    } else {
        unsigned taken = 0u;
        for (int r = 0; r < KNN; ++r) {
            unsigned long long best = 0ull;
            #pragma unroll
            for (int t = 0; t < 32; ++t) {
                if (!((taken >> t) & 1u)) {
                    int m = (t << 6) | lane;
                    unsigned long long ck = ((unsigned long long)key[t] << 16) | (unsigned)(2047 - m);
                    if (ck > best) best = ck;
                }
            }
            #pragma unroll
            for (int d = 1; d < 64; d <<= 1) {
                unsigned long long o = shflx_u64(best, d);
                if (o > best) best = o;
            }
            int m = 2047 - (int)(unsigned)(best & 0xFFFFull);
            if (lane == 0) op[r] = m;
            if ((m & 63) == lane) taken |= 1u << (m >> 6);
        }
    }
}

// ---------------------------------------------------------------- edge conv + max over k -> hcatT[:,0:64] bf16
__global__ __launch_bounds__(256) void edge_conv_kernel(const float* __restrict__ x, const int* __restrict__ idx,
                                                        const float* __restrict__ Wec, const float* __restrict__ bec,
                                                        unsigned short* __restrict__ hcatT) {
    int tid = threadIdx.x;
    int g = tid >> 6, o = tid & 63;
    int p = blockIdx.x * 4 + g;
    int b = p >> 11;
    __shared__ float nb[4][KNN][3];
    __shared__ float ctr[4][3];
    if (o < KNN) {
        int j = idx[(size_t)p * KNN + o];
        const float* xp = x + ((size_t)b * NP + j) * 3;
        nb[g][o][0] = xp[0]; nb[g][o][1] = xp[1]; nb[g][o][2] = xp[2];
    }
    if (o >= KNN && o < KNN + 3) ctr[g][o - KNN] = x[(size_t)p * 3 + (o - KNN)];
    __syncthreads();
    float w0 = Wec[o * 6 + 0], w1 = Wec[o * 6 + 1], w2 = Wec[o * 6 + 2];
    float w3 = Wec[o * 6 + 3], w4 = Wec[o * 6 + 4], w5 = Wec[o * 6 + 5];
    float c0 = ctr[g][0], c1 = ctr[g][1], c2 = ctr[g][2];
    float base = bec[o] + w3 * c0 + w4 * c1 + w5 * c2;
    float m = -3.4e38f;
    #pragma unroll
    for (int k = 0; k < KNN; ++k) {
        float v = base + w0 * (nb[g][k][0] - c0) + w1 * (nb[g][k][1] - c1) + w2 * (nb[g][k][2] - c2);
        v = v > 0.f ? v : 0.2f * v;
        m = fmaxf(m, v);
    }
    hcatT[(size_t)p * 512 + o] = f2bf(m);
}

// ---------------------------------------------------------------- graph max pool, bf16 [pt][ch] -> bf16 [pt][C]
__global__ __launch_bounds__(256) void pool_bf16_kernel(const unsigned short* __restrict__ src, int s_coff,
                                                        const int* __restrict__ idx,
                                                        unsigned short* __restrict__ dst, int C) {
    int tid = threadIdx.x, wv = tid >> 6, lane = tid & 63;
    int p = blockIdx.x * 4 + wv;
    int b = p >> 11;
    const int* ip = idx + (size_t)p * KNN;
    const unsigned short* sb = src + (size_t)b * NP * 512 + s_coff;
    for (int c0 = 0; c0 < C; c0 += 64) {
        int ch = c0 + lane;
        float m = -3.4e38f;
        #pragma unroll
        for (int k = 0; k < KNN; ++k) {
            int j = ip[k];
            m = fmaxf(m, bf2f(sb[(size_t)j * 512 + ch]));
        }
        dst[(size_t)p * C + ch] = f2bf(m);
    }
}

// ---------------------------------------------------------------- conv1 MFMA: 128pts x 64ch, K=64
__global__ __launch_bounds__(256) void mfma_conv64_kernel(const unsigned short* __restrict__ A,
                                                          const unsigned short* __restrict__ W,
                                                          const float* __restrict__ bias,
                                                          unsigned short* __restrict__ hcatT, int coff) {
    __shared__ unsigned short As[128][72];
    __shared__ unsigned short Bs[64][72];
    int m0 = blockIdx.x * 128, b = blockIdx.z;
    int tid = threadIdx.x;
    int lane = tid & 63, wave = tid >> 6;
    int wr = wave >> 1, wc = wave & 1;
    int quad = lane >> 4, l16 = lane & 15;
    {
        int r = tid >> 1, s = (tid & 1) * 32;
        const unsigned short* ap = A + (size_t)b * NP * 64 + (size_t)(m0 + r) * 64 + s;
        uint4 v0 = *(const uint4*)(ap);
        uint4 v1 = *(const uint4*)(ap + 8);
        uint4 v2 = *(const uint4*)(ap + 16);
        uint4 v3 = *(const uint4*)(ap + 24);
        *(uint4*)&As[r][s] = v0; *(uint4*)&As[r][s + 8] = v1;
        *(uint4*)&As[r][s + 16] = v2; *(uint4*)&As[r][s + 24] = v3;
    }
    {
        int r = tid >> 2, s = (tid & 3) * 16;
        const unsigned short* wp = W + r * 64 + s;
        *(uint4*)&Bs[r][s] = *(const uint4*)wp;
        *(uint4*)&Bs[r][s + 8] = *(const uint4*)(wp + 8);
    }
    __syncthreads();
    f32x4 acc[4][2] = {};
    #pragma unroll
    for (int k0 = 0; k0 < 64; k0 += 32) {
        bf16x8 af[4], bfv[2];
        #pragma unroll
        for (int i = 0; i < 4; ++i) af[i] = *(const bf16x8*)&As[wr * 64 + i * 16 + l16][k0 + quad * 8];
        #pragma unroll
        for (int j = 0; j < 2; ++j) bfv[j] = *(const bf16x8*)&Bs[wc * 32 + j * 16 + l16][k0 + quad * 8];
        #pragma unroll
        for (int i = 0; i < 4; ++i)
            #pragma unroll
            for (int j = 0; j < 2; ++j)
                acc[i][j] = __builtin_amdgcn_mfma_f32_16x16x32_bf16(af[i], bfv[j], acc[i][j], 0, 0, 0);
    }
    #pragma unroll
    for (int i = 0; i < 4; ++i) {
        #pragma unroll
        for (int r = 0; r < 4; ++r) {
            int pt = m0 + wr * 64 + i * 16 + quad * 4 + r;
            #pragma unroll
            for (int j = 0; j < 2; ++j) {
                int ch = wc * 32 + j * 16 + l16;
                float v = acc[i][j][r] + bias[ch];
                v = v > 0.f ? v : 0.2f * v;
                hcatT[((size_t)b * NP + pt) * 512 + coff + ch] = f2bf(v);
            }
        }
    }
}

// ---------------------------------------------------------------- weight/bias cast + xm init (one launch)
__global__ __launch_bounds__(256) void wcast_kernel(const float* __restrict__ Wf, const float* __restrict__ Wc3,
                                                    const float* __restrict__ Wk, const float* __restrict__ Wv,
                                                    const float* __restrict__ bk, const float* __restrict__ bv,
                                                    const float* __restrict__ Wc1, const float* __restrict__ Wc2,
                                                    const float* __restrict__ Wq, const float* __restrict__ Wo,
                                                    const float* __restrict__ Wff1, const float* __restrict__ Wff2,
                                                    unsigned short* __restrict__ WfB, unsigned short* __restrict__ Wc3B,
                                                    unsigned short* __restrict__ WkvB, float* __restrict__ bkv,
                                                    unsigned short* __restrict__ Wc1B, unsigned short* __restrict__ Wc2B,
                                                    unsigned short* __restrict__ WtB, unsigned short* __restrict__ Wff1B,
                                                    unsigned short* __restrict__ Wff2B,
                                                    unsigned* __restrict__ xmk) {
    int id = blockIdx.x * 256 + threadIdx.x;
    if (id < 262144) { WfB[id] = f2bf(Wf[id]); return; }
    int j = id - 262144;
    if (j < 32768) { Wc3B[j] = f2bf(Wc3[j]); return; }
    j -= 32768;
    if (j < 524288) {
        int l = j >> 17, r = j & 131071;
        float v = (r < 65536) ? Wk[(size_t)(l * 2 + 1) * 65536 + r]
                              : Wv[(size_t)(l * 2 + 1) * 65536 + (r - 65536)];
        WkvB[j] = f2bf(v);
        return;
    }
    j -= 524288;
    if (j < 2048) {
        int l = j >> 9, r = j & 511;
        bkv[j] = (r < 256) ? bk[(l * 2 + 1) * 256 + r] : bv[(l * 2 + 1) * 256 + (r - 256)];
        return;
    }
    j -= 2048;
    if (j < 4096) { Wc1B[j] = f2bf(Wc1[j]); return; }
    j -= 4096;
    if (j < 8192) { Wc2B[j] = f2bf(Wc2[j]); return; }
    j -= 8192;
    if (j < 4096) { xmk[j] = 0u; return; }
    j -= 4096;
    if (j < 1572864) {
        int l = j / 393216;
        int r = j - l * 393216;
        int m = r >> 16, c = r & 65535;
        float v;
        if (m == 0)      v = Wq[(size_t)(l * 2 + 0) * 65536 + c];
        else if (m == 1) v = Wk[(size_t)(l * 2 + 0) * 65536 + c];
        else if (m == 2) v = Wv[(size_t)(l * 2 + 0) * 65536 + c];
        else if (m == 3) v = Wo[(size_t)(l * 2 + 0) * 65536 + c];
        else if (m == 4) v = Wq[(size_t)(l * 2 + 1) * 65536 + c];
        else             v = Wo[(size_t)(l * 2 + 1) * 65536 + c];
        WtB[j] = f2bf(v);
        return;
    }
    j -= 1572864;
    if (j < 524288) { Wff1B[j] = f2bf(Wff1[j]); return; }
    j -= 524288;
    if (j < 524288) { Wff2B[j] = f2bf(Wff2[j]); return; }
}

// ---------------------------------------------------------------- generic bf16 MFMA GEMM (encoder)
__global__ __launch_bounds__(256) void mfma_gemm_kernel(const unsigned short* __restrict__ A, size_t a_bstride,
                                                        const unsigned short* __restrict__ B, size_t b_bstride,
                                                        const float* __restrict__ bias, int bias_per_m,
                                                        void* __restrict__ C, size_t c_bstride, int c_rstride,
                                                        int K, int act, int out_bf16,
                                                        unsigned* __restrict__ xmk, int domax) {
    __shared__ unsigned short As[128][40];
    __shared__ unsigned short Bs[128][40];
    int m0 = blockIdx.x * 128, n0 = blockIdx.y * 128, b = blockIdx.z;
    int tid = threadIdx.x;
    int lane = tid & 63, wave = tid >> 6;
    int wr = wave >> 1, wc = wave & 1;
    int quad = lane >> 4, l16 = lane & 15;
    int r0 = tid >> 2, kc0 = (tid & 3) * 8;
    f32x4 acc[4][4] = {};
    const unsigned short* Ab = A + (size_t)b * a_bstride;
    const unsigned short* Bb = B + (size_t)b * b_bstride;
    for (int k0 = 0; k0 < K; k0 += 32) {
        uint4 a0 = *(const uint4*)(Ab + (size_t)(m0 + r0) * K + k0 + kc0);
        uint4 a1 = *(const uint4*)(Ab + (size_t)(m0 + r0 + 64) * K + k0 + kc0);
        uint4 b0 = *(const uint4*)(Bb + (size_t)(n0 + r0) * K + k0 + kc0);
        uint4 b1 = *(const uint4*)(Bb + (size_t)(n0 + r0 + 64) * K + k0 + kc0);
        __syncthreads();
        *(uint4*)&As[r0][kc0] = a0;
        *(uint4*)&As[r0 + 64][kc0] = a1;
        *(uint4*)&Bs[r0][kc0] = b0;
        *(uint4*)&Bs[r0 + 64][kc0] = b1;
        __syncthreads();
        bf16x8 af[4], bfv[4];
        #pragma unroll
        for (int i = 0; i < 4; ++i) af[i] = *(const bf16x8*)&As[wr * 64 + i * 16 + l16][quad * 8];
        #pragma unroll
        for (int j = 0; j < 4; ++j) bfv[j] = *(const bf16x8*)&Bs[wc * 64 + j * 16 + l16][quad * 8];
        #pragma unroll
        for (int i = 0; i < 4; ++i)
            #pragma unroll
            for (int j = 0; j < 4; ++j)
                acc[i][j] = __builtin_amdgcn_mfma_f32_16x16x32_bf16(af[i], bfv[j], acc[i][j], 0, 0, 0);
    }
    if (domax) {
        #pragma unroll
        for (int i = 0; i < 4; ++i) {
            #pragma unroll
            for (int r = 0; r < 4; ++r) {
                int m = m0 + wr * 64 + i * 16 + quad * 4 + r;
                float v = fmaxf(fmaxf(acc[i][0][r], acc[i][1][r]), fmaxf(acc[i][2][r], acc[i][3][r]));
                v += bias[m];
                #pragma unroll
                for (int off = 1; off <= 8; off <<= 1) v = fmaxf(v, __shfl_xor(v, off));
                if (l16 == 0) atomicMax(&xmk[(size_t)b * 512 + m], fmono(v));
            }
        }
        return;
    }
    #pragma unroll
    for (int i = 0; i < 4; ++i) {
        #pragma unroll
        for (int r = 0; r < 4; ++r) {
            int m = m0 + wr * 64 + i * 16 + quad * 4 + r;
            float bm = bias_per_m ? bias[m] : 0.f;
            #pragma unroll
            for (int j = 0; j < 4; ++j) {
                int n = n0 + wc * 64 + j * 16 + l16;
                float v = acc[i][j][r] + (bias_per_m ? bm : bias[n]);
                if (act) v = v > 0.f ? v : 0.2f * v;
                size_t off = (size_t)b * c_bstride + (size_t)m * c_rstride + n;
                if (out_bf16) ((unsigned short*)C)[off] = f2bf(v);
                else          ((float*)C)[off] = v;
            }
        }
    }
}

// ---------------------------------------------------------------- KV for ALL layers
__global__ __launch_bounds__(256) void mfma_kv_all_kernel(const unsigned short* __restrict__ A,
                                                          const unsigned short* __restrict__ W,
                                                          const float* __restrict__ bkv,
                                                          unsigned short* __restrict__ KVall) {
    __shared__ unsigned short As[128][40];
    __shared__ unsigned short Bs[128][40];
    int m0 = blockIdx.x * 128;
    int nb = blockIdx.y & 3, l = blockIdx.y >> 2;
    int n0 = nb * 128;
    int b = blockIdx.z;
    int tid = threadIdx.x;
    int lane = tid & 63, wave = tid >> 6;
    int wr = wave >> 1, wc = wave & 1;
    int quad = lane >> 4, l16 = lane & 15;
    int r0 = tid >> 2, kc0 = (tid & 3) * 8;
    f32x4 acc[4][4] = {};
    const unsigned short* Ab = A + (size_t)b * NP * 256;
    const unsigned short* Bb = W + (size_t)l * 131072;
    const float* bias = bkv + l * 512;
    for (int k0 = 0; k0 < 256; k0 += 32) {
        uint4 a0 = *(const uint4*)(Ab + (size_t)(m0 + r0) * 256 + k0 + kc0);
        uint4 a1 = *(const uint4*)(Ab + (size_t)(m0 + r0 + 64) * 256 + k0 + kc0);
        uint4 b0 = *(const uint4*)(Bb + (size_t)(n0 + r0) * 256 + k0 + kc0);
        uint4 b1 = *(const uint4*)(Bb + (size_t)(n0 + r0 + 64) * 256 + k0 + kc0);
        __syncthreads();
        *(uint4*)&As[r0][kc0] = a0;
        *(uint4*)&As[r0 + 64][kc0] = a1;
        *(uint4*)&Bs[r0][kc0] = b0;
        *(uint4*)&Bs[r0 + 64][kc0] = b1;
        __syncthreads();
        bf16x8 af[4], bfv[4];
        #pragma unroll
        for (int i = 0; i < 4; ++i) af[i] = *(const bf16x8*)&As[wr * 64 + i * 16 + l16][quad * 8];
        #pragma unroll
        for (int j = 0; j < 4; ++j) bfv[j] = *(const bf16x8*)&Bs[wc * 64 + j * 16 + l16][quad * 8];
        #pragma unroll
        for (int i = 0; i < 4; ++i)
            #pragma unroll
            for (int j = 0; j < 4; ++j)
                acc[i][j] = __builtin_amdgcn_mfma_f32_16x16x32_bf16(af[i], bfv[j], acc[i][j], 0, 0, 0);
    }
    unsigned short* Cb = KVall + ((size_t)l * BN + b) * NP * 512;
    #pragma unroll
    for (int i = 0; i < 4; ++i) {
        #pragma unroll
        for (int r = 0; r < 4; ++r) {
            int m = m0 + wr * 64 + i * 16 + quad * 4 + r;
            #pragma unroll
            for (int j = 0; j < 4; ++j) {
                int n = n0 + wc * 64 + j * 16 + l16;
                Cb[(size_t)m * 512 + n] = f2bf(acc[i][j][r] + bias[n]);
            }
        }
    }
}

// ---------------------------------------------------------------- q0 row + fold layer-0 QKV projection
__global__ __launch_bounds__(256) void pc_kernel(const unsigned* __restrict__ xmk, const float* __restrict__ Wpc,
                                                 const float* __restrict__ bpc,
                                                 const unsigned short* __restrict__ Wqkv,
                                                 const float* __restrict__ bq0, const float* __restrict__ bk0,
                                                 const float* __restrict__ bv0,
                                                 float* __restrict__ q, float* __restrict__ Qs,
                                                 float* __restrict__ Ks, float* __restrict__ Vs) {
    int row = blockIdx.x, tid = threadIdx.x;
    int id = row * 256 + tid;
    int b = row >> 3, i = row & 7;
    // L2 prefetch: one dword per 64B line of Wqkv (384 KB = 6144 lines / 256 thr = 24)
    float pf = 0.f;
    {
        const float* p3 = (const float*)Wqkv;
        #pragma unroll
        for (int t = 0; t < 24; ++t) pf += p3[(size_t)(tid + t * 256) << 4];
    }
    const unsigned* xr = xmk + b * 512 + i * 64;
    const float* w = Wpc + (size_t)tid * 64;
    float acc = bpc[tid];
    #pragma unroll
    for (int e = 0; e < 64; ++e) acc += funmono(xr[e]) * w[e];
    float qv = acc > 0.f ? acc : 0.2f * acc;
    q[id] = qv;
    __shared__ __align__(16) float a[256];
    a[tid] = qv;
    __syncthreads();
    asm volatile("" :: "v"(pf));
    Qs[id] = bq0[tid] + gemv_dot(Wqkv + (size_t)tid * 256, a, 32);
    Ks[id] = bk0[tid] + gemv_dot(Wqkv + 65536 + (size_t)tid * 256, a, 32);
    Vs[id] = bv0[tid] + gemv_dot(Wqkv + 131072 + (size_t)tid * 256, a, 32);
}

// ---------------------------------------------------------------- memB = bf16(act(x @ Wpi.T + bpi))
__global__ __launch_bounds__(256) void mem_kernel(const float* __restrict__ x, const float* __restrict__ Wpi,
                                                  const float* __restrict__ bpi, unsigned short* __restrict__ memB) {
    size_t id = (size_t)blockIdx.x * 256 + threadIdx.x;
    int p = (int)(id & 255);
    size_t pt = id >> 8;
    float x0 = x[pt * 3 + 0], x1 = x[pt * 3 + 1], x2 = x[pt * 3 + 2];
    float v = bpi[p] + x0 * Wpi[p * 3 + 0] + x1 * Wpi[p * 3 + 1] + x2 * Wpi[p * 3 + 2];
    v = v > 0.f ? v : 0.2f * v;
    memB[id] = f2bf(v);
}

// ---------------------------------------------------------------- self-attn + O-proj + res + LN + cross-Q-proj (1024 thr)
__global__ __launch_bounds__(1024) void attn_ln_kernel(const float* __restrict__ Qs, const float* __restrict__ Ks,
                                                       const float* __restrict__ Vs,
                                                       const unsigned short* __restrict__ WoB,
                                                       const float* __restrict__ bo, const float* __restrict__ res,
                                                       const float* __restrict__ g, const float* __restrict__ bt,
                                                       const unsigned short* __restrict__ Wq1B,
                                                       const float* __restrict__ bq1,
                                                       float* __restrict__ out, float* __restrict__ Qc) {
    int row = blockIdx.x, tid = threadIdx.x;
    int b = row >> 3;
    __shared__ float Kl[2048], Vl[2048];
    __shared__ __align__(16) float qr[256];
    __shared__ float sc[64];
    __shared__ __align__(16) float r[256];
    __shared__ __align__(16) float aout[256];
    __shared__ float red[1024];
    // L2 prefetch: Wo + Wq1 (2 x 128 KB = 2 x 2048 lines / 1024 thr = 2+2)
    float pf = 0.f;
    {
        const float* p0 = (const float*)WoB;
        const float* p1 = (const float*)Wq1B;
        #pragma unroll
        for (int t = 0; t < 2; ++t) pf += p0[(size_t)(tid + t * 1024) << 4];
        #pragma unroll
        for (int t = 0; t < 2; ++t) pf += p1[(size_t)(tid + t * 1024) << 4];
    }
    for (int t = tid; t < 2048; t += 1024) {
        Kl[t] = Ks[(size_t)b * 2048 + t];
        Vl[t] = Vs[(size_t)b * 2048 + t];
    }
    if (tid < 256) qr[tid] = Qs[(size_t)row * 256 + tid];
    __syncthreads();
    const float scale = 0.17677669529663687f;
    {
        int pair = tid >> 4, part = tid & 15;
        int h = pair >> 3, k = pair & 7;
        int d = part * 2;
        float dot = qr[h * 32 + d] * Kl[k * 256 + h * 32 + d]
                  + qr[h * 32 + d + 1] * Kl[k * 256 + h * 32 + d + 1];
        dot += __shfl_xor(dot, 1);
        dot += __shfl_xor(dot, 2);
        dot += __shfl_xor(dot, 4);
        dot += __shfl_xor(dot, 8);
        if (part == 0) sc[pair] = dot * scale;
    }
    __syncthreads();
    if (tid < 64) {
        float v = sc[tid];
        float m = v;
        #pragma unroll
        for (int off = 1; off < 8; off <<= 1) m = fmaxf(m, __shfl_xor(m, off));
        float e = __expf(v - m);
        float s = e;
        #pragma unroll
        for (int off = 1; off < 8; off <<= 1) s += __shfl_xor(s, off);
        sc[tid] = e / s;
    }
    __syncthreads();
    if (tid < 256) {
        int h = tid >> 5;
        float acc = 0.f;
        #pragma unroll
        for (int k = 0; k < 8; ++k) acc += sc[h * 8 + k] * Vl[k * 256 + tid];
        r[tid] = acc;
    }
    __syncthreads();
    asm volatile("" :: "v"(pf));
    // O-proj: 4 threads/output, 64-elem partials
    int o4 = tid >> 2, p4 = tid & 3;
    float v;
    {
        float acc = gemv_dot(WoB + (size_t)o4 * 256 + p4 * 64, r + p4 * 64, 8);
        acc += __shfl_xor(acc, 1);
        acc += __shfl_xor(acc, 2);
        v = (p4 == 0) ? (bo[o4] + acc + res[(size_t)row * 256 + o4]) : 0.f;
    }
    red[tid] = v; __syncthreads();
    for (int s = 512; s; s >>= 1) { if (tid < s) red[tid] += red[tid + s]; __syncthreads(); }
    float mean = red[0] * (1.0f / 256.0f);
    __syncthreads();
    float dv = (p4 == 0) ? v - mean : 0.f;
    red[tid] = dv * dv; __syncthreads();
    for (int s = 512; s; s >>= 1) { if (tid < s) red[tid] += red[tid + s]; __syncthreads(); }
    float var = red[0] * (1.0f / 256.0f);
    if (p4 == 0) {
        float oln = g[o4] * dv * rsqrtf(var + 1e-5f) + bt[o4];
        out[(size_t)row * 256 + o4] = oln;
        aout[o4] = oln;
    }
    __syncthreads();
    {
        float qacc = gemv_dot(Wq1B + (size_t)o4 * 256 + p4 * 64, aout + p4 * 64, 8);
        qacc += __shfl_xor(qacc, 1);
        qacc += __shfl_xor(qacc, 2);
        if (p4 == 0) Qc[(size_t)row * 256 + o4] = bq1[o4] + qacc;
    }
}

// ---------------------------------------------------------------- cross-attn pass 1: 16 key-blocks of 128
__global__ __launch_bounds__(256) void ca_part_kernel(const float* __restrict__ Qc,
                                                      const unsigned short* __restrict__ KVl,
                                                      float* __restrict__ part) {
    int kb = blockIdx.x, h = blockIdx.y, b = blockIdx.z;
    int tid = threadIdx.x;
    __shared__ float q[8][32];
    __shared__ __align__(16) float S[8][128];
    __shared__ float om[8][8][32];
    const float scale = 0.17677669529663687f;
    {
        int i = tid >> 5, d = tid & 31;
        q[i][d] = Qc[(size_t)(b * 8 + i) * 256 + h * 32 + d];
    }
    __syncthreads();
    {
        int kk = tid & 127, half = tid >> 7;
        int k = kb * 128 + kk;
        const unsigned short* kp = KVl + ((size_t)b * NP + k) * 512 + h * 32;
        float kd[32];
        #pragma unroll
        for (int u = 0; u < 4; ++u) {
            uint4 raw = *(const uint4*)(kp + u * 8);
            unsigned w0 = raw.x, w1 = raw.y, w2 = raw.z, w3 = raw.w;
            kd[u * 8 + 0] = __uint_as_float(w0 << 16); kd[u * 8 + 1] = __uint_as_float(w0 & 0xFFFF0000u);
            kd[u * 8 + 2] = __uint_as_float(w1 << 16); kd[u * 8 + 3] = __uint_as_float(w1 & 0xFFFF0000u);
            kd[u * 8 + 4] = __uint_as_float(w2 << 16); kd[u * 8 + 5] = __uint_as_float(w2 & 0xFFFF0000u);
            kd[u * 8 + 6] = __uint_as_float(w3 << 16); kd[u * 8 + 7] = __uint_as_float(w3 & 0xFFFF0000u);
        }
        #pragma unroll
        for (int i = 0; i < 4; ++i) {
            int ri = half * 4 + i;
            float dot = 0.f;
            #pragma unroll
            for (int d = 0; d < 32; ++d) dot += q[ri][d] * kd[d];
            S[ri][kk] = dot * scale;
        }
    }
    __syncthreads();
    float* pout = part + (((size_t)(b * NH + h)) * 16 + kb) * 288;
    {
        int i = tid >> 5, l32 = tid & 31;
        float m = -3.4e38f;
        #pragma unroll
        for (int t = 0; t < 4; ++t) m = fmaxf(m, S[i][l32 + t * 32]);
        #pragma unroll
        for (int off = 16; off; off >>= 1) m = fmaxf(m, __shfl_xor(m, off));
        float s = 0.f;
        #pragma unroll
        for (int t = 0; t < 4; ++t) {
            float e = __expf(S[i][l32 + t * 32] - m);
            S[i][l32 + t * 32] = e;
            s += e;
        }
        #pragma unroll
        for (int off = 16; off; off >>= 1) s += __shfl_xor(s, off);
        if (l32 == 0) { pout[i] = m; pout[8 + i] = s; }
    }
    __syncthreads();
    {
        int d = tid & 31, grp = tid >> 5;
        const unsigned short* Vb = KVl + ((size_t)b * NP + kb * 128) * 512 + 256 + h * 32 + d;
        float acc[8] = {};
        #pragma unroll 4
        for (int t = 0; t < 16; ++t) {
            int kk = grp * 16 + t;
            float v = bf2f(Vb[(size_t)kk * 512]);
            #pragma unroll
            for (int i = 0; i < 8; ++i) acc[i] += S[i][kk] * v;
        }
        #pragma unroll
        for (int i = 0; i < 8; ++i) om[grp][i][d] = acc[i];
    }
    __syncthreads();
    {
        int i = tid >> 5, d = tid & 31;
        float sum = 0.f;
        #pragma unroll
        for (int g = 0; g < 8; ++g) sum += om[g][i][d];
        pout[16 + i * 32 + d] = sum;
    }
}

// ---------------------------------------------------------------- combine + O-proj + LN + FF + LN [+ next-layer QKV | final LN+Wcm] (1024 thr)
__global__ __launch_bounds__(1024) void combine_ff_kernel(const float* __restrict__ part,
                                                          const unsigned short* __restrict__ WoB,
                                                          const float* __restrict__ bo, const float* __restrict__ res,
                                                          const float* __restrict__ g2, const float* __restrict__ b2t,
                                                          const unsigned short* __restrict__ W1B,
                                                          const float* __restrict__ b1,
                                                          const unsigned short* __restrict__ W2B,
                                                          const float* __restrict__ b2,
                                                          const float* __restrict__ g3, const float* __restrict__ b3t,
                                                          float* __restrict__ out,
                                                          int is_last, const float* __restrict__ lnfg,
                                                          const float* __restrict__ lnfb, const float* __restrict__ Wcm,
                                                          const float* __restrict__ bcm, float* __restrict__ finout,
                                                          const unsigned short* __restrict__ Wqkvn,
                                                          const float* __restrict__ bqn, const float* __restrict__ bkn,
                                                          const float* __restrict__ bvn,
                                                          float* __restrict__ Qs, float* __restrict__ Ks,
                                                          float* __restrict__ Vs) {
    int row = blockIdx.x, tid = threadIdx.x;
    int b = row >> 3, i = row & 7;
    __shared__ __align__(16) float r[256];
    __shared__ __align__(16) float a[256];
    __shared__ __align__(16) float hbuf[512];
    __shared__ float red[1024];
    // L2 prefetch: Wo (2048 lines) + W1 (4096) + W2 (4096) + next QKV (6144), one dword per 64B line
    float pf = 0.f;
    {
        const float* p0 = (const float*)WoB;
        const float* p1 = (const float*)W1B;
        const float* p2 = (const float*)W2B;
        #pragma unroll
        for (int t = 0; t < 2; ++t) pf += p0[(size_t)(tid + t * 1024) << 4];
        #pragma unroll
        for (int t = 0; t < 4; ++t) pf += p1[(size_t)(tid + t * 1024) << 4];
        #pragma unroll
        for (int t = 0; t < 4; ++t) pf += p2[(size_t)(tid + t * 1024) << 4];
        if (!is_last) {
            const float* p3 = (const float*)Wqkvn;
            #pragma unroll
            for (int t = 0; t < 6; ++t) pf += p3[(size_t)(tid + t * 1024) << 4];
        }
    }
    // phase 1: combine cross-attn partials (4 threads per (h,d), each 4 key-blocks)
    {
        int h = tid >> 7, rem = tid & 127, d = rem >> 2, g = rem & 3;
        const float* pb = part + (size_t)(b * NH + h) * 16 * 288;
        float M = -3.4e38f;
        #pragma unroll
        for (int t = 0; t < 4; ++t) M = fmaxf(M, pb[(g * 4 + t) * 288 + i]);
        M = fmaxf(M, __shfl_xor(M, 1));
        M = fmaxf(M, __shfl_xor(M, 2));
        float L = 0.f, O = 0.f;
        #pragma unroll
        for (int t = 0; t < 4; ++t) {
            int kb = g * 4 + t;
            float w = __expf(pb[kb * 288 + i] - M);
            L += pb[kb * 288 + 8 + i] * w;
            O += pb[kb * 288 + 16 + i * 32 + d] * w;
        }
        L += __shfl_xor(L, 1); L += __shfl_xor(L, 2);
        O += __shfl_xor(O, 1); O += __shfl_xor(O, 2);
        if (g == 0) r[h * 32 + d] = O / L;
    }
    __syncthreads();
    asm volatile("" :: "v"(pf));
    int o4 = tid >> 2, p4 = tid & 3;
    // phase 2: O-proj (4 thr/out) + residual + LN
    float v;
    {
        float acc = gemv_dot(WoB + (size_t)o4 * 256 + p4 * 64, r + p4 * 64, 8);
        acc += __shfl_xor(acc, 1);
        acc += __shfl_xor(acc, 2);
        v = (p4 == 0) ? (bo[o4] + acc + res[(size_t)row * 256 + o4]) : 0.f;
    }
    red[tid] = v; __syncthreads();
    for (int s = 512; s; s >>= 1) { if (tid < s) red[tid] += red[tid + s]; __syncthreads(); }
    float mean = red[0] * (1.0f / 256.0f);
    __syncthreads();
    float dv = (p4 == 0) ? v - mean : 0.f;
    red[tid] = dv * dv; __syncthreads();
    for (int s = 512; s; s >>= 1) { if (tid < s) red[tid] += red[tid + s]; __syncthreads(); }
    float var = red[0] * (1.0f / 256.0f);
    if (p4 == 0) a[o4] = g2[o4] * dv * rsqrtf(var + 1e-5f) + b2t[o4];
    __syncthreads();
    // phase 3: FF1 (2 thr/out, 128-elem partials)
    {
        int o = tid >> 1, p = tid & 1;
        float acc = gemv_dot(W1B + (size_t)o * 256 + p * 128, a + p * 128, 16);
        acc += __shfl_xor(acc, 1);
        if (p == 0) { float t = b1[o] + acc; hbuf[o] = t > 0.f ? t : 0.2f * t; }
    }
    __syncthreads();
    // phase 4: FF2 (4 thr/out, K=512) + residual + LN
    float vF;
    {
        float acc = gemv_dot(W2B + (size_t)o4 * 512 + p4 * 128, hbuf + p4 * 128, 16);
        acc += __shfl_xor(acc, 1);
        acc += __shfl_xor(acc, 2);
        vF = (p4 == 0) ? (b2[o4] + acc + a[o4]) : 0.f;
    }
    red[tid] = vF; __syncthreads();
    for (int s = 512; s; s >>= 1) { if (tid < s) red[tid] += red[tid + s]; __syncthreads(); }
    float mean2 = red[0] * (1.0f / 256.0f);
    __syncthreads();
    float dv2 = (p4 == 0) ? vF - mean2 : 0.f;
    red[tid] = dv2 * dv2; __syncthreads();
    for (int s = 512; s; s >>= 1) { if (tid < s) red[tid] += red[tid + s]; __syncthreads(); }
    float var2 = red[0] * (1.0f / 256.0f);
    float tln = 0.f;
    if (p4 == 0) {
        tln = g3[o4] * dv2 * rsqrtf(var2 + 1e-5f) + b3t[o4];
        r[o4] = tln;
    }
    __syncthreads();
    if (!is_last) {
        if (p4 == 0) out[(size_t)row * 256 + o4] = tln;
        // next-layer QKV from tln row in r[]: 768 full-dot threads
        if (tid < 768) {
            int which = tid >> 8, o = tid & 255;
            float acc = gemv_dot(Wqkvn + (size_t)which * 65536 + (size_t)o * 256, r, 32);
            float bb = (which == 0) ? bqn[o] : (which == 1) ? bkn[o] : bvn[o];
            float* dst = (which == 0) ? Qs : (which == 1) ? Ks : Vs;
            dst[(size_t)row * 256 + o] = bb + acc;
        }
        return;
    }
    // final LN + Wcm
    float tf = (tid < 256) ? r[tid] : 0.f;
    red[tid] = tf; __syncthreads();
    for (int s = 512; s; s >>= 1) { if (tid < s) red[tid] += red[tid + s]; __syncthreads(); }
    float mean3 = red[0] * (1.0f / 256.0f);
    __syncthreads();
    float d3 = (tid < 256) ? tf - mean3 : 0.f;
    red[tid] = d3 * d3; __syncthreads();
    for (int s = 512; s; s >>= 1) { if (tid < s) red[tid] += red[tid + s]; __syncthreads(); }
    float var3 = red[0] * (1.0f / 256.0f);
    if (tid < 256) a[tid] = lnfg[tid] * d3 * rsqrtf(var3 + 1e-5f) + lnfb[tid];
    __syncthreads();
    if (tid < 64) {
        const float4* w4 = (const float4*)(Wcm + (size_t)tid * 256);
        const float4* a4 = (const float4*)a;
        float acc = bcm[tid];
        #pragma unroll 8
        for (int c = 0; c < 64; ++c) {
            float4 av = a4[c], wv = w4[c];
            acc += av.x * wv.x + av.y * wv.y + av.z * wv.z + av.w * wv.w;
        }
        finout[(size_t)b * 512 + i * 64 + tid] = acc;
    }
}

// ================================================================ host
extern "C" void kernel_launch(void* const* d_in, const int* in_sizes, int n_in,
                              void* d_out, int out_size, void* d_ws, size_t ws_size,
                              hipStream_t stream) {
    const float* x    = (const float*)d_in[0];
    const float* Wec  = (const float*)d_in[1];
    const float* bec  = (const float*)d_in[2];
    const float* Wc1  = (const float*)d_in[3];
    const float* bc1  = (const float*)d_in[4];
    const float* Wc2  = (const float*)d_in[5];
    const float* bc2  = (const float*)d_in[6];
    const float* Wc3  = (const float*)d_in[7];
    const float* bc3  = (const float*)d_in[8];
    const float* Wf   = (const float*)d_in[9];
    const float* bf   = (const float*)d_in[10];
    const float* Wpc  = (const float*)d_in[11];
    const float* bpc  = (const float*)d_in[12];
    const float* Wpi  = (const float*)d_in[13];
    const float* bpi  = (const float*)d_in[14];
    const float* Wq   = (const float*)d_in[15];
    const float* bq   = (const float*)d_in[16];
    const float* Wk   = (const float*)d_in[17];
    const float* bk   = (const float*)d_in[18];
    const float* Wv   = (const float*)d_in[19];
    const float* bv   = (const float*)d_in[20];
    const float* Wo   = (const float*)d_in[21];
    const float* bo   = (const float*)d_in[22];
    const float* ln1g = (const float*)d_in[23];
    const float* ln1b = (const float*)d_in[24];
    const float* ln2g = (const float*)d_in[25];
    const float* ln2b = (const float*)d_in[26];
    const float* Wff1 = (const float*)d_in[27];
    const float* bff1 = (const float*)d_in[28];
    const float* Wff2 = (const float*)d_in[29];
    const float* bff2 = (const float*)d_in[30];
    const float* ln3g = (const float*)d_in[31];
    const float* ln3b = (const float*)d_in[32];
    const float* lnfg = (const float*)d_in[33];
    const float* lnfb = (const float*)d_in[34];
    const float* Wcm  = (const float*)d_in[35];
    const float* bcm  = (const float*)d_in[36];
    float* out = (float*)d_out;

    float* ws = (float*)d_ws;
    size_t off = 0;
    auto alloc = [&](size_t n) { float* p = ws + off; off += (n + 3) & ~(size_t)3; return p; };
    int*            idx   = (int*)alloc((size_t)BN * NP * KNN);
    unsigned short* hcatT = (unsigned short*)alloc((size_t)BN * NP * 512 / 2);
    unsigned short* poolT = (unsigned short*)alloc((size_t)BN * NP * 128 / 2);
    unsigned short* WfB   = (unsigned short*)alloc(262144 / 2);
    unsigned short* Wc1B  = (unsigned short*)alloc(4096 / 2);
    unsigned short* Wc2B  = (unsigned short*)alloc(8192 / 2);
    unsigned short* Wc3B  = (unsigned short*)alloc(32768 / 2);
    unsigned short* WkvB  = (unsigned short*)alloc(524288 / 2);
    float*          bkv   = alloc(2048);
    unsigned short* memB  = (unsigned short*)alloc((size_t)BN * NP * 256 / 2);
    unsigned short* KVall = (unsigned short*)alloc((size_t)NL * BN * NP * 512 / 2);
    unsigned*       xmk   = (unsigned*)alloc((size_t)BN * 512);
    unsigned short* WtB   = (unsigned short*)alloc(1572864 / 2);
    unsigned short* Wff1B = (unsigned short*)alloc(524288 / 2);
    unsigned short* Wff2B = (unsigned short*)alloc(524288 / 2);
    float*          qa    = alloc((size_t)BN * 8 * 256);
    float*          qb    = alloc((size_t)BN * 8 * 256);
    float*          Qs    = alloc((size_t)BN * 8 * 256);
    float*          Ks    = alloc((size_t)BN * 8 * 256);
    float*          Vs    = alloc((size_t)BN * 8 * 256);
    float*          Qc    = alloc((size_t)BN * 8 * 256);
    float*          part  = alloc((size_t)BN * NH * 16 * 288);

    // ---- weight casts + xm-key init (no deps) ----
    wcast_kernel<<<13512, 256, 0, stream>>>(Wf, Wc3, Wk, Wv, bk, bv, Wc1, Wc2, Wq, Wo, Wff1, Wff2,
                                            WfB, Wc3B, WkvB, bkv, Wc1B, Wc2B, WtB, Wff1B, Wff2B, xmk);

    // ---- point-cloud encoder (all-bf16 [pt][ch] chain) ----
    knn_kernel<<<BN * NP / 4, 256, 0, stream>>>(x, idx);
    edge_conv_kernel<<<BN * NP / 4, 256, 0, stream>>>(x, idx, Wec, bec, hcatT);

    pool_bf16_kernel<<<BN * NP / 4, 256, 0, stream>>>(hcatT, 0, idx, poolT, 64);
    mfma_conv64_kernel<<<dim3(NP / 128, 1, BN), 256, 0, stream>>>(poolT, Wc1B, bc1, hcatT, 64);
    pool_bf16_kernel<<<BN * NP / 4, 256, 0, stream>>>(hcatT, 64, idx, poolT, 64);
    mfma_gemm_kernel<<<dim3(NP / 128, 1, BN), 256, 0, stream>>>(poolT, (size_t)NP * 64, Wc2B, 0,
                                                                bc2, 0, (void*)(hcatT + 128), (size_t)NP * 512, 512,
                                                                64, 1, 1, nullptr, 0);
    pool_bf16_kernel<<<BN * NP / 4, 256, 0, stream>>>(hcatT, 128, idx, poolT, 128);
    mfma_gemm_kernel<<<dim3(NP / 128, 2, BN), 256, 0, stream>>>(poolT, (size_t)NP * 128, Wc3B, 0,
                                                                bc3, 0, (void*)(hcatT + 256), (size_t)NP * 512, 512,
                                                                128, 1, 1, nullptr, 0);
    mfma_gemm_kernel<<<dim3(4, NP / 128, BN), 256, 0, stream>>>(WfB, 0, hcatT, (size_t)NP * 512,
                                                                bf, 1, nullptr, 0, 0,
                                                                512, 0, 0, xmk, 1);
    pc_kernel<<<BN * 8, 256, 0, stream>>>(xmk, Wpc, bpc, WtB, bq, bk, bv, qa, Qs, Ks, Vs);
    mem_kernel<<<BN * NP, 256, 0, stream>>>(x, Wpi, bpi, memB);
    mfma_kv_all_kernel<<<dim3(NP / 128, 4 * NL, BN), 256, 0, stream>>>(memB, WkvB, bkv, KVall);

    // ---- transformer layers (3 launches/layer; QKV folded into producer) ----
    for (int l = 0; l < NL; ++l) {
        const unsigned short* Wl = WtB + (size_t)l * 393216;
        const float* bo0 = bo + (l * 2 + 0) * 256;
        const float* bq1 = bq + (l * 2 + 1) * 256;
        const float* bo1 = bo + (l * 2 + 1) * 256;
        int last = (l == NL - 1);

        attn_ln_kernel<<<BN * 8, 1024, 0, stream>>>(Qs, Ks, Vs, Wl + 3 * 65536, bo0, qa,
                                                    ln1g + l * 256, ln1b + l * 256, Wl + 4 * 65536, bq1, qb, Qc);
        ca_part_kernel<<<dim3(16, NH, BN), 256, 0, stream>>>(Qc, KVall + (size_t)l * BN * NP * 512, part);
        combine_ff_kernel<<<BN * 8, 1024, 0, stream>>>(part, Wl + 5 * 65536, bo1, qb,
                                                       ln2g + l * 256, ln2b + l * 256,
                                                       Wff1B + (size_t)l * 131072, bff1 + l * 512,
                                                       Wff2B + (size_t)l * 131072, bff2 + l * 256,
                                                       ln3g + l * 256, ln3b + l * 256, qa,
                                                       last, lnfg, lnfb, Wcm, bcm, out,
                                                       last ? nullptr : WtB + (size_t)(l + 1) * 393216,
                                                       bq + ((l + 1) * 2) * 256, bk + ((l + 1) * 2) * 256,
                                                       bv + ((l + 1) * 2) * 256,
                                                       Qs, Ks, Vs);
    }

    (void)in_sizes; (void)n_in; (void)out_size; (void)ws_size;
}

// Round 9
// 560.954 us; speedup vs baseline: 1.0523x; 1.0523x over previous
//
#include <hip/hip_runtime.h>
#include <math.h>

#define BN 8
#define NP 2048
#define KNN 16
#define NL 4
#define NH 8

typedef __attribute__((ext_vector_type(8))) short bf16x8;
typedef __attribute__((ext_vector_type(4))) float f32x4;

__device__ __forceinline__ unsigned short f2bf(float f) {
    unsigned u = __float_as_uint(f);
    unsigned r = (u + 0x7FFFu + ((u >> 16) & 1u)) >> 16;
    return (unsigned short)r;
}
__device__ __forceinline__ float bf2f(unsigned short s) {
    return __uint_as_float(((unsigned)s) << 16);
}
__device__ __forceinline__ unsigned fmono(float f) {
    unsigned u = __float_as_uint(f);
    return (u & 0x80000000u) ? ~u : (u | 0x80000000u);
}
__device__ __forceinline__ float funmono(unsigned k) {
    return (k & 0x80000000u) ? __uint_as_float(k ^ 0x80000000u) : __uint_as_float(~k);
}
__device__ __forceinline__ int xcc_id() {
    int x;
    asm("s_getreg_b32 %0, hwreg(HW_REG_XCC_ID)" : "=s"(x));
    return x & 7;
}

// dot of one bf16 weight row (K8*8 elements) against fp32 vector in LDS.
// 4 independent accumulator chains so the compiler keeps >=4 loads in flight.
__device__ __forceinline__ float gemv_dot(const unsigned short* __restrict__ wrow, const float* sm, int K8) {
    const uint4* w8 = (const uint4*)wrow;
    const float4* r4 = (const float4*)sm;
    float a0 = 0.f, a1 = 0.f, a2 = 0.f, a3 = 0.f;
    #pragma unroll 8
    for (int c = 0; c < K8; ++c) {
        uint4 wv = w8[c];
        float4 x0 = r4[c * 2], x1 = r4[c * 2 + 1];
        a0 += x0.x * __uint_as_float(wv.x << 16) + x0.y * __uint_as_float(wv.x & 0xFFFF0000u);
        a1 += x0.z * __uint_as_float(wv.y << 16) + x0.w * __uint_as_float(wv.y & 0xFFFF0000u);
        a2 += x1.x * __uint_as_float(wv.z << 16) + x1.y * __uint_as_float(wv.z & 0xFFFF0000u);
        a3 += x1.z * __uint_as_float(wv.w << 16) + x1.w * __uint_as_float(wv.w & 0xFFFF0000u);
    }
    return (a0 + a1) + (a2 + a3);
}

// ---------------------------------------------------------------- knn v7: pivot-filter select (verified R2)
__device__ __forceinline__ unsigned long long shflx_u64(unsigned long long v, int j) {
    int lo = __shfl_xor((int)(unsigned)(v & 0xFFFFFFFFull), j);
    int hi = __shfl_xor((int)(unsigned)(v >> 32), j);
    return ((unsigned long long)(unsigned)hi << 32) | (unsigned)lo;
}

__device__ __forceinline__ unsigned sort64_u32(unsigned v, int lane) {
    #pragma unroll
    for (int k = 2; k <= 64; k <<= 1) {
        #pragma unroll
        for (int j = k >> 1; j > 0; j >>= 1) {
            unsigned o = (unsigned)__shfl_xor((int)v, j);
            bool up = ((lane & k) == 0);
            bool lower = ((lane & j) == 0);
            unsigned mn = v < o ? v : o;
            unsigned mx = v < o ? o : v;
            v = (up == lower) ? mn : mx;
        }
    }
    return v;
}

__device__ __forceinline__ unsigned long long sort64_u64(unsigned long long v, int lane) {
    #pragma unroll
    for (int k = 2; k <= 64; k <<= 1) {
        #pragma unroll
        for (int j = k >> 1; j > 0; j >>= 1) {
            unsigned long long o = shflx_u64(v, j);
            bool up = ((lane & k) == 0);
            bool lower = ((lane & j) == 0);
            unsigned long long mn = v < o ? v : o;
            unsigned long long mx = v < o ? o : v;
            v = (up == lower) ? mn : mx;
        }
    }
    return v;
}

__global__ __launch_bounds__(256) void knn_kernel(const float* __restrict__ x, int* __restrict__ idxout) {
    __shared__ unsigned long long cand[4][64];
    int tid = threadIdx.x;
    int wv = tid >> 6, lane = tid & 63;
    int p = blockIdx.x * 4 + wv;
    int b = p >> 11, n = p & 2047;
    const float* xb = x + (size_t)b * NP * 3;
    float cx = xb[n * 3 + 0], cy = xb[n * 3 + 1], cz = xb[n * 3 + 2];
    float xn = cx * cx + cy * cy + cz * cz;
    unsigned key[32];
    unsigned lmax = 0u;
    #pragma unroll
    for (int t = 0; t < 32; ++t) {
        int m = (t << 6) | lane;
        float mx = xb[m * 3 + 0], my = xb[m * 3 + 1], mz = xb[m * 3 + 2];
        float xxm = mx * mx + my * my + mz * mz;
        float inner = cx * mx + cy * my + cz * mz;
        float dd = 2.0f * inner - xn - xxm;
        unsigned u = __float_as_uint(dd);
        u = (u & 0x80000000u) ? ~u : (u | 0x80000000u);
        key[t] = u;
        lmax = lmax > u ? lmax : u;
    }
    unsigned sorted = sort64_u32(lmax, lane);
    unsigned S = (unsigned)__shfl((int)sorted, 48);
    int c = 0;
    #pragma unroll
    for (int t = 0; t < 32; ++t) c += (key[t] >= S) ? 1 : 0;
    int inc = c;
    #pragma unroll
    for (int d = 1; d < 64; d <<= 1) {
        int tsh = __shfl_up(inc, d);
        if (lane >= d) inc += tsh;
    }
    int C = __shfl(inc, 63);
    int* op = idxout + (size_t)p * KNN;
    if (C <= 64) {
        int off = inc - c;
        #pragma unroll
        for (int t = 0; t < 32; ++t) {
            if (key[t] >= S) {
                int m = (t << 6) | lane;
                cand[wv][off++] = ((unsigned long long)key[t] << 16) | (unsigned)(2047 - m);
            }
        }
        asm volatile("s_waitcnt lgkmcnt(0)" ::: "memory");
        unsigned long long ck = (lane < C) ? cand[wv][lane] : 0ull;
        ck = sort64_u64(ck, lane);
        if (lane >= 48) op[63 - lane] = 2047 - (int)(unsigned)(ck & 0xFFFFull);
    } else {
        unsigned taken = 0u;
        for (int r = 0; r < KNN; ++r) {
            unsigned long long best = 0ull;
            #pragma unroll
            for (int t = 0; t < 32; ++t) {
                if (!((taken >> t) & 1u)) {
                    int m = (t << 6) | lane;
                    unsigned long long ck = ((unsigned long long)key[t] << 16) | (unsigned)(2047 - m);
                    if (ck > best) best = ck;
                }
            }
            #pragma unroll
            for (int d = 1; d < 64; d <<= 1) {
                unsigned long long o = shflx_u64(best, d);
                if (o > best) best = o;
            }
            int m = 2047 - (int)(unsigned)(best & 0xFFFFull);
            if (lane == 0) op[r] = m;
            if ((m & 63) == lane) taken |= 1u << (m >> 6);
        }
    }
}

// ---------------------------------------------------------------- edge conv + max over k -> hcatT[:,0:64] bf16
__global__ __launch_bounds__(256) void edge_conv_kernel(const float* __restrict__ x, const int* __restrict__ idx,
                                                        const float* __restrict__ Wec, const float* __restrict__ bec,
                                                        unsigned short* __restrict__ hcatT) {
    int tid = threadIdx.x;
    int g = tid >> 6, o = tid & 63;
    int p = blockIdx.x * 4 + g;
    int b = p >> 11;
    __shared__ float nb[4][KNN][3];
    __shared__ float ctr[4][3];
    if (o < KNN) {
        int j = idx[(size_t)p * KNN + o];
        const float* xp = x + ((size_t)b * NP + j) * 3;
        nb[g][o][0] = xp[0]; nb[g][o][1] = xp[1]; nb[g][o][2] = xp[2];
    }
    if (o >= KNN && o < KNN + 3) ctr[g][o - KNN] = x[(size_t)p * 3 + (o - KNN)];
    __syncthreads();
    float w0 = Wec[o * 6 + 0], w1 = Wec[o * 6 + 1], w2 = Wec[o * 6 + 2];
    float w3 = Wec[o * 6 + 3], w4 = Wec[o * 6 + 4], w5 = Wec[o * 6 + 5];
    float c0 = ctr[g][0], c1 = ctr[g][1], c2 = ctr[g][2];
    float base = bec[o] + w3 * c0 + w4 * c1 + w5 * c2;
    float m = -3.4e38f;
    #pragma unroll
    for (int k = 0; k < KNN; ++k) {
        float v = base + w0 * (nb[g][k][0] - c0) + w1 * (nb[g][k][1] - c1) + w2 * (nb[g][k][2] - c2);
        v = v > 0.f ? v : 0.2f * v;
        m = fmaxf(m, v);
    }
    hcatT[(size_t)p * 512 + o] = f2bf(m);
}

// ---------------------------------------------------------------- graph max pool, bf16 [pt][ch] -> bf16 [pt][C]
__global__ __launch_bounds__(256) void pool_bf16_kernel(const unsigned short* __restrict__ src, int s_coff,
                                                        const int* __restrict__ idx,
                                                        unsigned short* __restrict__ dst, int C) {
    int tid = threadIdx.x, wv = tid >> 6, lane = tid & 63;
    int p = blockIdx.x * 4 + wv;
    int b = p >> 11;
    const int* ip = idx + (size_t)p * KNN;
    const unsigned short* sb = src + (size_t)b * NP * 512 + s_coff;
    for (int c0 = 0; c0 < C; c0 += 64) {
        int ch = c0 + lane;
        float m = -3.4e38f;
        #pragma unroll
        for (int k = 0; k < KNN; ++k) {
            int j = ip[k];
            m = fmaxf(m, bf2f(sb[(size_t)j * 512 + ch]));
        }
        dst[(size_t)p * C + ch] = f2bf(m);
    }
}

// ---------------------------------------------------------------- conv1 MFMA: 128pts x 64ch, K=64
__global__ __launch_bounds__(256) void mfma_conv64_kernel(const unsigned short* __restrict__ A,
                                                          const unsigned short* __restrict__ W,
                                                          const float* __restrict__ bias,
                                                          unsigned short* __restrict__ hcatT, int coff) {
    __shared__ unsigned short As[128][72];
    __shared__ unsigned short Bs[64][72];
    int m0 = blockIdx.x * 128, b = blockIdx.z;
    int tid = threadIdx.x;
    int lane = tid & 63, wave = tid >> 6;
    int wr = wave >> 1, wc = wave & 1;
    int quad = lane >> 4, l16 = lane & 15;
    {
        int r = tid >> 1, s = (tid & 1) * 32;
        const unsigned short* ap = A + (size_t)b * NP * 64 + (size_t)(m0 + r) * 64 + s;
        uint4 v0 = *(const uint4*)(ap);
        uint4 v1 = *(const uint4*)(ap + 8);
        uint4 v2 = *(const uint4*)(ap + 16);
        uint4 v3 = *(const uint4*)(ap + 24);
        *(uint4*)&As[r][s] = v0; *(uint4*)&As[r][s + 8] = v1;
        *(uint4*)&As[r][s + 16] = v2; *(uint4*)&As[r][s + 24] = v3;
    }
    {
        int r = tid >> 2, s = (tid & 3) * 16;
        const unsigned short* wp = W + r * 64 + s;
        *(uint4*)&Bs[r][s] = *(const uint4*)wp;
        *(uint4*)&Bs[r][s + 8] = *(const uint4*)(wp + 8);
    }
    __syncthreads();
    f32x4 acc[4][2] = {};
    #pragma unroll
    for (int k0 = 0; k0 < 64; k0 += 32) {
        bf16x8 af[4], bfv[2];
        #pragma unroll
        for (int i = 0; i < 4; ++i) af[i] = *(const bf16x8*)&As[wr * 64 + i * 16 + l16][k0 + quad * 8];
        #pragma unroll
        for (int j = 0; j < 2; ++j) bfv[j] = *(const bf16x8*)&Bs[wc * 32 + j * 16 + l16][k0 + quad * 8];
        #pragma unroll
        for (int i = 0; i < 4; ++i)
            #pragma unroll
            for (int j = 0; j < 2; ++j)
                acc[i][j] = __builtin_amdgcn_mfma_f32_16x16x32_bf16(af[i], bfv[j], acc[i][j], 0, 0, 0);
    }
    #pragma unroll
    for (int i = 0; i < 4; ++i) {
        #pragma unroll
        for (int r = 0; r < 4; ++r) {
            int pt = m0 + wr * 64 + i * 16 + quad * 4 + r;
            #pragma unroll
            for (int j = 0; j < 2; ++j) {
                int ch = wc * 32 + j * 16 + l16;
                float v = acc[i][j][r] + bias[ch];
                v = v > 0.f ? v : 0.2f * v;
                hcatT[((size_t)b * NP + pt) * 512 + coff + ch] = f2bf(v);
            }
        }
    }
}

// ---------------------------------------------------------------- weight/bias cast + xm init (one launch)
__global__ __launch_bounds__(256) void wcast_kernel(const float* __restrict__ Wf, const float* __restrict__ Wc3,
                                                    const float* __restrict__ Wk, const float* __restrict__ Wv,
                                                    const float* __restrict__ bk, const float* __restrict__ bv,
                                                    const float* __restrict__ Wc1, const float* __restrict__ Wc2,
                                                    const float* __restrict__ Wq, const float* __restrict__ Wo,
                                                    const float* __restrict__ Wff1, const float* __restrict__ Wff2,
                                                    unsigned short* __restrict__ WfB, unsigned short* __restrict__ Wc3B,
                                                    unsigned short* __restrict__ WkvB, float* __restrict__ bkv,
                                                    unsigned short* __restrict__ Wc1B, unsigned short* __restrict__ Wc2B,
                                                    unsigned short* __restrict__ WtB, unsigned short* __restrict__ Wff1B,
                                                    unsigned short* __restrict__ Wff2B,
                                                    unsigned* __restrict__ xmk) {
    int id = blockIdx.x * 256 + threadIdx.x;
    if (id < 262144) { WfB[id] = f2bf(Wf[id]); return; }
    int j = id - 262144;
    if (j < 32768) { Wc3B[j] = f2bf(Wc3[j]); return; }
    j -= 32768;
    if (j < 524288) {
        int l = j >> 17, r = j & 131071;
        float v = (r < 65536) ? Wk[(size_t)(l * 2 + 1) * 65536 + r]
                              : Wv[(size_t)(l * 2 + 1) * 65536 + (r - 65536)];
        WkvB[j] = f2bf(v);
        return;
    }
    j -= 524288;
    if (j < 2048) {
        int l = j >> 9, r = j & 511;
        bkv[j] = (r < 256) ? bk[(l * 2 + 1) * 256 + r] : bv[(l * 2 + 1) * 256 + (r - 256)];
        return;
    }
    j -= 2048;
    if (j < 4096) { Wc1B[j] = f2bf(Wc1[j]); return; }
    j -= 4096;
    if (j < 8192) { Wc2B[j] = f2bf(Wc2[j]); return; }
    j -= 8192;
    if (j < 4096) { xmk[j] = 0u; return; }
    j -= 4096;
    if (j < 1572864) {
        int l = j / 393216;
        int r = j - l * 393216;
        int m = r >> 16, c = r & 65535;
        float v;
        if (m == 0)      v = Wq[(size_t)(l * 2 + 0) * 65536 + c];
        else if (m == 1) v = Wk[(size_t)(l * 2 + 0) * 65536 + c];
        else if (m == 2) v = Wv[(size_t)(l * 2 + 0) * 65536 + c];
        else if (m == 3) v = Wo[(size_t)(l * 2 + 0) * 65536 + c];
        else if (m == 4) v = Wq[(size_t)(l * 2 + 1) * 65536 + c];
        else             v = Wo[(size_t)(l * 2 + 1) * 65536 + c];
        WtB[j] = f2bf(v);
        return;
    }
    j -= 1572864;
    if (j < 524288) { Wff1B[j] = f2bf(Wff1[j]); return; }
    j -= 524288;
    if (j < 524288) { Wff2B[j] = f2bf(Wff2[j]); return; }
}

// ---------------------------------------------------------------- generic bf16 MFMA GEMM (encoder)
__global__ __launch_bounds__(256) void mfma_gemm_kernel(const unsigned short* __restrict__ A, size_t a_bstride,
                                                        const unsigned short* __restrict__ B, size_t b_bstride,
                                                        const float* __restrict__ bias, int bias_per_m,
                                                        void* __restrict__ C, size_t c_bstride, int c_rstride,
                                                        int K, int act, int out_bf16,
                                                        unsigned* __restrict__ xmk, int domax) {
    __shared__ unsigned short As[128][40];
    __shared__ unsigned short Bs[128][40];
    int m0 = blockIdx.x * 128, n0 = blockIdx.y * 128, b = blockIdx.z;
    int tid = threadIdx.x;
    int lane = tid & 63, wave = tid >> 6;
    int wr = wave >> 1, wc = wave & 1;
    int quad = lane >> 4, l16 = lane & 15;
    int r0 = tid >> 2, kc0 = (tid & 3) * 8;
    f32x4 acc[4][4] = {};
    const unsigned short* Ab = A + (size_t)b * a_bstride;
    const unsigned short* Bb = B + (size_t)b * b_bstride;
    for (int k0 = 0; k0 < K; k0 += 32) {
        uint4 a0 = *(const uint4*)(Ab + (size_t)(m0 + r0) * K + k0 + kc0);
        uint4 a1 = *(const uint4*)(Ab + (size_t)(m0 + r0 + 64) * K + k0 + kc0);
        uint4 b0 = *(const uint4*)(Bb + (size_t)(n0 + r0) * K + k0 + kc0);
        uint4 b1 = *(const uint4*)(Bb + (size_t)(n0 + r0 + 64) * K + k0 + kc0);
        __syncthreads();
        *(uint4*)&As[r0][kc0] = a0;
        *(uint4*)&As[r0 + 64][kc0] = a1;
        *(uint4*)&Bs[r0][kc0] = b0;
        *(uint4*)&Bs[r0 + 64][kc0] = b1;
        __syncthreads();
        bf16x8 af[4], bfv[4];
        #pragma unroll
        for (int i = 0; i < 4; ++i) af[i] = *(const bf16x8*)&As[wr * 64 + i * 16 + l16][quad * 8];
        #pragma unroll
        for (int j = 0; j < 4; ++j) bfv[j] = *(const bf16x8*)&Bs[wc * 64 + j * 16 + l16][quad * 8];
        #pragma unroll
        for (int i = 0; i < 4; ++i)
            #pragma unroll
            for (int j = 0; j < 4; ++j)
                acc[i][j] = __builtin_amdgcn_mfma_f32_16x16x32_bf16(af[i], bfv[j], acc[i][j], 0, 0, 0);
    }
    if (domax) {
        #pragma unroll
        for (int i = 0; i < 4; ++i) {
            #pragma unroll
            for (int r = 0; r < 4; ++r) {
                int m = m0 + wr * 64 + i * 16 + quad * 4 + r;
                float v = fmaxf(fmaxf(acc[i][0][r], acc[i][1][r]), fmaxf(acc[i][2][r], acc[i][3][r]));
                v += bias[m];
                #pragma unroll
                for (int off = 1; off <= 8; off <<= 1) v = fmaxf(v, __shfl_xor(v, off));
                if (l16 == 0) atomicMax(&xmk[(size_t)b * 512 + m], fmono(v));
            }
        }
        return;
    }
    #pragma unroll
    for (int i = 0; i < 4; ++i) {
        #pragma unroll
        for (int r = 0; r < 4; ++r) {
            int m = m0 + wr * 64 + i * 16 + quad * 4 + r;
            float bm = bias_per_m ? bias[m] : 0.f;
            #pragma unroll
            for (int j = 0; j < 4; ++j) {
                int n = n0 + wc * 64 + j * 16 + l16;
                float v = acc[i][j][r] + (bias_per_m ? bm : bias[n]);
                if (act) v = v > 0.f ? v : 0.2f * v;
                size_t off = (size_t)b * c_bstride + (size_t)m * c_rstride + n;
                if (out_bf16) ((unsigned short*)C)[off] = f2bf(v);
                else          ((float*)C)[off] = v;
            }
        }
    }
}

// ---------------------------------------------------------------- KV for ALL layers
__global__ __launch_bounds__(256) void mfma_kv_all_kernel(const unsigned short* __restrict__ A,
                                                          const unsigned short* __restrict__ W,
                                                          const float* __restrict__ bkv,
                                                          unsigned short* __restrict__ KVall) {
    __shared__ unsigned short As[128][40];
    __shared__ unsigned short Bs[128][40];
    int m0 = blockIdx.x * 128;
    int nb = blockIdx.y & 3, l = blockIdx.y >> 2;
    int n0 = nb * 128;
    int b = blockIdx.z;
    int tid = threadIdx.x;
    int lane = tid & 63, wave = tid >> 6;
    int wr = wave >> 1, wc = wave & 1;
    int quad = lane >> 4, l16 = lane & 15;
    int r0 = tid >> 2, kc0 = (tid & 3) * 8;
    f32x4 acc[4][4] = {};
    const unsigned short* Ab = A + (size_t)b * NP * 256;
    const unsigned short* Bb = W + (size_t)l * 131072;
    const float* bias = bkv + l * 512;
    for (int k0 = 0; k0 < 256; k0 += 32) {
        uint4 a0 = *(const uint4*)(Ab + (size_t)(m0 + r0) * 256 + k0 + kc0);
        uint4 a1 = *(const uint4*)(Ab + (size_t)(m0 + r0 + 64) * 256 + k0 + kc0);
        uint4 b0 = *(const uint4*)(Bb + (size_t)(n0 + r0) * 256 + k0 + kc0);
        uint4 b1 = *(const uint4*)(Bb + (size_t)(n0 + r0 + 64) * 256 + k0 + kc0);
        __syncthreads();
        *(uint4*)&As[r0][kc0] = a0;
        *(uint4*)&As[r0 + 64][kc0] = a1;
        *(uint4*)&Bs[r0][kc0] = b0;
        *(uint4*)&Bs[r0 + 64][kc0] = b1;
        __syncthreads();
        bf16x8 af[4], bfv[4];
        #pragma unroll
        for (int i = 0; i < 4; ++i) af[i] = *(const bf16x8*)&As[wr * 64 + i * 16 + l16][quad * 8];
        #pragma unroll
        for (int j = 0; j < 4; ++j) bfv[j] = *(const bf16x8*)&Bs[wc * 64 + j * 16 + l16][quad * 8];
        #pragma unroll
        for (int i = 0; i < 4; ++i)
            #pragma unroll
            for (int j = 0; j < 4; ++j)
                acc[i][j] = __builtin_amdgcn_mfma_f32_16x16x32_bf16(af[i], bfv[j], acc[i][j], 0, 0, 0);
    }
    unsigned short* Cb = KVall + ((size_t)l * BN + b) * NP * 512;
    #pragma unroll
    for (int i = 0; i < 4; ++i) {
        #pragma unroll
        for (int r = 0; r < 4; ++r) {
            int m = m0 + wr * 64 + i * 16 + quad * 4 + r;
            #pragma unroll
            for (int j = 0; j < 4; ++j) {
                int n = n0 + wc * 64 + j * 16 + l16;
                Cb[(size_t)m * 512 + n] = f2bf(acc[i][j][r] + bias[n]);
            }
        }
    }
}

// ---------------------------------------------------------------- q0 row + fold layer-0 QKV projection
__global__ __launch_bounds__(256) void pc_kernel(const unsigned* __restrict__ xmk, const float* __restrict__ Wpc,
                                                 const float* __restrict__ bpc,
                                                 const unsigned short* __restrict__ Wqkv,
                                                 const float* __restrict__ bq0, const float* __restrict__ bk0,
                                                 const float* __restrict__ bv0,
                                                 float* __restrict__ q, float* __restrict__ Qs,
                                                 float* __restrict__ Ks, float* __restrict__ Vs) {
    int row = blockIdx.x, tid = threadIdx.x;
    int id = row * 256 + tid;
    int b = row >> 3, i = row & 7;
    // XCD-sliced prefetch: Wqkv = 6144 lines, this XCD's 768-line slice (3 loads/thread)
    int xcd = xcc_id();
    float pf = 0.f;
    {
        const float* p3 = (const float*)Wqkv;
        #pragma unroll
        for (int t = 0; t < 3; ++t) pf += p3[(size_t)(xcd * 768 + t * 256 + tid) << 4];
    }
    const unsigned* xr = xmk + b * 512 + i * 64;
    const float* w = Wpc + (size_t)tid * 64;
    float acc = bpc[tid];
    #pragma unroll
    for (int e = 0; e < 64; ++e) acc += funmono(xr[e]) * w[e];
    float qv = acc > 0.f ? acc : 0.2f * acc;
    q[id] = qv;
    __shared__ __align__(16) float a[256];
    a[tid] = qv;
    __syncthreads();
    asm volatile("" :: "v"(pf));
    Qs[id] = bq0[tid] + gemv_dot(Wqkv + (size_t)tid * 256, a, 32);
    Ks[id] = bk0[tid] + gemv_dot(Wqkv + 65536 + (size_t)tid * 256, a, 32);
    Vs[id] = bv0[tid] + gemv_dot(Wqkv + 131072 + (size_t)tid * 256, a, 32);
}

// ---------------------------------------------------------------- memB = bf16(act(x @ Wpi.T + bpi))
__global__ __launch_bounds__(256) void mem_kernel(const float* __restrict__ x, const float* __restrict__ Wpi,
                                                  const float* __restrict__ bpi, unsigned short* __restrict__ memB) {
    size_t id = (size_t)blockIdx.x * 256 + threadIdx.x;
    int p = (int)(id & 255);
    size_t pt = id >> 8;
    float x0 = x[pt * 3 + 0], x1 = x[pt * 3 + 1], x2 = x[pt * 3 + 2];
    float v = bpi[p] + x0 * Wpi[p * 3 + 0] + x1 * Wpi[p * 3 + 1] + x2 * Wpi[p * 3 + 2];
    v = v > 0.f ? v : 0.2f * v;
    memB[id] = f2bf(v);
}

// ---------------------------------------------------------------- self-attn + O-proj + res + LN + cross-Q-proj (1024 thr)
__global__ __launch_bounds__(1024) void attn_ln_kernel(const float* __restrict__ Qs, const float* __restrict__ Ks,
                                                       const float* __restrict__ Vs,
                                                       const unsigned short* __restrict__ WoB,
                                                       const float* __restrict__ bo, const float* __restrict__ res,
                                                       const float* __restrict__ g, const float* __restrict__ bt,
                                                       const unsigned short* __restrict__ Wq1B,
                                                       const float* __restrict__ bq1,
                                                       float* __restrict__ out, float* __restrict__ Qc) {
    int row = blockIdx.x, tid = threadIdx.x;
    int b = row >> 3;
    __shared__ float Kl[2048], Vl[2048];
    __shared__ __align__(16) float qr[256];
    __shared__ float sc[64];
    __shared__ __align__(16) float r[256];
    __shared__ __align__(16) float aout[256];
    __shared__ float red[1024];
    // XCD-sliced prefetch: Wo + Wq1, each 2048 lines -> 256-line slice per XCD
    int xcd = xcc_id();
    float pf = 0.f;
    if (tid < 256) {
        pf += ((const float*)WoB)[(size_t)(xcd * 256 + tid) << 4];
        pf += ((const float*)Wq1B)[(size_t)(xcd * 256 + tid) << 4];
    }
    for (int t = tid; t < 2048; t += 1024) {
        Kl[t] = Ks[(size_t)b * 2048 + t];
        Vl[t] = Vs[(size_t)b * 2048 + t];
    }
    if (tid < 256) qr[tid] = Qs[(size_t)row * 256 + tid];
    __syncthreads();
    const float scale = 0.17677669529663687f;
    {
        int pair = tid >> 4, part = tid & 15;
        int h = pair >> 3, k = pair & 7;
        int d = part * 2;
        float dot = qr[h * 32 + d] * Kl[k * 256 + h * 32 + d]
                  + qr[h * 32 + d + 1] * Kl[k * 256 + h * 32 + d + 1];
        dot += __shfl_xor(dot, 1);
        dot += __shfl_xor(dot, 2);
        dot += __shfl_xor(dot, 4);
        dot += __shfl_xor(dot, 8);
        if (part == 0) sc[pair] = dot * scale;
    }
    __syncthreads();
    if (tid < 64) {
        float v = sc[tid];
        float m = v;
        #pragma unroll
        for (int off = 1; off < 8; off <<= 1) m = fmaxf(m, __shfl_xor(m, off));
        float e = __expf(v - m);
        float s = e;
        #pragma unroll
        for (int off = 1; off < 8; off <<= 1) s += __shfl_xor(s, off);
        sc[tid] = e / s;
    }
    __syncthreads();
    if (tid < 256) {
        int h = tid >> 5;
        float acc = 0.f;
        #pragma unroll
        for (int k = 0; k < 8; ++k) acc += sc[h * 8 + k] * Vl[k * 256 + tid];
        r[tid] = acc;
    }
    __syncthreads();
    asm volatile("" :: "v"(pf));
    // O-proj: 4 threads/output, 64-elem partials
    int o4 = tid >> 2, p4 = tid & 3;
    float v;
    {
        float acc = gemv_dot(WoB + (size_t)o4 * 256 + p4 * 64, r + p4 * 64, 8);
        acc += __shfl_xor(acc, 1);
        acc += __shfl_xor(acc, 2);
        v = (p4 == 0) ? (bo[o4] + acc + res[(size_t)row * 256 + o4]) : 0.f;
    }
    red[tid] = v; __syncthreads();
    for (int s = 512; s; s >>= 1) { if (tid < s) red[tid] += red[tid + s]; __syncthreads(); }
    float mean = red[0] * (1.0f / 256.0f);
    __syncthreads();
    float dv = (p4 == 0) ? v - mean : 0.f;
    red[tid] = dv * dv; __syncthreads();
    for (int s = 512; s; s >>= 1) { if (tid < s) red[tid] += red[tid + s]; __syncthreads(); }
    float var = red[0] * (1.0f / 256.0f);
    if (p4 == 0) {
        float oln = g[o4] * dv * rsqrtf(var + 1e-5f) + bt[o4];
        out[(size_t)row * 256 + o4] = oln;
        aout[o4] = oln;
    }
    __syncthreads();
    {
        float qacc = gemv_dot(Wq1B + (size_t)o4 * 256 + p4 * 64, aout + p4 * 64, 8);
        qacc += __shfl_xor(qacc, 1);
        qacc += __shfl_xor(qacc, 2);
        if (p4 == 0) Qc[(size_t)row * 256 + o4] = bq1[o4] + qacc;
    }
}

// ---------------------------------------------------------------- cross-attn pass 1: 16 key-blocks of 128
__global__ __launch_bounds__(256) void ca_part_kernel(const float* __restrict__ Qc,
                                                      const unsigned short* __restrict__ KVl,
                                                      float* __restrict__ part) {
    int kb = blockIdx.x, h = blockIdx.y, b = blockIdx.z;
    int tid = threadIdx.x;
    __shared__ float q[8][32];
    __shared__ __align__(16) float S[8][128];
    __shared__ float om[8][8][32];
    const float scale = 0.17677669529663687f;
    {
        int i = tid >> 5, d = tid & 31;
        q[i][d] = Qc[(size_t)(b * 8 + i) * 256 + h * 32 + d];
    }
    __syncthreads();
    {
        int kk = tid & 127, half = tid >> 7;
        int k = kb * 128 + kk;
        const unsigned short* kp = KVl + ((size_t)b * NP + k) * 512 + h * 32;
        float kd[32];
        #pragma unroll
        for (int u = 0; u < 4; ++u) {
            uint4 raw = *(const uint4*)(kp + u * 8);
            unsigned w0 = raw.x, w1 = raw.y, w2 = raw.z, w3 = raw.w;
            kd[u * 8 + 0] = __uint_as_float(w0 << 16); kd[u * 8 + 1] = __uint_as_float(w0 & 0xFFFF0000u);
            kd[u * 8 + 2] = __uint_as_float(w1 << 16); kd[u * 8 + 3] = __uint_as_float(w1 & 0xFFFF0000u);
            kd[u * 8 + 4] = __uint_as_float(w2 << 16); kd[u * 8 + 5] = __uint_as_float(w2 & 0xFFFF0000u);
            kd[u * 8 + 6] = __uint_as_float(w3 << 16); kd[u * 8 + 7] = __uint_as_float(w3 & 0xFFFF0000u);
        }
        #pragma unroll
        for (int i = 0; i < 4; ++i) {
            int ri = half * 4 + i;
            float dot = 0.f;
            #pragma unroll
            for (int d = 0; d < 32; ++d) dot += q[ri][d] * kd[d];
            S[ri][kk] = dot * scale;
        }
    }
    __syncthreads();
    float* pout = part + (((size_t)(b * NH + h)) * 16 + kb) * 288;
    {
        int i = tid >> 5, l32 = tid & 31;
        float m = -3.4e38f;
        #pragma unroll
        for (int t = 0; t < 4; ++t) m = fmaxf(m, S[i][l32 + t * 32]);
        #pragma unroll
        for (int off = 16; off; off >>= 1) m = fmaxf(m, __shfl_xor(m, off));
        float s = 0.f;
        #pragma unroll
        for (int t = 0; t < 4; ++t) {
            float e = __expf(S[i][l32 + t * 32] - m);
            S[i][l32 + t * 32] = e;
            s += e;
        }
        #pragma unroll
        for (int off = 16; off; off >>= 1) s += __shfl_xor(s, off);
        if (l32 == 0) { pout[i] = m; pout[8 + i] = s; }
    }
    __syncthreads();
    {
        int d = tid & 31, grp = tid >> 5;
        const unsigned short* Vb = KVl + ((size_t)b * NP + kb * 128) * 512 + 256 + h * 32 + d;
        float acc[8] = {};
        #pragma unroll 4
        for (int t = 0; t < 16; ++t) {
            int kk = grp * 16 + t;
            float v = bf2f(Vb[(size_t)kk * 512]);
            #pragma unroll
            for (int i = 0; i < 8; ++i) acc[i] += S[i][kk] * v;
        }
        #pragma unroll
        for (int i = 0; i < 8; ++i) om[grp][i][d] = acc[i];
    }
    __syncthreads();
    {
        int i = tid >> 5, d = tid & 31;
        float sum = 0.f;
        #pragma unroll
        for (int g = 0; g < 8; ++g) sum += om[g][i][d];
        pout[16 + i * 32 + d] = sum;
    }
}

// ---------------------------------------------------------------- combine + O-proj + LN + FF + LN [+ next-layer QKV | final LN+Wcm] (1024 thr)
__global__ __launch_bounds__(1024) void combine_ff_kernel(const float* __restrict__ part,
                                                          const unsigned short* __restrict__ WoB,
                                                          const float* __restrict__ bo, const float* __restrict__ res,
                                                          const float* __restrict__ g2, const float* __restrict__ b2t,
                                                          const unsigned short* __restrict__ W1B,
                                                          const float* __restrict__ b1,
                                                          const unsigned short* __restrict__ W2B,
                                                          const float* __restrict__ b2,
                                                          const float* __restrict__ g3, const float* __restrict__ b3t,
                                                          float* __restrict__ out,
                                                          int is_last, const float* __restrict__ lnfg,
                                                          const float* __restrict__ lnfb, const float* __restrict__ Wcm,
                                                          const float* __restrict__ bcm, float* __restrict__ finout,
                                                          const unsigned short* __restrict__ Wqkvn,
                                                          const float* __restrict__ bqn, const float* __restrict__ bkn,
                                                          const float* __restrict__ bvn,
                                                          float* __restrict__ Qs, float* __restrict__ Ks,
                                                          float* __restrict__ Vs) {
    int row = blockIdx.x, tid = threadIdx.x;
    int b = row >> 3, i = row & 7;
    __shared__ __align__(16) float r[256];
    __shared__ __align__(16) float a[256];
    __shared__ __align__(16) float hbuf[512];
    __shared__ float red[1024];
    // XCD-sliced prefetch: each XCD pulls only its 1/8 of each panel (disjoint lines)
    int xcd = xcc_id();
    float pf = 0.f;
    {
        // part (own batch): 2304 lines -> 288-line slice
        const float* pb0 = part + (size_t)b * NH * 16 * 288;
        if (tid < 288) pf += pb0[(size_t)(xcd * 288 + tid) << 4];
        // Wo: 2048 lines -> 256; W1/W2: 4096 -> 512 each
        if (tid < 256) pf += ((const float*)WoB)[(size_t)(xcd * 256 + tid) << 4];
        if (tid < 512) pf += ((const float*)W1B)[(size_t)(xcd * 512 + tid) << 4];
        if (tid < 512) pf += ((const float*)W2B)[(size_t)(xcd * 512 + tid) << 4];
        if (Wqkvn && tid < 768) pf += ((const float*)Wqkvn)[(size_t)(xcd * 768 + tid) << 4];
    }
    // phase 1: combine cross-attn partials (4 threads per (h,d), each 4 key-blocks)
    {
        int h = tid >> 7, rem = tid & 127, d = rem >> 2, g = rem & 3;
        const float* pb = part + (size_t)(b * NH + h) * 16 * 288;
        float M = -3.4e38f;
        #pragma unroll
        for (int t = 0; t < 4; ++t) M = fmaxf(M, pb[(g * 4 + t) * 288 + i]);
        M = fmaxf(M, __shfl_xor(M, 1));
        M = fmaxf(M, __shfl_xor(M, 2));
        float L = 0.f, O = 0.f;
        #pragma unroll
        for (int t = 0; t < 4; ++t) {
            int kb = g * 4 + t;
            float w = __expf(pb[kb * 288 + i] - M);
            L += pb[kb * 288 + 8 + i] * w;
            O += pb[kb * 288 + 16 + i * 32 + d] * w;
        }
        L += __shfl_xor(L, 1); L += __shfl_xor(L, 2);
        O += __shfl_xor(O, 1); O += __shfl_xor(O, 2);
        if (g == 0) r[h * 32 + d] = O / L;
    }
    __syncthreads();
    asm volatile("" :: "v"(pf));
    int o4 = tid >> 2, p4 = tid & 3;
    // phase 2: O-proj (4 thr/out) + residual + LN
    float v;
    {
        float acc = gemv_dot(WoB + (size_t)o4 * 256 + p4 * 64, r + p4 * 64, 8);
        acc += __shfl_xor(acc, 1);
        acc += __shfl_xor(acc, 2);
        v = (p4 == 0) ? (bo[o4] + acc + res[(size_t)row * 256 + o4]) : 0.f;
    }
    red[tid] = v; __syncthreads();
    for (int s = 512; s; s >>= 1) { if (tid < s) red[tid] += red[tid + s]; __syncthreads(); }
    float mean = red[0] * (1.0f / 256.0f);
    __syncthreads();
    float dv = (p4 == 0) ? v - mean : 0.f;
    red[tid] = dv * dv; __syncthreads();
    for (int s = 512; s; s >>= 1) { if (tid < s) red[tid] += red[tid + s]; __syncthreads(); }
    float var = red[0] * (1.0f / 256.0f);
    if (p4 == 0) a[o4] = g2[o4] * dv * rsqrtf(var + 1e-5f) + b2t[o4];
    __syncthreads();
    // phase 3: FF1 (2 thr/out, 128-elem partials)
    {
        int o = tid >> 1, p = tid & 1;
        float acc = gemv_dot(W1B + (size_t)o * 256 + p * 128, a + p * 128, 16);
        acc += __shfl_xor(acc, 1);
        if (p == 0) { float t = b1[o] + acc; hbuf[o] = t > 0.f ? t : 0.2f * t; }
    }
    __syncthreads();
    // phase 4: FF2 (4 thr/out, K=512) + residual + LN
    float vF;
    {
        float acc = gemv_dot(W2B + (size_t)o4 * 512 + p4 * 128, hbuf + p4 * 128, 16);
        acc += __shfl_xor(acc, 1);
        acc += __shfl_xor(acc, 2);
        vF = (p4 == 0) ? (b2[o4] + acc + a[o4]) : 0.f;
    }
    red[tid] = vF; __syncthreads();
    for (int s = 512; s; s >>= 1) { if (tid < s) red[tid] += red[tid + s]; __syncthreads(); }
    float mean2 = red[0] * (1.0f / 256.0f);
    __syncthreads();
    float dv2 = (p4 == 0) ? vF - mean2 : 0.f;
    red[tid] = dv2 * dv2; __syncthreads();
    for (int s = 512; s; s >>= 1) { if (tid < s) red[tid] += red[tid + s]; __syncthreads(); }
    float var2 = red[0] * (1.0f / 256.0f);
    float tln = 0.f;
    if (p4 == 0) {
        tln = g3[o4] * dv2 * rsqrtf(var2 + 1e-5f) + b3t[o4];
        r[o4] = tln;
    }
    __syncthreads();
    if (!is_last) {
        if (p4 == 0) out[(size_t)row * 256 + o4] = tln;
        // next-layer QKV from tln row in r[]: 768 full-dot threads
        if (tid < 768) {
            int which = tid >> 8, o = tid & 255;
            float acc = gemv_dot(Wqkvn + (size_t)which * 65536 + (size_t)o * 256, r, 32);
            float bb = (which == 0) ? bqn[o] : (which == 1) ? bkn[o] : bvn[o];
            float* dst = (which == 0) ? Qs : (which == 1) ? Ks : Vs;
            dst[(size_t)row * 256 + o] = bb + acc;
        }
        return;
    }
    // final LN + Wcm
    float tf = (tid < 256) ? r[tid] : 0.f;
    red[tid] = tf; __syncthreads();
    for (int s = 512; s; s >>= 1) { if (tid < s) red[tid] += red[tid + s]; __syncthreads(); }
    float mean3 = red[0] * (1.0f / 256.0f);
    __syncthreads();
    float d3 = (tid < 256) ? tf - mean3 : 0.f;
    red[tid] = d3 * d3; __syncthreads();
    for (int s = 512; s; s >>= 1) { if (tid < s) red[tid] += red[tid + s]; __syncthreads(); }
    float var3 = red[0] * (1.0f / 256.0f);
    if (tid < 256) a[tid] = lnfg[tid] * d3 * rsqrtf(var3 + 1e-5f) + lnfb[tid];
    __syncthreads();
    if (tid < 64) {
        const float4* w4 = (const float4*)(Wcm + (size_t)tid * 256);
        const float4* a4 = (const float4*)a;
        float acc = bcm[tid];
        #pragma unroll 8
        for (int c = 0; c < 64; ++c) {
            float4 av = a4[c], wv = w4[c];
            acc += av.x * wv.x + av.y * wv.y + av.z * wv.z + av.w * wv.w;
        }
        finout[(size_t)b * 512 + i * 64 + tid] = acc;
    }
}

// ================================================================ host
extern "C" void kernel_launch(void* const* d_in, const int* in_sizes, int n_in,
                              void* d_out, int out_size, void* d_ws, size_t ws_size,
                              hipStream_t stream) {
    const float* x    = (const float*)d_in[0];
    const float* Wec  = (const float*)d_in[1];
    const float* bec  = (const float*)d_in[2];
    const float* Wc1  = (const float*)d_in[3];
    const float* bc1  = (const float*)d_in[4];
    const float* Wc2  = (const float*)d_in[5];
    const float* bc2  = (const float*)d_in[6];
    const float* Wc3  = (const float*)d_in[7];
    const float* bc3  = (const float*)d_in[8];
    const float* Wf   = (const float*)d_in[9];
    const float* bf   = (const float*)d_in[10];
    const float* Wpc  = (const float*)d_in[11];
    const float* bpc  = (const float*)d_in[12];
    const float* Wpi  = (const float*)d_in[13];
    const float* bpi  = (const float*)d_in[14];
    const float* Wq   = (const float*)d_in[15];
    const float* bq   = (const float*)d_in[16];
    const float* Wk   = (const float*)d_in[17];
    const float* bk   = (const float*)d_in[18];
    const float* Wv   = (const float*)d_in[19];
    const float* bv   = (const float*)d_in[20];
    const float* Wo   = (const float*)d_in[21];
    const float* bo   = (const float*)d_in[22];
    const float* ln1g = (const float*)d_in[23];
    const float* ln1b = (const float*)d_in[24];
    const float* ln2g = (const float*)d_in[25];
    const float* ln2b = (const float*)d_in[26];
    const float* Wff1 = (const float*)d_in[27];
    const float* bff1 = (const float*)d_in[28];
    const float* Wff2 = (const float*)d_in[29];
    const float* bff2 = (const float*)d_in[30];
    const float* ln3g = (const float*)d_in[31];
    const float* ln3b = (const float*)d_in[32];
    const float* lnfg = (const float*)d_in[33];
    const float* lnfb = (const float*)d_in[34];
    const float* Wcm  = (const float*)d_in[35];
    const float* bcm  = (const float*)d_in[36];
    float* out = (float*)d_out;

    float* ws = (float*)d_ws;
    size_t off = 0;
    auto alloc = [&](size_t n) { float* p = ws + off; off += (n + 3) & ~(size_t)3; return p; };
    int*            idx   = (int*)alloc((size_t)BN * NP * KNN);
    unsigned short* hcatT = (unsigned short*)alloc((size_t)BN * NP * 512 / 2);
    unsigned short* poolT = (unsigned short*)alloc((size_t)BN * NP * 128 / 2);
    unsigned short* WfB   = (unsigned short*)alloc(262144 / 2);
    unsigned short* Wc1B  = (unsigned short*)alloc(4096 / 2);
    unsigned short* Wc2B  = (unsigned short*)alloc(8192 / 2);
    unsigned short* Wc3B  = (unsigned short*)alloc(32768 / 2);
    unsigned short* WkvB  = (unsigned short*)alloc(524288 / 2);
    float*          bkv   = alloc(2048);
    unsigned short* memB  = (unsigned short*)alloc((size_t)BN * NP * 256 / 2);
    unsigned short* KVall = (unsigned short*)alloc((size_t)NL * BN * NP * 512 / 2);
    unsigned*       xmk   = (unsigned*)alloc((size_t)BN * 512);
    unsigned short* WtB   = (unsigned short*)alloc(1572864 / 2);
    unsigned short* Wff1B = (unsigned short*)alloc(524288 / 2);
    unsigned short* Wff2B = (unsigned short*)alloc(524288 / 2);
    float*          qa    = alloc((size_t)BN * 8 * 256);
    float*          qb    = alloc((size_t)BN * 8 * 256);
    float*          Qs    = alloc((size_t)BN * 8 * 256);
    float*          Ks    = alloc((size_t)BN * 8 * 256);
    float*          Vs    = alloc((size_t)BN * 8 * 256);
    float*          Qc    = alloc((size_t)BN * 8 * 256);
    float*          part  = alloc((size_t)BN * NH * 16 * 288);

    // ---- weight casts + xm-key init (no deps) ----
    wcast_kernel<<<13512, 256, 0, stream>>>(Wf, Wc3, Wk, Wv, bk, bv, Wc1, Wc2, Wq, Wo, Wff1, Wff2,
                                            WfB, Wc3B, WkvB, bkv, Wc1B, Wc2B, WtB, Wff1B, Wff2B, xmk);

    // ---- point-cloud encoder (all-bf16 [pt][ch] chain) ----
    knn_kernel<<<BN * NP / 4, 256, 0, stream>>>(x, idx);
    edge_conv_kernel<<<BN * NP / 4, 256, 0, stream>>>(x, idx, Wec, bec, hcatT);

    pool_bf16_kernel<<<BN * NP / 4, 256, 0, stream>>>(hcatT, 0, idx, poolT, 64);
    mfma_conv64_kernel<<<dim3(NP / 128, 1, BN), 256, 0, stream>>>(poolT, Wc1B, bc1, hcatT, 64);
    pool_bf16_kernel<<<BN * NP / 4, 256, 0, stream>>>(hcatT, 64, idx, poolT, 64);
    mfma_gemm_kernel<<<dim3(NP / 128, 1, BN), 256, 0, stream>>>(poolT, (size_t)NP * 64, Wc2B, 0,
                                                                bc2, 0, (void*)(hcatT + 128), (size_t)NP * 512, 512,
                                                                64, 1, 1, nullptr, 0);
    pool_bf16_kernel<<<BN * NP / 4, 256, 0, stream>>>(hcatT, 128, idx, poolT, 128);
    mfma_gemm_kernel<<<dim3(NP / 128, 2, BN), 256, 0, stream>>>(poolT, (size_t)NP * 128, Wc3B, 0,
                                                                bc3, 0, (void*)(hcatT + 256), (size_t)NP * 512, 512,
                                                                128, 1, 1, nullptr, 0);
    mfma_gemm_kernel<<<dim3(4, NP / 128, BN), 256, 0, stream>>>(WfB, 0, hcatT, (size_t)NP * 512,
                                                                bf, 1, nullptr, 0, 0,
                                                                512, 0, 0, xmk, 1);
    pc_kernel<<<BN * 8, 256, 0, stream>>>(xmk, Wpc, bpc, WtB, bq, bk, bv, qa, Qs, Ks, Vs);
    mem_kernel<<<BN * NP, 256, 0, stream>>>(x, Wpi, bpi, memB);
    mfma_kv_all_kernel<<<dim3(NP / 128, 4 * NL, BN), 256, 0, stream>>>(memB, WkvB, bkv, KVall);

    // ---- transformer layers (3 launches/layer; QKV folded into producer) ----
    for (int l = 0; l < NL; ++l) {
        const unsigned short* Wl = WtB + (size_t)l * 393216;
        const float* bo0 = bo + (l * 2 + 0) * 256;
        const float* bq1 = bq + (l * 2 + 1) * 256;
        const float* bo1 = bo + (l * 2 + 1) * 256;
        int last = (l == NL - 1);

        attn_ln_kernel<<<BN * 8, 1024, 0, stream>>>(Qs, Ks, Vs, Wl + 3 * 65536, bo0, qa,
                                                    ln1g + l * 256, ln1b + l * 256, Wl + 4 * 65536, bq1, qb, Qc);
        ca_part_kernel<<<dim3(16, NH, BN), 256, 0, stream>>>(Qc, KVall + (size_t)l * BN * NP * 512, part);
        combine_ff_kernel<<<BN * 8, 1024, 0, stream>>>(part, Wl + 5 * 65536, bo1, qb,
                                                       ln2g + l * 256, ln2b + l * 256,
                                                       Wff1B + (size_t)l * 131072, bff1 + l * 512,
                                                       Wff2B + (size_t)l * 131072, bff2 + l * 256,
                                                       ln3g + l * 256, ln3b + l * 256, qa,
                                                       last, lnfg, lnfb, Wcm, bcm, out,
                                                       last ? nullptr : WtB + (size_t)(l + 1) * 393216,
                                                       bq + ((l + 1) * 2) * 256, bk + ((l + 1) * 2) * 256,
                                                       bv + ((l + 1) * 2) * 256,
                                                       Qs, Ks, Vs);
    }

    (void)in_sizes; (void)n_in; (void)out_size; (void)ws_size;
}

// Round 10
// 559.171 us; speedup vs baseline: 1.0557x; 1.0032x over previous
//
#include <hip/hip_runtime.h>
#include <math.h>

#define BN 8
#define NP 2048
#define KNN 16
#define NL 4
#define NH 8

typedef __attribute__((ext_vector_type(8))) short bf16x8;
typedef __attribute__((ext_vector_type(4))) float f32x4;

__device__ __forceinline__ unsigned short f2bf(float f) {
    unsigned u = __float_as_uint(f);
    unsigned r = (u + 0x7FFFu + ((u >> 16) & 1u)) >> 16;
    return (unsigned short)r;
}
__device__ __forceinline__ float bf2f(unsigned short s) {
    return __uint_as_float(((unsigned)s) << 16);
}
__device__ __forceinline__ unsigned fmono(float f) {
    unsigned u = __float_as_uint(f);
    return (u & 0x80000000u) ? ~u : (u | 0x80000000u);
}
__device__ __forceinline__ float funmono(unsigned k) {
    return (k & 0x80000000u) ? __uint_as_float(k ^ 0x80000000u) : __uint_as_float(~k);
}

// dot of one bf16 weight row (K8*8 elements) against fp32 vector in LDS.
// 4 independent accumulator chains so the compiler keeps >=4 loads in flight.
__device__ __forceinline__ float gemv_dot(const unsigned short* __restrict__ wrow, const float* sm, int K8) {
    const uint4* w8 = (const uint4*)wrow;
    const float4* r4 = (const float4*)sm;
    float a0 = 0.f, a1 = 0.f, a2 = 0.f, a3 = 0.f;
    #pragma unroll 8
    for (int c = 0; c < K8; ++c) {
        uint4 wv = w8[c];
        float4 x0 = r4[c * 2], x1 = r4[c * 2 + 1];
        a0 += x0.x * __uint_as_float(wv.x << 16) + x0.y * __uint_as_float(wv.x & 0xFFFF0000u);
        a1 += x0.z * __uint_as_float(wv.y << 16) + x0.w * __uint_as_float(wv.y & 0xFFFF0000u);
        a2 += x1.x * __uint_as_float(wv.z << 16) + x1.y * __uint_as_float(wv.z & 0xFFFF0000u);
        a3 += x1.z * __uint_as_float(wv.w << 16) + x1.w * __uint_as_float(wv.w & 0xFFFF0000u);
    }
    return (a0 + a1) + (a2 + a3);
}

// ---------------------------------------------------------------- knn v7: pivot-filter select (verified R2)
__device__ __forceinline__ unsigned long long shflx_u64(unsigned long long v, int j) {
    int lo = __shfl_xor((int)(unsigned)(v & 0xFFFFFFFFull), j);
    int hi = __shfl_xor((int)(unsigned)(v >> 32), j);
    return ((unsigned long long)(unsigned)hi << 32) | (unsigned)lo;
}

__device__ __forceinline__ unsigned sort64_u32(unsigned v, int lane) {
    #pragma unroll
    for (int k = 2; k <= 64; k <<= 1) {
        #pragma unroll
        for (int j = k >> 1; j > 0; j >>= 1) {
            unsigned o = (unsigned)__shfl_xor((int)v, j);
            bool up = ((lane & k) == 0);
            bool lower = ((lane & j) == 0);
            unsigned mn = v < o ? v : o;
            unsigned mx = v < o ? o : v;
            v = (up == lower) ? mn : mx;
        }
    }
    return v;
}

__device__ __forceinline__ unsigned long long sort64_u64(unsigned long long v, int lane) {
    #pragma unroll
    for (int k = 2; k <= 64; k <<= 1) {
        #pragma unroll
        for (int j = k >> 1; j > 0; j >>= 1) {
            unsigned long long o = shflx_u64(v, j);
            bool up = ((lane & k) == 0);
            bool lower = ((lane & j) == 0);
            unsigned long long mn = v < o ? v : o;
            unsigned long long mx = v < o ? o : v;
            v = (up == lower) ? mn : mx;
        }
    }
    return v;
}

__global__ __launch_bounds__(256) void knn_kernel(const float* __restrict__ x, int* __restrict__ idxout) {
    __shared__ unsigned long long cand[4][64];
    int tid = threadIdx.x;
    int wv = tid >> 6, lane = tid & 63;
    int p = blockIdx.x * 4 + wv;
    int b = p >> 11, n = p & 2047;
    const float* xb = x + (size_t)b * NP * 3;
    float cx = xb[n * 3 + 0], cy = xb[n * 3 + 1], cz = xb[n * 3 + 2];
    float xn = cx * cx + cy * cy + cz * cz;
    unsigned key[32];
    unsigned lmax = 0u;
    #pragma unroll
    for (int t = 0; t < 32; ++t) {
        int m = (t << 6) | lane;
        float mx = xb[m * 3 + 0], my = xb[m * 3 + 1], mz = xb[m * 3 + 2];
        float xxm = mx * mx + my * my + mz * mz;
        float inner = cx * mx + cy * my + cz * mz;
        float dd = 2.0f * inner - xn - xxm;
        unsigned u = __float_as_uint(dd);
        u = (u & 0x80000000u) ? ~u : (u | 0x80000000u);
        key[t] = u;
        lmax = lmax > u ? lmax : u;
    }
    unsigned sorted = sort64_u32(lmax, lane);
    unsigned S = (unsigned)__shfl((int)sorted, 48);
    int c = 0;
    #pragma unroll
    for (int t = 0; t < 32; ++t) c += (key[t] >= S) ? 1 : 0;
    int inc = c;
    #pragma unroll
    for (int d = 1; d < 64; d <<= 1) {
        int tsh = __shfl_up(inc, d);
        if (lane >= d) inc += tsh;
    }
    int C = __shfl(inc, 63);
    int* op = idxout + (size_t)p * KNN;
    if (C <= 64) {
        int off = inc - c;
        #pragma unroll
        for (int t = 0; t < 32; ++t) {
            if (key[t] >= S) {
                int m = (t << 6) | lane;
                cand[wv][off++] = ((unsigned long long)key[t] << 16) | (unsigned)(2047 - m);
            }
        }
        asm volatile("s_waitcnt lgkmcnt(0)" ::: "memory");
        unsigned long long ck = (lane < C) ? cand[wv][lane] : 0ull;
        ck = sort64_u64(ck, lane);
        if (lane >= 48) op[63 - lane] = 2047 - (int)(unsigned)(ck & 0xFFFFull);
    } else {
        unsigned taken = 0u;
        for (int r = 0; r < KNN; ++r) {
            unsigned long long best = 0ull;
            #pragma unroll
            for (int t = 0; t < 32; ++t) {
                if (!((taken >> t) & 1u)) {
                    int m = (t << 6) | lane;
                    unsigned long long ck = ((unsigned long long)key[t] << 16) | (unsigned)(2047 - m);
                    if (ck > best) best = ck;
                }
            }
            #pragma unroll
            for (int d = 1; d < 64; d <<= 1) {
                unsigned long long o = shflx_u64(best, d);
                if (o > best) best = o;
            }
            int m = 2047 - (int)(unsigned)(best & 0xFFFFull);
            if (lane == 0) op[r] = m;
            if ((m & 63) == lane) taken |= 1u << (m >> 6);
        }
    }
}

// ---------------------------------------------------------------- edge conv + max over k -> hcatT[:,0:64] bf16
__global__ __launch_bounds__(256) void edge_conv_kernel(const float* __restrict__ x, const int* __restrict__ idx,
                                                        const float* __restrict__ Wec, const float* __restrict__ bec,
                                                        unsigned short* __restrict__ hcatT) {
    int tid = threadIdx.x;
    int g = tid >> 6, o = tid & 63;
    int p = blockIdx.x * 4 + g;
    int b = p >> 11;
    __shared__ float nb[4][KNN][3];
    __shared__ float ctr[4][3];
    if (o < KNN) {
        int j = idx[(size_t)p * KNN + o];
        const float* xp = x + ((size_t)b * NP + j) * 3;
        nb[g][o][0] = xp[0]; nb[g][o][1] = xp[1]; nb[g][o][2] = xp[2];
    }
    if (o >= KNN && o < KNN + 3) ctr[g][o - KNN] = x[(size_t)p * 3 + (o - KNN)];
    __syncthreads();
    float w0 = Wec[o * 6 + 0], w1 = Wec[o * 6 + 1], w2 = Wec[o * 6 + 2];
    float w3 = Wec[o * 6 + 3], w4 = Wec[o * 6 + 4], w5 = Wec[o * 6 + 5];
    float c0 = ctr[g][0], c1 = ctr[g][1], c2 = ctr[g][2];
    float base = bec[o] + w3 * c0 + w4 * c1 + w5 * c2;
    float m = -3.4e38f;
    #pragma unroll
    for (int k = 0; k < KNN; ++k) {
        float v = base + w0 * (nb[g][k][0] - c0) + w1 * (nb[g][k][1] - c1) + w2 * (nb[g][k][2] - c2);
        v = v > 0.f ? v : 0.2f * v;
        m = fmaxf(m, v);
    }
    hcatT[(size_t)p * 512 + o] = f2bf(m);
}

// ---------------------------------------------------------------- graph max pool, bf16 [pt][ch] -> bf16 [pt][C]
__global__ __launch_bounds__(256) void pool_bf16_kernel(const unsigned short* __restrict__ src, int s_coff,
                                                        const int* __restrict__ idx,
                                                        unsigned short* __restrict__ dst, int C) {
    int tid = threadIdx.x, wv = tid >> 6, lane = tid & 63;
    int p = blockIdx.x * 4 + wv;
    int b = p >> 11;
    const int* ip = idx + (size_t)p * KNN;
    const unsigned short* sb = src + (size_t)b * NP * 512 + s_coff;
    for (int c0 = 0; c0 < C; c0 += 64) {
        int ch = c0 + lane;
        float m = -3.4e38f;
        #pragma unroll
        for (int k = 0; k < KNN; ++k) {
            int j = ip[k];
            m = fmaxf(m, bf2f(sb[(size_t)j * 512 + ch]));
        }
        dst[(size_t)p * C + ch] = f2bf(m);
    }
}

// ---------------------------------------------------------------- conv1 MFMA: 128pts x 64ch, K=64
__global__ __launch_bounds__(256) void mfma_conv64_kernel(const unsigned short* __restrict__ A,
                                                          const unsigned short* __restrict__ W,
                                                          const float* __restrict__ bias,
                                                          unsigned short* __restrict__ hcatT, int coff) {
    __shared__ unsigned short As[128][72];
    __shared__ unsigned short Bs[64][72];
    int m0 = blockIdx.x * 128, b = blockIdx.z;
    int tid = threadIdx.x;
    int lane = tid & 63, wave = tid >> 6;
    int wr = wave >> 1, wc = wave & 1;
    int quad = lane >> 4, l16 = lane & 15;
    {
        int r = tid >> 1, s = (tid & 1) * 32;
        const unsigned short* ap = A + (size_t)b * NP * 64 + (size_t)(m0 + r) * 64 + s;
        uint4 v0 = *(const uint4*)(ap);
        uint4 v1 = *(const uint4*)(ap + 8);
        uint4 v2 = *(const uint4*)(ap + 16);
        uint4 v3 = *(const uint4*)(ap + 24);
        *(uint4*)&As[r][s] = v0; *(uint4*)&As[r][s + 8] = v1;
        *(uint4*)&As[r][s + 16] = v2; *(uint4*)&As[r][s + 24] = v3;
    }
    {
        int r = tid >> 2, s = (tid & 3) * 16;
        const unsigned short* wp = W + r * 64 + s;
        *(uint4*)&Bs[r][s] = *(const uint4*)wp;
        *(uint4*)&Bs[r][s + 8] = *(const uint4*)(wp + 8);
    }
    __syncthreads();
    f32x4 acc[4][2] = {};
    #pragma unroll
    for (int k0 = 0; k0 < 64; k0 += 32) {
        bf16x8 af[4], bfv[2];
        #pragma unroll
        for (int i = 0; i < 4; ++i) af[i] = *(const bf16x8*)&As[wr * 64 + i * 16 + l16][k0 + quad * 8];
        #pragma unroll
        for (int j = 0; j < 2; ++j) bfv[j] = *(const bf16x8*)&Bs[wc * 32 + j * 16 + l16][k0 + quad * 8];
        #pragma unroll
        for (int i = 0; i < 4; ++i)
            #pragma unroll
            for (int j = 0; j < 2; ++j)
                acc[i][j] = __builtin_amdgcn_mfma_f32_16x16x32_bf16(af[i], bfv[j], acc[i][j], 0, 0, 0);
    }
    #pragma unroll
    for (int i = 0; i < 4; ++i) {
        #pragma unroll
        for (int r = 0; r < 4; ++r) {
            int pt = m0 + wr * 64 + i * 16 + quad * 4 + r;
            #pragma unroll
            for (int j = 0; j < 2; ++j) {
                int ch = wc * 32 + j * 16 + l16;
                float v = acc[i][j][r] + bias[ch];
                v = v > 0.f ? v : 0.2f * v;
                hcatT[((size_t)b * NP + pt) * 512 + coff + ch] = f2bf(v);
            }
        }
    }
}

// ---------------------------------------------------------------- weight/bias cast + xm init (one launch)
__global__ __launch_bounds__(256) void wcast_kernel(const float* __restrict__ Wf, const float* __restrict__ Wc3,
                                                    const float* __restrict__ Wk, const float* __restrict__ Wv,
                                                    const float* __restrict__ bk, const float* __restrict__ bv,
                                                    const float* __restrict__ Wc1, const float* __restrict__ Wc2,
                                                    const float* __restrict__ Wq, const float* __restrict__ Wo,
                                                    const float* __restrict__ Wff1, const float* __restrict__ Wff2,
                                                    unsigned short* __restrict__ WfB, unsigned short* __restrict__ Wc3B,
                                                    unsigned short* __restrict__ WkvB, float* __restrict__ bkv,
                                                    unsigned short* __restrict__ Wc1B, unsigned short* __restrict__ Wc2B,
                                                    unsigned short* __restrict__ WtB, unsigned short* __restrict__ Wff1B,
                                                    unsigned short* __restrict__ Wff2B,
                                                    unsigned* __restrict__ xmk) {
    int id = blockIdx.x * 256 + threadIdx.x;
    if (id < 262144) { WfB[id] = f2bf(Wf[id]); return; }
    int j = id - 262144;
    if (j < 32768) { Wc3B[j] = f2bf(Wc3[j]); return; }
    j -= 32768;
    if (j < 524288) {
        int l = j >> 17, r = j & 131071;
        float v = (r < 65536) ? Wk[(size_t)(l * 2 + 1) * 65536 + r]
                              : Wv[(size_t)(l * 2 + 1) * 65536 + (r - 65536)];
        WkvB[j] = f2bf(v);
        return;
    }
    j -= 524288;
    if (j < 2048) {
        int l = j >> 9, r = j & 511;
        bkv[j] = (r < 256) ? bk[(l * 2 + 1) * 256 + r] : bv[(l * 2 + 1) * 256 + (r - 256)];
        return;
    }
    j -= 2048;
    if (j < 4096) { Wc1B[j] = f2bf(Wc1[j]); return; }
    j -= 4096;
    if (j < 8192) { Wc2B[j] = f2bf(Wc2[j]); return; }
    j -= 8192;
    if (j < 4096) { xmk[j] = 0u; return; }
    j -= 4096;
    if (j < 1572864) {
        int l = j / 393216;
        int r = j - l * 393216;
        int m = r >> 16, c = r & 65535;
        float v;
        if (m == 0)      v = Wq[(size_t)(l * 2 + 0) * 65536 + c];
        else if (m == 1) v = Wk[(size_t)(l * 2 + 0) * 65536 + c];
        else if (m == 2) v = Wv[(size_t)(l * 2 + 0) * 65536 + c];
        else if (m == 3) v = Wo[(size_t)(l * 2 + 0) * 65536 + c];
        else if (m == 4) v = Wq[(size_t)(l * 2 + 1) * 65536 + c];
        else             v = Wo[(size_t)(l * 2 + 1) * 65536 + c];
        WtB[j] = f2bf(v);
        return;
    }
    j -= 1572864;
    if (j < 524288) { Wff1B[j] = f2bf(Wff1[j]); return; }
    j -= 524288;
    if (j < 524288) { Wff2B[j] = f2bf(Wff2[j]); return; }
}

// ---------------------------------------------------------------- generic bf16 MFMA GEMM (encoder)
__global__ __launch_bounds__(256) void mfma_gemm_kernel(const unsigned short* __restrict__ A, size_t a_bstride,
                                                        const unsigned short* __restrict__ B, size_t b_bstride,
                                                        const float* __restrict__ bias, int bias_per_m,
                                                        void* __restrict__ C, size_t c_bstride, int c_rstride,
                                                        int K, int act, int out_bf16,
                                                        unsigned* __restrict__ xmk, int domax) {
    __shared__ unsigned short As[128][40];
    __shared__ unsigned short Bs[128][40];
    int m0 = blockIdx.x * 128, n0 = blockIdx.y * 128, b = blockIdx.z;
    int tid = threadIdx.x;
    int lane = tid & 63, wave = tid >> 6;
    int wr = wave >> 1, wc = wave & 1;
    int quad = lane >> 4, l16 = lane & 15;
    int r0 = tid >> 2, kc0 = (tid & 3) * 8;
    f32x4 acc[4][4] = {};
    const unsigned short* Ab = A + (size_t)b * a_bstride;
    const unsigned short* Bb = B + (size_t)b * b_bstride;
    for (int k0 = 0; k0 < K; k0 += 32) {
        uint4 a0 = *(const uint4*)(Ab + (size_t)(m0 + r0) * K + k0 + kc0);
        uint4 a1 = *(const uint4*)(Ab + (size_t)(m0 + r0 + 64) * K + k0 + kc0);
        uint4 b0 = *(const uint4*)(Bb + (size_t)(n0 + r0) * K + k0 + kc0);
        uint4 b1 = *(const uint4*)(Bb + (size_t)(n0 + r0 + 64) * K + k0 + kc0);
        __syncthreads();
        *(uint4*)&As[r0][kc0] = a0;
        *(uint4*)&As[r0 + 64][kc0] = a1;
        *(uint4*)&Bs[r0][kc0] = b0;
        *(uint4*)&Bs[r0 + 64][kc0] = b1;
        __syncthreads();
        bf16x8 af[4], bfv[4];
        #pragma unroll
        for (int i = 0; i < 4; ++i) af[i] = *(const bf16x8*)&As[wr * 64 + i * 16 + l16][quad * 8];
        #pragma unroll
        for (int j = 0; j < 4; ++j) bfv[j] = *(const bf16x8*)&Bs[wc * 64 + j * 16 + l16][quad * 8];
        #pragma unroll
        for (int i = 0; i < 4; ++i)
            #pragma unroll
            for (int j = 0; j < 4; ++j)
                acc[i][j] = __builtin_amdgcn_mfma_f32_16x16x32_bf16(af[i], bfv[j], acc[i][j], 0, 0, 0);
    }
    if (domax) {
        #pragma unroll
        for (int i = 0; i < 4; ++i) {
            #pragma unroll
            for (int r = 0; r < 4; ++r) {
                int m = m0 + wr * 64 + i * 16 + quad * 4 + r;
                float v = fmaxf(fmaxf(acc[i][0][r], acc[i][1][r]), fmaxf(acc[i][2][r], acc[i][3][r]));
                v += bias[m];
                #pragma unroll
                for (int off = 1; off <= 8; off <<= 1) v = fmaxf(v, __shfl_xor(v, off));
                if (l16 == 0) atomicMax(&xmk[(size_t)b * 512 + m], fmono(v));
            }
        }
        return;
    }
    #pragma unroll
    for (int i = 0; i < 4; ++i) {
        #pragma unroll
        for (int r = 0; r < 4; ++r) {
            int m = m0 + wr * 64 + i * 16 + quad * 4 + r;
            float bm = bias_per_m ? bias[m] : 0.f;
            #pragma unroll
            for (int j = 0; j < 4; ++j) {
                int n = n0 + wc * 64 + j * 16 + l16;
                float v = acc[i][j][r] + (bias_per_m ? bm : bias[n]);
                if (act) v = v > 0.f ? v : 0.2f * v;
                size_t off = (size_t)b * c_bstride + (size_t)m * c_rstride + n;
                if (out_bf16) ((unsigned short*)C)[off] = f2bf(v);
                else          ((float*)C)[off] = v;
            }
        }
    }
}

// ---------------------------------------------------------------- KV for ALL layers (+ prefetch of layer-0 tail weights)
__global__ __launch_bounds__(256) void mfma_kv_all_kernel(const unsigned short* __restrict__ A,
                                                          const unsigned short* __restrict__ W,
                                                          const float* __restrict__ bkv,
                                                          unsigned short* __restrict__ KVall,
                                                          const unsigned short* __restrict__ pfW) {
    __shared__ unsigned short As[128][40];
    __shared__ unsigned short Bs[128][40];
    int m0 = blockIdx.x * 128;
    int nb = blockIdx.y & 3, l = blockIdx.y >> 2;
    int n0 = nb * 128;
    int b = blockIdx.z;
    int tid = threadIdx.x;
    int lane = tid & 63, wave = tid >> 6;
    int wr = wave >> 1, wc = wave & 1;
    int quad = lane >> 4, l16 = lane & 15;
    int r0 = tid >> 2, kc0 = (tid & 3) * 8;
    // wide prefetch: layer-0 WtB block (12288 cachelines over 2048 blocks = 6/block)
    float pf = 0.f;
    {
        int bid = ((blockIdx.z * 16 + blockIdx.y) * 16 + blockIdx.x);
        if (tid < 6) pf = ((const float*)pfW)[(size_t)(bid * 6 + tid) << 4];
    }
    f32x4 acc[4][4] = {};
    const unsigned short* Ab = A + (size_t)b * NP * 256;
    const unsigned short* Bb = W + (size_t)l * 131072;
    const float* bias = bkv + l * 512;
    for (int k0 = 0; k0 < 256; k0 += 32) {
        uint4 a0 = *(const uint4*)(Ab + (size_t)(m0 + r0) * 256 + k0 + kc0);
        uint4 a1 = *(const uint4*)(Ab + (size_t)(m0 + r0 + 64) * 256 + k0 + kc0);
        uint4 b0 = *(const uint4*)(Bb + (size_t)(n0 + r0) * 256 + k0 + kc0);
        uint4 b1 = *(const uint4*)(Bb + (size_t)(n0 + r0 + 64) * 256 + k0 + kc0);
        __syncthreads();
        *(uint4*)&As[r0][kc0] = a0;
        *(uint4*)&As[r0 + 64][kc0] = a1;
        *(uint4*)&Bs[r0][kc0] = b0;
        *(uint4*)&Bs[r0 + 64][kc0] = b1;
        __syncthreads();
        bf16x8 af[4], bfv[4];
        #pragma unroll
        for (int i = 0; i < 4; ++i) af[i] = *(const bf16x8*)&As[wr * 64 + i * 16 + l16][quad * 8];
        #pragma unroll
        for (int j = 0; j < 4; ++j) bfv[j] = *(const bf16x8*)&Bs[wc * 64 + j * 16 + l16][quad * 8];
        #pragma unroll
        for (int i = 0; i < 4; ++i)
            #pragma unroll
            for (int j = 0; j < 4; ++j)
                acc[i][j] = __builtin_amdgcn_mfma_f32_16x16x32_bf16(af[i], bfv[j], acc[i][j], 0, 0, 0);
    }
    unsigned short* Cb = KVall + ((size_t)l * BN + b) * NP * 512;
    #pragma unroll
    for (int i = 0; i < 4; ++i) {
        #pragma unroll
        for (int r = 0; r < 4; ++r) {
            int m = m0 + wr * 64 + i * 16 + quad * 4 + r;
            #pragma unroll
            for (int j = 0; j < 4; ++j) {
                int n = n0 + wc * 64 + j * 16 + l16;
                Cb[(size_t)m * 512 + n] = f2bf(acc[i][j][r] + bias[n]);
            }
        }
    }
    asm volatile("" :: "v"(pf));
}

// ---------------------------------------------------------------- q0 row + fold layer-0 QKV projection
__global__ __launch_bounds__(256) void pc_kernel(const unsigned* __restrict__ xmk, const float* __restrict__ Wpc,
                                                 const float* __restrict__ bpc,
                                                 const unsigned short* __restrict__ Wqkv,
                                                 const float* __restrict__ bq0, const float* __restrict__ bk0,
                                                 const float* __restrict__ bv0,
                                                 float* __restrict__ q, float* __restrict__ Qs,
                                                 float* __restrict__ Ks, float* __restrict__ Vs) {
    int row = blockIdx.x, tid = threadIdx.x;
    int id = row * 256 + tid;
    int b = row >> 3, i = row & 7;
    const unsigned* xr = xmk + b * 512 + i * 64;
    const float* w = Wpc + (size_t)tid * 64;
    float acc = bpc[tid];
    #pragma unroll
    for (int e = 0; e < 64; ++e) acc += funmono(xr[e]) * w[e];
    float qv = acc > 0.f ? acc : 0.2f * acc;
    q[id] = qv;
    __shared__ __align__(16) float a[256];
    a[tid] = qv;
    __syncthreads();
    Qs[id] = bq0[tid] + gemv_dot(Wqkv + (size_t)tid * 256, a, 32);
    Ks[id] = bk0[tid] + gemv_dot(Wqkv + 65536 + (size_t)tid * 256, a, 32);
    Vs[id] = bv0[tid] + gemv_dot(Wqkv + 131072 + (size_t)tid * 256, a, 32);
}

// ---------------------------------------------------------------- memB = bf16(act(x @ Wpi.T + bpi))
__global__ __launch_bounds__(256) void mem_kernel(const float* __restrict__ x, const float* __restrict__ Wpi,
                                                  const float* __restrict__ bpi, unsigned short* __restrict__ memB) {
    size_t id = (size_t)blockIdx.x * 256 + threadIdx.x;
    int p = (int)(id & 255);
    size_t pt = id >> 8;
    float x0 = x[pt * 3 + 0], x1 = x[pt * 3 + 1], x2 = x[pt * 3 + 2];
    float v = bpi[p] + x0 * Wpi[p * 3 + 0] + x1 * Wpi[p * 3 + 1] + x2 * Wpi[p * 3 + 2];
    v = v > 0.f ? v : 0.2f * v;
    memB[id] = f2bf(v);
}

// ---------------------------------------------------------------- self-attn + O-proj + res + LN + cross-Q-proj (1024 thr)
__global__ __launch_bounds__(1024) void attn_ln_kernel(const float* __restrict__ Qs, const float* __restrict__ Ks,
                                                       const float* __restrict__ Vs,
                                                       const unsigned short* __restrict__ WoB,
                                                       const float* __restrict__ bo, const float* __restrict__ res,
                                                       const float* __restrict__ g, const float* __restrict__ bt,
                                                       const unsigned short* __restrict__ Wq1B,
                                                       const float* __restrict__ bq1,
                                                       float* __restrict__ out, float* __restrict__ Qc) {
    int row = blockIdx.x, tid = threadIdx.x;
    int b = row >> 3;
    __shared__ float Kl[2048], Vl[2048];
    __shared__ __align__(16) float qr[256];
    __shared__ float sc[64];
    __shared__ __align__(16) float r[256];
    __shared__ __align__(16) float aout[256];
    __shared__ float red[1024];
    for (int t = tid; t < 2048; t += 1024) {
        Kl[t] = Ks[(size_t)b * 2048 + t];
        Vl[t] = Vs[(size_t)b * 2048 + t];
    }
    if (tid < 256) qr[tid] = Qs[(size_t)row * 256 + tid];
    __syncthreads();
    const float scale = 0.17677669529663687f;
    {
        int pair = tid >> 4, part = tid & 15;
        int h = pair >> 3, k = pair & 7;
        int d = part * 2;
        float dot = qr[h * 32 + d] * Kl[k * 256 + h * 32 + d]
                  + qr[h * 32 + d + 1] * Kl[k * 256 + h * 32 + d + 1];
        dot += __shfl_xor(dot, 1);
        dot += __shfl_xor(dot, 2);
        dot += __shfl_xor(dot, 4);
        dot += __shfl_xor(dot, 8);
        if (part == 0) sc[pair] = dot * scale;
    }
    __syncthreads();
    if (tid < 64) {
        float v = sc[tid];
        float m = v;
        #pragma unroll
        for (int off = 1; off < 8; off <<= 1) m = fmaxf(m, __shfl_xor(m, off));
        float e = __expf(v - m);
        float s = e;
        #pragma unroll
        for (int off = 1; off < 8; off <<= 1) s += __shfl_xor(s, off);
        sc[tid] = e / s;
    }
    __syncthreads();
    if (tid < 256) {
        int h = tid >> 5;
        float acc = 0.f;
        #pragma unroll
        for (int k = 0; k < 8; ++k) acc += sc[h * 8 + k] * Vl[k * 256 + tid];
        r[tid] = acc;
    }
    __syncthreads();
    // O-proj: 4 threads/output, 64-elem partials
    int o4 = tid >> 2, p4 = tid & 3;
    float v;
    {
        float acc = gemv_dot(WoB + (size_t)o4 * 256 + p4 * 64, r + p4 * 64, 8);
        acc += __shfl_xor(acc, 1);
        acc += __shfl_xor(acc, 2);
        v = (p4 == 0) ? (bo[o4] + acc + res[(size_t)row * 256 + o4]) : 0.f;
    }
    red[tid] = v; __syncthreads();
    for (int s = 512; s; s >>= 1) { if (tid < s) red[tid] += red[tid + s]; __syncthreads(); }
    float mean = red[0] * (1.0f / 256.0f);
    __syncthreads();
    float dv = (p4 == 0) ? v - mean : 0.f;
    red[tid] = dv * dv; __syncthreads();
    for (int s = 512; s; s >>= 1) { if (tid < s) red[tid] += red[tid + s]; __syncthreads(); }
    float var = red[0] * (1.0f / 256.0f);
    if (p4 == 0) {
        float oln = g[o4] * dv * rsqrtf(var + 1e-5f) + bt[o4];
        out[(size_t)row * 256 + o4] = oln;
        aout[o4] = oln;
    }
    __syncthreads();
    {
        float qacc = gemv_dot(Wq1B + (size_t)o4 * 256 + p4 * 64, aout + p4 * 64, 8);
        qacc += __shfl_xor(qacc, 1);
        qacc += __shfl_xor(qacc, 2);
        if (p4 == 0) Qc[(size_t)row * 256 + o4] = bq1[o4] + qacc;
    }
}

// ---------------------------------------------------------------- cross-attn pass 1: 16 key-blocks of 128
// + wide prefetch of this layer's combine weights and next layer's attn/QKV weights
__global__ __launch_bounds__(256) void ca_part_kernel(const float* __restrict__ Qc,
                                                      const unsigned short* __restrict__ KVl,
                                                      float* __restrict__ part,
                                                      const unsigned short* __restrict__ pfWo,
                                                      const unsigned short* __restrict__ pfW1,
                                                      const unsigned short* __restrict__ pfW2,
                                                      const unsigned short* __restrict__ pfWn) {
    int kb = blockIdx.x, h = blockIdx.y, b = blockIdx.z;
    int tid = threadIdx.x;
    __shared__ float q[8][32];
    __shared__ __align__(16) float S[8][128];
    __shared__ float om[8][8][32];
    const float scale = 0.17677669529663687f;
    // prefetch: 2048 (Wo) + 4096 (W1) + 4096 (W2) + 12288 (next WtB) = 22528 lines / 1024 blocks = 22/block
    float pf = 0.f;
    {
        int bid = ((b * NH + h) * 16 + kb);
        if (tid < 22) {
            int L = bid * 22 + tid;
            if (L < 2048)       pf = ((const float*)pfWo)[(size_t)L << 4];
            else if (L < 6144)  pf = ((const float*)pfW1)[(size_t)(L - 2048) << 4];
            else if (L < 10240) pf = ((const float*)pfW2)[(size_t)(L - 6144) << 4];
            else if (pfWn)      pf = ((const float*)pfWn)[(size_t)(L - 10240) << 4];
        }
    }
    {
        int i = tid >> 5, d = tid & 31;
        q[i][d] = Qc[(size_t)(b * 8 + i) * 256 + h * 32 + d];
    }
    __syncthreads();
    {
        int kk = tid & 127, half = tid >> 7;
        int k = kb * 128 + kk;
        const unsigned short* kp = KVl + ((size_t)b * NP + k) * 512 + h * 32;
        float kd[32];
        #pragma unroll
        for (int u = 0; u < 4; ++u) {
            uint4 raw = *(const uint4*)(kp + u * 8);
            unsigned w0 = raw.x, w1 = raw.y, w2 = raw.z, w3 = raw.w;
            kd[u * 8 + 0] = __uint_as_float(w0 << 16); kd[u * 8 + 1] = __uint_as_float(w0 & 0xFFFF0000u);
            kd[u * 8 + 2] = __uint_as_float(w1 << 16); kd[u * 8 + 3] = __uint_as_float(w1 & 0xFFFF0000u);
            kd[u * 8 + 4] = __uint_as_float(w2 << 16); kd[u * 8 + 5] = __uint_as_float(w2 & 0xFFFF0000u);
            kd[u * 8 + 6] = __uint_as_float(w3 << 16); kd[u * 8 + 7] = __uint_as_float(w3 & 0xFFFF0000u);
        }
        #pragma unroll
        for (int i = 0; i < 4; ++i) {
            int ri = half * 4 + i;
            float dot = 0.f;
            #pragma unroll
            for (int d = 0; d < 32; ++d) dot += q[ri][d] * kd[d];
            S[ri][kk] = dot * scale;
        }
    }
    __syncthreads();
    float* pout = part + (((size_t)(b * NH + h)) * 16 + kb) * 288;
    {
        int i = tid >> 5, l32 = tid & 31;
        float m = -3.4e38f;
        #pragma unroll
        for (int t = 0; t < 4; ++t) m = fmaxf(m, S[i][l32 + t * 32]);
        #pragma unroll
        for (int off = 16; off; off >>= 1) m = fmaxf(m, __shfl_xor(m, off));
        float s = 0.f;
        #pragma unroll
        for (int t = 0; t < 4; ++t) {
            float e = __expf(S[i][l32 + t * 32] - m);
            S[i][l32 + t * 32] = e;
            s += e;
        }
        #pragma unroll
        for (int off = 16; off; off >>= 1) s += __shfl_xor(s, off);
        if (l32 == 0) { pout[i] = m; pout[8 + i] = s; }
    }
    __syncthreads();
    {
        int d = tid & 31, grp = tid >> 5;
        const unsigned short* Vb = KVl + ((size_t)b * NP + kb * 128) * 512 + 256 + h * 32 + d;
        float acc[8] = {};
        #pragma unroll 4
        for (int t = 0; t < 16; ++t) {
            int kk = grp * 16 + t;
            float v = bf2f(Vb[(size_t)kk * 512]);
            #pragma unroll
            for (int i = 0; i < 8; ++i) acc[i] += S[i][kk] * v;
        }
        #pragma unroll
        for (int i = 0; i < 8; ++i) om[grp][i][d] = acc[i];
    }
    __syncthreads();
    {
        int i = tid >> 5, d = tid & 31;
        float sum = 0.f;
        #pragma unroll
        for (int g = 0; g < 8; ++g) sum += om[g][i][d];
        pout[16 + i * 32 + d] = sum;
    }
    asm volatile("" :: "v"(pf));
}

// ---------------------------------------------------------------- combine + O-proj + LN + FF + LN [+ next-layer QKV | final LN+Wcm] (1024 thr)
__global__ __launch_bounds__(1024) void combine_ff_kernel(const float* __restrict__ part,
                                                          const unsigned short* __restrict__ WoB,
                                                          const float* __restrict__ bo, const float* __restrict__ res,
                                                          const float* __restrict__ g2, const float* __restrict__ b2t,
                                                          const unsigned short* __restrict__ W1B,
                                                          const float* __restrict__ b1,
                                                          const unsigned short* __restrict__ W2B,
                                                          const float* __restrict__ b2,
                                                          const float* __restrict__ g3, const float* __restrict__ b3t,
                                                          float* __restrict__ out,
                                                          int is_last, const float* __restrict__ lnfg,
                                                          const float* __restrict__ lnfb, const float* __restrict__ Wcm,
                                                          const float* __restrict__ bcm, float* __restrict__ finout,
                                                          const unsigned short* __restrict__ Wqkvn,
                                                          const float* __restrict__ bqn, const float* __restrict__ bkn,
                                                          const float* __restrict__ bvn,
                                                          float* __restrict__ Qs, float* __restrict__ Ks,
                                                          float* __restrict__ Vs) {
    int row = blockIdx.x, tid = threadIdx.x;
    int b = row >> 3, i = row & 7;
    __shared__ __align__(16) float r[256];
    __shared__ __align__(16) float a[256];
    __shared__ __align__(16) float hbuf[512];
    __shared__ float red[1024];
    // phase 1: combine cross-attn partials (4 threads per (h,d), each 4 key-blocks)
    {
        int h = tid >> 7, rem = tid & 127, d = rem >> 2, g = rem & 3;
        const float* pb = part + (size_t)(b * NH + h) * 16 * 288;
        float M = -3.4e38f;
        #pragma unroll
        for (int t = 0; t < 4; ++t) M = fmaxf(M, pb[(g * 4 + t) * 288 + i]);
        M = fmaxf(M, __shfl_xor(M, 1));
        M = fmaxf(M, __shfl_xor(M, 2));
        float L = 0.f, O = 0.f;
        #pragma unroll
        for (int t = 0; t < 4; ++t) {
            int kb = g * 4 + t;
            float w = __expf(pb[kb * 288 + i] - M);
            L += pb[kb * 288 + 8 + i] * w;
            O += pb[kb * 288 + 16 + i * 32 + d] * w;
        }
        L += __shfl_xor(L, 1); L += __shfl_xor(L, 2);
        O += __shfl_xor(O, 1); O += __shfl_xor(O, 2);
        if (g == 0) r[h * 32 + d] = O / L;
    }
    __syncthreads();
    int o4 = tid >> 2, p4 = tid & 3;
    // phase 2: O-proj (4 thr/out) + residual + LN
    float v;
    {
        float acc = gemv_dot(WoB + (size_t)o4 * 256 + p4 * 64, r + p4 * 64, 8);
        acc += __shfl_xor(acc, 1);
        acc += __shfl_xor(acc, 2);
        v = (p4 == 0) ? (bo[o4] + acc + res[(size_t)row * 256 + o4]) : 0.f;
    }
    red[tid] = v; __syncthreads();
    for (int s = 512; s; s >>= 1) { if (tid < s) red[tid] += red[tid + s]; __syncthreads(); }
    float mean = red[0] * (1.0f / 256.0f);
    __syncthreads();
    float dv = (p4 == 0) ? v - mean : 0.f;
    red[tid] = dv * dv; __syncthreads();
    for (int s = 512; s; s >>= 1) { if (tid < s) red[tid] += red[tid + s]; __syncthreads(); }
    float var = red[0] * (1.0f / 256.0f);
    if (p4 == 0) a[o4] = g2[o4] * dv * rsqrtf(var + 1e-5f) + b2t[o4];
    __syncthreads();
    // phase 3: FF1 (2 thr/out, 128-elem partials)
    {
        int o = tid >> 1, p = tid & 1;
        float acc = gemv_dot(W1B + (size_t)o * 256 + p * 128, a + p * 128, 16);
        acc += __shfl_xor(acc, 1);
        if (p == 0) { float t = b1[o] + acc; hbuf[o] = t > 0.f ? t : 0.2f * t; }
    }
    __syncthreads();
    // phase 4: FF2 (4 thr/out, K=512) + residual + LN
    float vF;
    {
        float acc = gemv_dot(W2B + (size_t)o4 * 512 + p4 * 128, hbuf + p4 * 128, 16);
        acc += __shfl_xor(acc, 1);
        acc += __shfl_xor(acc, 2);
        vF = (p4 == 0) ? (b2[o4] + acc + a[o4]) : 0.f;
    }
    red[tid] = vF; __syncthreads();
    for (int s = 512; s; s >>= 1) { if (tid < s) red[tid] += red[tid + s]; __syncthreads(); }
    float mean2 = red[0] * (1.0f / 256.0f);
    __syncthreads();
    float dv2 = (p4 == 0) ? vF - mean2 : 0.f;
    red[tid] = dv2 * dv2; __syncthreads();
    for (int s = 512; s; s >>= 1) { if (tid < s) red[tid] += red[tid + s]; __syncthreads(); }
    float var2 = red[0] * (1.0f / 256.0f);
    float tln = 0.f;
    if (p4 == 0) {
        tln = g3[o4] * dv2 * rsqrtf(var2 + 1e-5f) + b3t[o4];
        r[o4] = tln;
    }
    __syncthreads();
    if (!is_last) {
        if (p4 == 0) out[(size_t)row * 256 + o4] = tln;
        // next-layer QKV from tln row in r[]: 768 full-dot threads
        if (tid < 768) {
            int which = tid >> 8, o = tid & 255;
            float acc = gemv_dot(Wqkvn + (size_t)which * 65536 + (size_t)o * 256, r, 32);
            float bb = (which == 0) ? bqn[o] : (which == 1) ? bkn[o] : bvn[o];
            float* dst = (which == 0) ? Qs : (which == 1) ? Ks : Vs;
            dst[(size_t)row * 256 + o] = bb + acc;
        }
        return;
    }
    // final LN + Wcm
    float tf = (tid < 256) ? r[tid] : 0.f;
    red[tid] = tf; __syncthreads();
    for (int s = 512; s; s >>= 1) { if (tid < s) red[tid] += red[tid + s]; __syncthreads(); }
    float mean3 = red[0] * (1.0f / 256.0f);
    __syncthreads();
    float d3 = (tid < 256) ? tf - mean3 : 0.f;
    red[tid] = d3 * d3; __syncthreads();
    for (int s = 512; s; s >>= 1) { if (tid < s) red[tid] += red[tid + s]; __syncthreads(); }
    float var3 = red[0] * (1.0f / 256.0f);
    if (tid < 256) a[tid] = lnfg[tid] * d3 * rsqrtf(var3 + 1e-5f) + lnfb[tid];
    __syncthreads();
    if (tid < 64) {
        const float4* w4 = (const float4*)(Wcm + (size_t)tid * 256);
        const float4* a4 = (const float4*)a;
        float acc = bcm[tid];
        #pragma unroll 8
        for (int c = 0; c < 64; ++c) {
            float4 av = a4[c], wv = w4[c];
            acc += av.x * wv.x + av.y * wv.y + av.z * wv.z + av.w * wv.w;
        }
        finout[(size_t)b * 512 + i * 64 + tid] = acc;
    }
}

// ================================================================ host
extern "C" void kernel_launch(void* const* d_in, const int* in_sizes, int n_in,
                              void* d_out, int out_size, void* d_ws, size_t ws_size,
                              hipStream_t stream) {
    const float* x    = (const float*)d_in[0];
    const float* Wec  = (const float*)d_in[1];
    const float* bec  = (const float*)d_in[2];
    const float* Wc1  = (const float*)d_in[3];
    const float* bc1  = (const float*)d_in[4];
    const float* Wc2  = (const float*)d_in[5];
    const float* bc2  = (const float*)d_in[6];
    const float* Wc3  = (const float*)d_in[7];
    const float* bc3  = (const float*)d_in[8];
    const float* Wf   = (const float*)d_in[9];
    const float* bf   = (const float*)d_in[10];
    const float* Wpc  = (const float*)d_in[11];
    const float* bpc  = (const float*)d_in[12];
    const float* Wpi  = (const float*)d_in[13];
    const float* bpi  = (const float*)d_in[14];
    const float* Wq   = (const float*)d_in[15];
    const float* bq   = (const float*)d_in[16];
    const float* Wk   = (const float*)d_in[17];
    const float* bk   = (const float*)d_in[18];
    const float* Wv   = (const float*)d_in[19];
    const float* bv   = (const float*)d_in[20];
    const float* Wo   = (const float*)d_in[21];
    const float* bo   = (const float*)d_in[22];
    const float* ln1g = (const float*)d_in[23];
    const float* ln1b = (const float*)d_in[24];
    const float* ln2g = (const float*)d_in[25];
    const float* ln2b = (const float*)d_in[26];
    const float* Wff1 = (const float*)d_in[27];
    const float* bff1 = (const float*)d_in[28];
    const float* Wff2 = (const float*)d_in[29];
    const float* bff2 = (const float*)d_in[30];
    const float* ln3g = (const float*)d_in[31];
    const float* ln3b = (const float*)d_in[32];
    const float* lnfg = (const float*)d_in[33];
    const float* lnfb = (const float*)d_in[34];
    const float* Wcm  = (const float*)d_in[35];
    const float* bcm  = (const float*)d_in[36];
    float* out = (float*)d_out;

    float* ws = (float*)d_ws;
    size_t off = 0;
    auto alloc = [&](size_t n) { float* p = ws + off; off += (n + 3) & ~(size_t)3; return p; };
    int*            idx   = (int*)alloc((size_t)BN * NP * KNN);
    unsigned short* hcatT = (unsigned short*)alloc((size_t)BN * NP * 512 / 2);
    unsigned short* poolT = (unsigned short*)alloc((size_t)BN * NP * 128 / 2);
    unsigned short* WfB   = (unsigned short*)alloc(262144 / 2);
    unsigned short* Wc1B  = (unsigned short*)alloc(4096 / 2);
    unsigned short* Wc2B  = (unsigned short*)alloc(8192 / 2);
    unsigned short* Wc3B  = (unsigned short*)alloc(32768 / 2);
    unsigned short* WkvB  = (unsigned short*)alloc(524288 / 2);
    float*          bkv   = alloc(2048);
    unsigned short* memB  = (unsigned short*)alloc((size_t)BN * NP * 256 / 2);
    unsigned short* KVall = (unsigned short*)alloc((size_t)NL * BN * NP * 512 / 2);
    unsigned*       xmk   = (unsigned*)alloc((size_t)BN * 512);
    unsigned short* WtB   = (unsigned short*)alloc(1572864 / 2);
    unsigned short* Wff1B = (unsigned short*)alloc(524288 / 2);
    unsigned short* Wff2B = (unsigned short*)alloc(524288 / 2);
    float*          qa    = alloc((size_t)BN * 8 * 256);
    float*          qb    = alloc((size_t)BN * 8 * 256);
    float*          Qs    = alloc((size_t)BN * 8 * 256);
    float*          Ks    = alloc((size_t)BN * 8 * 256);
    float*          Vs    = alloc((size_t)BN * 8 * 256);
    float*          Qc    = alloc((size_t)BN * 8 * 256);
    float*          part  = alloc((size_t)BN * NH * 16 * 288);

    // ---- weight casts + xm-key init (no deps) ----
    wcast_kernel<<<13512, 256, 0, stream>>>(Wf, Wc3, Wk, Wv, bk, bv, Wc1, Wc2, Wq, Wo, Wff1, Wff2,
                                            WfB, Wc3B, WkvB, bkv, Wc1B, Wc2B, WtB, Wff1B, Wff2B, xmk);

    // ---- point-cloud encoder (all-bf16 [pt][ch] chain) ----
    knn_kernel<<<BN * NP / 4, 256, 0, stream>>>(x, idx);
    edge_conv_kernel<<<BN * NP / 4, 256, 0, stream>>>(x, idx, Wec, bec, hcatT);

    pool_bf16_kernel<<<BN * NP / 4, 256, 0, stream>>>(hcatT, 0, idx, poolT, 64);
    mfma_conv64_kernel<<<dim3(NP / 128, 1, BN), 256, 0, stream>>>(poolT, Wc1B, bc1, hcatT, 64);
    pool_bf16_kernel<<<BN * NP / 4, 256, 0, stream>>>(hcatT, 64, idx, poolT, 64);
    mfma_gemm_kernel<<<dim3(NP / 128, 1, BN), 256, 0, stream>>>(poolT, (size_t)NP * 64, Wc2B, 0,
                                                                bc2, 0, (void*)(hcatT + 128), (size_t)NP * 512, 512,
                                                                64, 1, 1, nullptr, 0);
    pool_bf16_kernel<<<BN * NP / 4, 256, 0, stream>>>(hcatT, 128, idx, poolT, 128);
    mfma_gemm_kernel<<<dim3(NP / 128, 2, BN), 256, 0, stream>>>(poolT, (size_t)NP * 128, Wc3B, 0,
                                                                bc3, 0, (void*)(hcatT + 256), (size_t)NP * 512, 512,
                                                                128, 1, 1, nullptr, 0);
    mfma_gemm_kernel<<<dim3(4, NP / 128, BN), 256, 0, stream>>>(WfB, 0, hcatT, (size_t)NP * 512,
                                                                bf, 1, nullptr, 0, 0,
                                                                512, 0, 0, xmk, 1);
    pc_kernel<<<BN * 8, 256, 0, stream>>>(xmk, Wpc, bpc, WtB, bq, bk, bv, qa, Qs, Ks, Vs);
    mem_kernel<<<BN * NP, 256, 0, stream>>>(x, Wpi, bpi, memB);
    mfma_kv_all_kernel<<<dim3(NP / 128, 4 * NL, BN), 256, 0, stream>>>(memB, WkvB, bkv, KVall, WtB);

    // ---- transformer layers (3 launches/layer; QKV folded into producer) ----
    for (int l = 0; l < NL; ++l) {
        const unsigned short* Wl = WtB + (size_t)l * 393216;
        const float* bo0 = bo + (l * 2 + 0) * 256;
        const float* bq1 = bq + (l * 2 + 1) * 256;
        const float* bo1 = bo + (l * 2 + 1) * 256;
        int last = (l == NL - 1);

        attn_ln_kernel<<<BN * 8, 1024, 0, stream>>>(Qs, Ks, Vs, Wl + 3 * 65536, bo0, qa,
                                                    ln1g + l * 256, ln1b + l * 256, Wl + 4 * 65536, bq1, qb, Qc);
        ca_part_kernel<<<dim3(16, NH, BN), 256, 0, stream>>>(Qc, KVall + (size_t)l * BN * NP * 512, part,
                                                             Wl + 5 * 65536,
                                                             Wff1B + (size_t)l * 131072,
                                                             Wff2B + (size_t)l * 131072,
                                                             last ? nullptr : WtB + (size_t)(l + 1) * 393216);
        combine_ff_kernel<<<BN * 8, 1024, 0, stream>>>(part, Wl + 5 * 65536, bo1, qb,
                                                       ln2g + l * 256, ln2b + l * 256,
                                                       Wff1B + (size_t)l * 131072, bff1 + l * 512,
                                                       Wff2B + (size_t)l * 131072, bff2 + l * 256,
                                                       ln3g + l * 256, ln3b + l * 256, qa,
                                                       last, lnfg, lnfb, Wcm, bcm, out,
                                                       last ? nullptr : WtB + (size_t)(l + 1) * 393216,
                                                       bq + ((l + 1) * 2) * 256, bk + ((l + 1) * 2) * 256,
                                                       bv + ((l + 1) * 2) * 256,
                                                       Qs, Ks, Vs);
    }

    (void)in_sizes; (void)n_in; (void)out_size; (void)ws_size;
}

// Round 11
// 517.288 us; speedup vs baseline: 1.1412x; 1.0810x over previous
//
#include <hip/hip_runtime.h>
#include <math.h>

#define BN 8
#define NP 2048
#define KNN 16
#define NL 4
#define NH 8

typedef __attribute__((ext_vector_type(8))) short bf16x8;
typedef __attribute__((ext_vector_type(4))) float f32x4;

__device__ __forceinline__ unsigned short f2bf(float f) {
    unsigned u = __float_as_uint(f);
    unsigned r = (u + 0x7FFFu + ((u >> 16) & 1u)) >> 16;
    return (unsigned short)r;
}
__device__ __forceinline__ float bf2f(unsigned short s) {
    return __uint_as_float(((unsigned)s) << 16);
}
__device__ __forceinline__ unsigned fmono(float f) {
    unsigned u = __float_as_uint(f);
    return (u & 0x80000000u) ? ~u : (u | 0x80000000u);
}
__device__ __forceinline__ float funmono(unsigned k) {
    return (k & 0x80000000u) ? __uint_as_float(k ^ 0x80000000u) : __uint_as_float(~k);
}

// bf16 weight-row dot (K8 groups of 8) vs fp32 vector in LDS; 4 accumulator chains.
__device__ __forceinline__ float gemv_dot(const unsigned short* __restrict__ wrow, const float* sm, int K8) {
    const uint4* w8 = (const uint4*)wrow;
    const float4* r4 = (const float4*)sm;
    float a0 = 0.f, a1 = 0.f, a2 = 0.f, a3 = 0.f;
    #pragma unroll 8
    for (int c = 0; c < K8; ++c) {
        uint4 wv = w8[c];
        float4 x0 = r4[c * 2], x1 = r4[c * 2 + 1];
        a0 += x0.x * __uint_as_float(wv.x << 16) + x0.y * __uint_as_float(wv.x & 0xFFFF0000u);
        a1 += x0.z * __uint_as_float(wv.y << 16) + x0.w * __uint_as_float(wv.y & 0xFFFF0000u);
        a2 += x1.x * __uint_as_float(wv.z << 16) + x1.y * __uint_as_float(wv.z & 0xFFFF0000u);
        a3 += x1.z * __uint_as_float(wv.w << 16) + x1.w * __uint_as_float(wv.w & 0xFFFF0000u);
    }
    return (a0 + a1) + (a2 + a3);
}

// int8 weight-row dot (K16 groups of 16) vs fp32 vector in LDS; caller applies row scale.
__device__ __forceinline__ float gemv_i8(const char* __restrict__ wrow, const float* sm, int K16) {
    const uint4* w16 = (const uint4*)wrow;
    const float4* r4 = (const float4*)sm;
    float a0 = 0.f, a1 = 0.f, a2 = 0.f, a3 = 0.f;
    #pragma unroll 4
    for (int c = 0; c < K16; ++c) {
        uint4 wv = w16[c];
        float4 x0 = r4[c * 4], x1 = r4[c * 4 + 1], x2 = r4[c * 4 + 2], x3 = r4[c * 4 + 3];
        a0 += x0.x * (float)(signed char)(wv.x) + x0.y * (float)(signed char)(wv.x >> 8)
            + x0.z * (float)(signed char)(wv.x >> 16) + x0.w * (float)(signed char)(wv.x >> 24);
        a1 += x1.x * (float)(signed char)(wv.y) + x1.y * (float)(signed char)(wv.y >> 8)
            + x1.z * (float)(signed char)(wv.y >> 16) + x1.w * (float)(signed char)(wv.y >> 24);
        a2 += x2.x * (float)(signed char)(wv.z) + x2.y * (float)(signed char)(wv.z >> 8)
            + x2.z * (float)(signed char)(wv.z >> 16) + x2.w * (float)(signed char)(wv.z >> 24);
        a3 += x3.x * (float)(signed char)(wv.w) + x3.y * (float)(signed char)(wv.w >> 8)
            + x3.z * (float)(signed char)(wv.w >> 16) + x3.w * (float)(signed char)(wv.w >> 24);
    }
    return (a0 + a1) + (a2 + a3);
}

// ---------------------------------------------------------------- knn v8: LDS-staged points + pivot-filter select
__device__ __forceinline__ unsigned long long shflx_u64(unsigned long long v, int j) {
    int lo = __shfl_xor((int)(unsigned)(v & 0xFFFFFFFFull), j);
    int hi = __shfl_xor((int)(unsigned)(v >> 32), j);
    return ((unsigned long long)(unsigned)hi << 32) | (unsigned)lo;
}

__device__ __forceinline__ unsigned sort64_u32(unsigned v, int lane) {
    #pragma unroll
    for (int k = 2; k <= 64; k <<= 1) {
        #pragma unroll
        for (int j = k >> 1; j > 0; j >>= 1) {
            unsigned o = (unsigned)__shfl_xor((int)v, j);
            bool up = ((lane & k) == 0);
            bool lower = ((lane & j) == 0);
            unsigned mn = v < o ? v : o;
            unsigned mx = v < o ? o : v;
            v = (up == lower) ? mn : mx;
        }
    }
    return v;
}

__device__ __forceinline__ unsigned long long sort64_u64(unsigned long long v, int lane) {
    #pragma unroll
    for (int k = 2; k <= 64; k <<= 1) {
        #pragma unroll
        for (int j = k >> 1; j > 0; j >>= 1) {
            unsigned long long o = shflx_u64(v, j);
            bool up = ((lane & k) == 0);
            bool lower = ((lane & j) == 0);
            unsigned long long mn = v < o ? v : o;
            unsigned long long mx = v < o ? o : v;
            v = (up == lower) ? mn : mx;
        }
    }
    return v;
}

__global__ __launch_bounds__(256) void knn_kernel(const float* __restrict__ x, int* __restrict__ idxout) {
    __shared__ float xs[2048], ys[2048], zs[2048], ns[2048];
    __shared__ unsigned long long cand[4][64];
    int tid = threadIdx.x;
    int wv = tid >> 6, lane = tid & 63;
    int p = blockIdx.x * 4 + wv;
    int b = p >> 11, n = p & 2047;
    const float* xb = x + (size_t)b * NP * 3;
    for (int t = tid; t < 2048; t += 256) {
        float mx = xb[t * 3 + 0], my = xb[t * 3 + 1], mz = xb[t * 3 + 2];
        xs[t] = mx; ys[t] = my; zs[t] = mz;
        ns[t] = mx * mx + my * my + mz * mz;
    }
    __syncthreads();
    float cx = xs[n], cy = ys[n], cz = zs[n], xn = ns[n];
    unsigned key[32];
    unsigned lmax = 0u;
    #pragma unroll
    for (int t = 0; t < 32; ++t) {
        int m = (t << 6) | lane;
        float dd = 2.0f * (cx * xs[m] + cy * ys[m] + cz * zs[m]) - xn - ns[m];
        unsigned u = __float_as_uint(dd);
        u = (u & 0x80000000u) ? ~u : (u | 0x80000000u);
        key[t] = u;
        lmax = lmax > u ? lmax : u;
    }
    unsigned sorted = sort64_u32(lmax, lane);
    unsigned S = (unsigned)__shfl((int)sorted, 48);
    int c = 0;
    #pragma unroll
    for (int t = 0; t < 32; ++t) c += (key[t] >= S) ? 1 : 0;
    int inc = c;
    #pragma unroll
    for (int d = 1; d < 64; d <<= 1) {
        int tsh = __shfl_up(inc, d);
        if (lane >= d) inc += tsh;
    }
    int C = __shfl(inc, 63);
    int* op = idxout + (size_t)p * KNN;
    if (C <= 64) {
        int off = inc - c;
        #pragma unroll
        for (int t = 0; t < 32; ++t) {
            if (key[t] >= S) {
                int m = (t << 6) | lane;
                cand[wv][off++] = ((unsigned long long)key[t] << 16) | (unsigned)(2047 - m);
            }
        }
        asm volatile("s_waitcnt lgkmcnt(0)" ::: "memory");
        unsigned long long ck = (lane < C) ? cand[wv][lane] : 0ull;
        ck = sort64_u64(ck, lane);
        if (lane >= 48) op[63 - lane] = 2047 - (int)(unsigned)(ck & 0xFFFFull);
    } else {
        unsigned taken = 0u;
        for (int r = 0; r < KNN; ++r) {
            unsigned long long best = 0ull;
            #pragma unroll
            for (int t = 0; t < 32; ++t) {
                if (!((taken >> t) & 1u)) {
                    int m = (t << 6) | lane;
                    unsigned long long ck = ((unsigned long long)key[t] << 16) | (unsigned)(2047 - m);
                    if (ck > best) best = ck;
                }
            }
            #pragma unroll
            for (int d = 1; d < 64; d <<= 1) {
                unsigned long long o = shflx_u64(best, d);
                if (o > best) best = o;
            }
            int m = 2047 - (int)(unsigned)(best & 0xFFFFull);
            if (lane == 0) op[r] = m;
            if ((m & 63) == lane) taken |= 1u << (m >> 6);
        }
    }
}

// ---------------------------------------------------------------- edge conv + max over k -> hcatT[:,0:64] bf16
__global__ __launch_bounds__(256) void edge_conv_kernel(const float* __restrict__ x, const int* __restrict__ idx,
                                                        const float* __restrict__ Wec, const float* __restrict__ bec,
                                                        unsigned short* __restrict__ hcatT) {
    int tid = threadIdx.x;
    int g = tid >> 6, o = tid & 63;
    int p = blockIdx.x * 4 + g;
    int b = p >> 11;
    __shared__ float nb[4][KNN][3];
    __shared__ float ctr[4][3];
    if (o < KNN) {
        int j = idx[(size_t)p * KNN + o];
        const float* xp = x + ((size_t)b * NP + j) * 3;
        nb[g][o][0] = xp[0]; nb[g][o][1] = xp[1]; nb[g][o][2] = xp[2];
    }
    if (o >= KNN && o < KNN + 3) ctr[g][o - KNN] = x[(size_t)p * 3 + (o - KNN)];
    __syncthreads();
    float w0 = Wec[o * 6 + 0], w1 = Wec[o * 6 + 1], w2 = Wec[o * 6 + 2];
    float w3 = Wec[o * 6 + 3], w4 = Wec[o * 6 + 4], w5 = Wec[o * 6 + 5];
    float c0 = ctr[g][0], c1 = ctr[g][1], c2 = ctr[g][2];
    float base = bec[o] + w3 * c0 + w4 * c1 + w5 * c2;
    float m = -3.4e38f;
    #pragma unroll
    for (int k = 0; k < KNN; ++k) {
        float v = base + w0 * (nb[g][k][0] - c0) + w1 * (nb[g][k][1] - c1) + w2 * (nb[g][k][2] - c2);
        v = v > 0.f ? v : 0.2f * v;
        m = fmaxf(m, v);
    }
    hcatT[(size_t)p * 512 + o] = f2bf(m);
}

// ---------------------------------------------------------------- graph max pool, bf16 [pt][ch] -> bf16 [pt][C]
__global__ __launch_bounds__(256) void pool_bf16_kernel(const unsigned short* __restrict__ src, int s_coff,
                                                        const int* __restrict__ idx,
                                                        unsigned short* __restrict__ dst, int C) {
    int tid = threadIdx.x, wv = tid >> 6, lane = tid & 63;
    int p = blockIdx.x * 4 + wv;
    int b = p >> 11;
    const int* ip = idx + (size_t)p * KNN;
    const unsigned short* sb = src + (size_t)b * NP * 512 + s_coff;
    for (int c0 = 0; c0 < C; c0 += 64) {
        int ch = c0 + lane;
        float m = -3.4e38f;
        #pragma unroll
        for (int k = 0; k < KNN; ++k) {
            int j = ip[k];
            m = fmaxf(m, bf2f(sb[(size_t)j * 512 + ch]));
        }
        dst[(size_t)p * C + ch] = f2bf(m);
    }
}

// ---------------------------------------------------------------- conv1 MFMA: 128pts x 64ch, K=64
__global__ __launch_bounds__(256) void mfma_conv64_kernel(const unsigned short* __restrict__ A,
                                                          const unsigned short* __restrict__ W,
                                                          const float* __restrict__ bias,
                                                          unsigned short* __restrict__ hcatT, int coff) {
    __shared__ unsigned short As[128][72];
    __shared__ unsigned short Bs[64][72];
    int m0 = blockIdx.x * 128, b = blockIdx.z;
    int tid = threadIdx.x;
    int lane = tid & 63, wave = tid >> 6;
    int wr = wave >> 1, wc = wave & 1;
    int quad = lane >> 4, l16 = lane & 15;
    {
        int r = tid >> 1, s = (tid & 1) * 32;
        const unsigned short* ap = A + (size_t)b * NP * 64 + (size_t)(m0 + r) * 64 + s;
        uint4 v0 = *(const uint4*)(ap);
        uint4 v1 = *(const uint4*)(ap + 8);
        uint4 v2 = *(const uint4*)(ap + 16);
        uint4 v3 = *(const uint4*)(ap + 24);
        *(uint4*)&As[r][s] = v0; *(uint4*)&As[r][s + 8] = v1;
        *(uint4*)&As[r][s + 16] = v2; *(uint4*)&As[r][s + 24] = v3;
    }
    {
        int r = tid >> 2, s = (tid & 3) * 16;
        const unsigned short* wp = W + r * 64 + s;
        *(uint4*)&Bs[r][s] = *(const uint4*)wp;
        *(uint4*)&Bs[r][s + 8] = *(const uint4*)(wp + 8);
    }
    __syncthreads();
    f32x4 acc[4][2] = {};
    #pragma unroll
    for (int k0 = 0; k0 < 64; k0 += 32) {
        bf16x8 af[4], bfv[2];
        #pragma unroll
        for (int i = 0; i < 4; ++i) af[i] = *(const bf16x8*)&As[wr * 64 + i * 16 + l16][k0 + quad * 8];
        #pragma unroll
        for (int j = 0; j < 2; ++j) bfv[j] = *(const bf16x8*)&Bs[wc * 32 + j * 16 + l16][k0 + quad * 8];
        #pragma unroll
        for (int i = 0; i < 4; ++i)
            #pragma unroll
            for (int j = 0; j < 2; ++j)
                acc[i][j] = __builtin_amdgcn_mfma_f32_16x16x32_bf16(af[i], bfv[j], acc[i][j], 0, 0, 0);
    }
    #pragma unroll
    for (int i = 0; i < 4; ++i) {
        #pragma unroll
        for (int r = 0; r < 4; ++r) {
            int pt = m0 + wr * 64 + i * 16 + quad * 4 + r;
            #pragma unroll
            for (int j = 0; j < 2; ++j) {
                int ch = wc * 32 + j * 16 + l16;
                float v = acc[i][j][r] + bias[ch];
                v = v > 0.f ? v : 0.2f * v;
                hcatT[((size_t)b * NP + pt) * 512 + coff + ch] = f2bf(v);
            }
        }
    }
}

// ---------------------------------------------------------------- weight/bias cast + xm init (one launch)
__global__ __launch_bounds__(256) void wcast_kernel(const float* __restrict__ Wf, const float* __restrict__ Wc3,
                                                    const float* __restrict__ Wk, const float* __restrict__ Wv,
                                                    const float* __restrict__ bk, const float* __restrict__ bv,
                                                    const float* __restrict__ Wc1, const float* __restrict__ Wc2,
                                                    const float* __restrict__ Wq, const float* __restrict__ Wo,
                                                    const float* __restrict__ Wff1, const float* __restrict__ Wff2,
                                                    unsigned short* __restrict__ WfB, unsigned short* __restrict__ Wc3B,
                                                    unsigned short* __restrict__ WkvB, float* __restrict__ bkv,
                                                    unsigned short* __restrict__ Wc1B, unsigned short* __restrict__ Wc2B,
                                                    unsigned short* __restrict__ WtB, unsigned short* __restrict__ Wff1B,
                                                    unsigned short* __restrict__ Wff2B,
                                                    unsigned* __restrict__ xmk) {
    int id = blockIdx.x * 256 + threadIdx.x;
    if (id < 262144) { WfB[id] = f2bf(Wf[id]); return; }
    int j = id - 262144;
    if (j < 32768) { Wc3B[j] = f2bf(Wc3[j]); return; }
    j -= 32768;
    if (j < 524288) {
        int l = j >> 17, r = j & 131071;
        float v = (r < 65536) ? Wk[(size_t)(l * 2 + 1) * 65536 + r]
                              : Wv[(size_t)(l * 2 + 1) * 65536 + (r - 65536)];
        WkvB[j] = f2bf(v);
        return;
    }
    j -= 524288;
    if (j < 2048) {
        int l = j >> 9, r = j & 511;
        bkv[j] = (r < 256) ? bk[(l * 2 + 1) * 256 + r] : bv[(l * 2 + 1) * 256 + (r - 256)];
        return;
    }
    j -= 2048;
    if (j < 4096) { Wc1B[j] = f2bf(Wc1[j]); return; }
    j -= 4096;
    if (j < 8192) { Wc2B[j] = f2bf(Wc2[j]); return; }
    j -= 8192;
    if (j < 4096) { xmk[j] = 0u; return; }
    j -= 4096;
    if (j < 1572864) {
        int l = j / 393216;
        int r = j - l * 393216;
        int m = r >> 16, c = r & 65535;
        float v;
        if (m == 0)      v = Wq[(size_t)(l * 2 + 0) * 65536 + c];
        else if (m == 1) v = Wk[(size_t)(l * 2 + 0) * 65536 + c];
        else if (m == 2) v = Wv[(size_t)(l * 2 + 0) * 65536 + c];
        else if (m == 3) v = Wo[(size_t)(l * 2 + 0) * 65536 + c];
        else if (m == 4) v = Wq[(size_t)(l * 2 + 1) * 65536 + c];
        else             v = Wo[(size_t)(l * 2 + 1) * 65536 + c];
        WtB[j] = f2bf(v);
        return;
    }
    j -= 1572864;
    if (j < 524288) { Wff1B[j] = f2bf(Wff1[j]); return; }
    j -= 524288;
    if (j < 524288) { Wff2B[j] = f2bf(Wff2[j]); return; }
}

// ---------------------------------------------------------------- int8 per-row quantization of tail weights
// rows: [0,6144) WtB (K=256), [6144,8192) Wff1B (K=256), [8192,9216) Wff2B (K=512)
__global__ __launch_bounds__(256) void wquant_kernel(const unsigned short* __restrict__ WtB,
                                                     const unsigned short* __restrict__ Wff1B,
                                                     const unsigned short* __restrict__ Wff2B,
                                                     char* __restrict__ WtI, float* __restrict__ StW,
                                                     char* __restrict__ FF1I, float* __restrict__ SF1,
                                                     char* __restrict__ FF2I, float* __restrict__ SF2) {
    int tid = threadIdx.x, wv = tid >> 6, lane = tid & 63;
    int row = blockIdx.x * 4 + wv;
    const unsigned short* src;
    char* dst;
    float* sc;
    int K;
    if (row < 6144)      { src = WtB + (size_t)row * 256; dst = WtI + (size_t)row * 256; sc = StW + row; K = 256; }
    else if (row < 8192) { int r = row - 6144; src = Wff1B + (size_t)r * 256; dst = FF1I + (size_t)r * 256; sc = SF1 + r; K = 256; }
    else                 { int r = row - 8192; src = Wff2B + (size_t)r * 512; dst = FF2I + (size_t)r * 512; sc = SF2 + r; K = 512; }
    int per = K >> 6;
    float w[8];
    float mx = 0.f;
    for (int e = 0; e < per; ++e) { w[e] = bf2f(src[lane * per + e]); mx = fmaxf(mx, fabsf(w[e])); }
    #pragma unroll
    for (int off = 1; off < 64; off <<= 1) mx = fmaxf(mx, __shfl_xor(mx, off));
    float s = fmaxf(mx, 1e-30f) * (1.0f / 127.0f);
    float inv = 1.0f / s;
    unsigned pk[2] = {0u, 0u};
    for (int e = 0; e < per; ++e) {
        int q = (int)rintf(w[e] * inv);
        q = q > 127 ? 127 : (q < -127 ? -127 : q);
        pk[e >> 2] |= ((unsigned)(q & 255)) << (8 * (e & 3));
    }
    ((unsigned*)dst)[lane * (per >> 2)] = pk[0];
    if (per == 8) ((unsigned*)dst)[lane * 2 + 1] = pk[1];
    if (lane == 0) *sc = s;
}

// ---------------------------------------------------------------- generic bf16 MFMA GEMM (encoder)
__global__ __launch_bounds__(256) void mfma_gemm_kernel(const unsigned short* __restrict__ A, size_t a_bstride,
                                                        const unsigned short* __restrict__ B, size_t b_bstride,
                                                        const float* __restrict__ bias, int bias_per_m,
                                                        void* __restrict__ C, size_t c_bstride, int c_rstride,
                                                        int K, int act, int out_bf16,
                                                        unsigned* __restrict__ xmk, int domax) {
    __shared__ unsigned short As[128][40];
    __shared__ unsigned short Bs[128][40];
    int m0 = blockIdx.x * 128, n0 = blockIdx.y * 128, b = blockIdx.z;
    int tid = threadIdx.x;
    int lane = tid & 63, wave = tid >> 6;
    int wr = wave >> 1, wc = wave & 1;
    int quad = lane >> 4, l16 = lane & 15;
    int r0 = tid >> 2, kc0 = (tid & 3) * 8;
    f32x4 acc[4][4] = {};
    const unsigned short* Ab = A + (size_t)b * a_bstride;
    const unsigned short* Bb = B + (size_t)b * b_bstride;
    for (int k0 = 0; k0 < K; k0 += 32) {
        uint4 a0 = *(const uint4*)(Ab + (size_t)(m0 + r0) * K + k0 + kc0);
        uint4 a1 = *(const uint4*)(Ab + (size_t)(m0 + r0 + 64) * K + k0 + kc0);
        uint4 b0 = *(const uint4*)(Bb + (size_t)(n0 + r0) * K + k0 + kc0);
        uint4 b1 = *(const uint4*)(Bb + (size_t)(n0 + r0 + 64) * K + k0 + kc0);
        __syncthreads();
        *(uint4*)&As[r0][kc0] = a0;
        *(uint4*)&As[r0 + 64][kc0] = a1;
        *(uint4*)&Bs[r0][kc0] = b0;
        *(uint4*)&Bs[r0 + 64][kc0] = b1;
        __syncthreads();
        bf16x8 af[4], bfv[4];
        #pragma unroll
        for (int i = 0; i < 4; ++i) af[i] = *(const bf16x8*)&As[wr * 64 + i * 16 + l16][quad * 8];
        #pragma unroll
        for (int j = 0; j < 4; ++j) bfv[j] = *(const bf16x8*)&Bs[wc * 64 + j * 16 + l16][quad * 8];
        #pragma unroll
        for (int i = 0; i < 4; ++i)
            #pragma unroll
            for (int j = 0; j < 4; ++j)
                acc[i][j] = __builtin_amdgcn_mfma_f32_16x16x32_bf16(af[i], bfv[j], acc[i][j], 0, 0, 0);
    }
    if (domax) {
        #pragma unroll
        for (int i = 0; i < 4; ++i) {
            #pragma unroll
            for (int r = 0; r < 4; ++r) {
                int m = m0 + wr * 64 + i * 16 + quad * 4 + r;
                float v = fmaxf(fmaxf(acc[i][0][r], acc[i][1][r]), fmaxf(acc[i][2][r], acc[i][3][r]));
                v += bias[m];
                #pragma unroll
                for (int off = 1; off <= 8; off <<= 1) v = fmaxf(v, __shfl_xor(v, off));
                if (l16 == 0) atomicMax(&xmk[(size_t)b * 512 + m], fmono(v));
            }
        }
        return;
    }
    #pragma unroll
    for (int i = 0; i < 4; ++i) {
        #pragma unroll
        for (int r = 0; r < 4; ++r) {
            int m = m0 + wr * 64 + i * 16 + quad * 4 + r;
            float bm = bias_per_m ? bias[m] : 0.f;
            #pragma unroll
            for (int j = 0; j < 4; ++j) {
                int n = n0 + wc * 64 + j * 16 + l16;
                float v = acc[i][j][r] + (bias_per_m ? bm : bias[n]);
                if (act) v = v > 0.f ? v : 0.2f * v;
                size_t off = (size_t)b * c_bstride + (size_t)m * c_rstride + n;
                if (out_bf16) ((unsigned short*)C)[off] = f2bf(v);
                else          ((float*)C)[off] = v;
            }
        }
    }
}

// ---------------------------------------------------------------- KV for ALL layers
__global__ __launch_bounds__(256) void mfma_kv_all_kernel(const unsigned short* __restrict__ A,
                                                          const unsigned short* __restrict__ W,
                                                          const float* __restrict__ bkv,
                                                          unsigned short* __restrict__ KVall) {
    __shared__ unsigned short As[128][40];
    __shared__ unsigned short Bs[128][40];
    int m0 = blockIdx.x * 128;
    int nb = blockIdx.y & 3, l = blockIdx.y >> 2;
    int n0 = nb * 128;
    int b = blockIdx.z;
    int tid = threadIdx.x;
    int lane = tid & 63, wave = tid >> 6;
    int wr = wave >> 1, wc = wave & 1;
    int quad = lane >> 4, l16 = lane & 15;
    int r0 = tid >> 2, kc0 = (tid & 3) * 8;
    f32x4 acc[4][4] = {};
    const unsigned short* Ab = A + (size_t)b * NP * 256;
    const unsigned short* Bb = W + (size_t)l * 131072;
    const float* bias = bkv + l * 512;
    for (int k0 = 0; k0 < 256; k0 += 32) {
        uint4 a0 = *(const uint4*)(Ab + (size_t)(m0 + r0) * 256 + k0 + kc0);
        uint4 a1 = *(const uint4*)(Ab + (size_t)(m0 + r0 + 64) * 256 + k0 + kc0);
        uint4 b0 = *(const uint4*)(Bb + (size_t)(n0 + r0) * 256 + k0 + kc0);
        uint4 b1 = *(const uint4*)(Bb + (size_t)(n0 + r0 + 64) * 256 + k0 + kc0);
        __syncthreads();
        *(uint4*)&As[r0][kc0] = a0;
        *(uint4*)&As[r0 + 64][kc0] = a1;
        *(uint4*)&Bs[r0][kc0] = b0;
        *(uint4*)&Bs[r0 + 64][kc0] = b1;
        __syncthreads();
        bf16x8 af[4], bfv[4];
        #pragma unroll
        for (int i = 0; i < 4; ++i) af[i] = *(const bf16x8*)&As[wr * 64 + i * 16 + l16][quad * 8];
        #pragma unroll
        for (int j = 0; j < 4; ++j) bfv[j] = *(const bf16x8*)&Bs[wc * 64 + j * 16 + l16][quad * 8];
        #pragma unroll
        for (int i = 0; i < 4; ++i)
            #pragma unroll
            for (int j = 0; j < 4; ++j)
                acc[i][j] = __builtin_amdgcn_mfma_f32_16x16x32_bf16(af[i], bfv[j], acc[i][j], 0, 0, 0);
    }
    unsigned short* Cb = KVall + ((size_t)l * BN + b) * NP * 512;
    #pragma unroll
    for (int i = 0; i < 4; ++i) {
        #pragma unroll
        for (int r = 0; r < 4; ++r) {
            int m = m0 + wr * 64 + i * 16 + quad * 4 + r;
            #pragma unroll
            for (int j = 0; j < 4; ++j) {
                int n = n0 + wc * 64 + j * 16 + l16;
                Cb[(size_t)m * 512 + n] = f2bf(acc[i][j][r] + bias[n]);
            }
        }
    }
}

// ---------------------------------------------------------------- q0 row + fold layer-0 QKV projection
__global__ __launch_bounds__(256) void pc_kernel(const unsigned* __restrict__ xmk, const float* __restrict__ Wpc,
                                                 const float* __restrict__ bpc,
                                                 const unsigned short* __restrict__ Wqkv,
                                                 const float* __restrict__ bq0, const float* __restrict__ bk0,
                                                 const float* __restrict__ bv0,
                                                 float* __restrict__ q, float* __restrict__ Qs,
                                                 float* __restrict__ Ks, float* __restrict__ Vs) {
    int row = blockIdx.x, tid = threadIdx.x;
    int id = row * 256 + tid;
    int b = row >> 3, i = row & 7;
    const unsigned* xr = xmk + b * 512 + i * 64;
    const float* w = Wpc + (size_t)tid * 64;
    float acc = bpc[tid];
    #pragma unroll
    for (int e = 0; e < 64; ++e) acc += funmono(xr[e]) * w[e];
    float qv = acc > 0.f ? acc : 0.2f * acc;
    q[id] = qv;
    __shared__ __align__(16) float a[256];
    a[tid] = qv;
    __syncthreads();
    Qs[id] = bq0[tid] + gemv_dot(Wqkv + (size_t)tid * 256, a, 32);
    Ks[id] = bk0[tid] + gemv_dot(Wqkv + 65536 + (size_t)tid * 256, a, 32);
    Vs[id] = bv0[tid] + gemv_dot(Wqkv + 131072 + (size_t)tid * 256, a, 32);
}

// ---------------------------------------------------------------- memB = bf16(act(x @ Wpi.T + bpi))
__global__ __launch_bounds__(256) void mem_kernel(const float* __restrict__ x, const float* __restrict__ Wpi,
                                                  const float* __restrict__ bpi, unsigned short* __restrict__ memB) {
    size_t id = (size_t)blockIdx.x * 256 + threadIdx.x;
    int p = (int)(id & 255);
    size_t pt = id >> 8;
    float x0 = x[pt * 3 + 0], x1 = x[pt * 3 + 1], x2 = x[pt * 3 + 2];
    float v = bpi[p] + x0 * Wpi[p * 3 + 0] + x1 * Wpi[p * 3 + 1] + x2 * Wpi[p * 3 + 2];
    v = v > 0.f ? v : 0.2f * v;
    memB[id] = f2bf(v);
}

// ---------------------------------------------------------------- self-attn + O-proj + res + LN + cross-Q-proj (1024 thr)
__global__ __launch_bounds__(1024) void attn_ln_kernel(const float* __restrict__ Qs, const float* __restrict__ Ks,
                                                       const float* __restrict__ Vs,
                                                       const unsigned short* __restrict__ WoB,
                                                       const float* __restrict__ bo, const float* __restrict__ res,
                                                       const float* __restrict__ g, const float* __restrict__ bt,
                                                       const unsigned short* __restrict__ Wq1B,
                                                       const float* __restrict__ bq1,
                                                       float* __restrict__ out, float* __restrict__ Qc) {
    int row = blockIdx.x, tid = threadIdx.x;
    int b = row >> 3;
    __shared__ float Kl[2048], Vl[2048];
    __shared__ __align__(16) float qr[256];
    __shared__ float sc[64];
    __shared__ __align__(16) float r[256];
    __shared__ __align__(16) float aout[256];
    __shared__ float red[1024];
    for (int t = tid; t < 2048; t += 1024) {
        Kl[t] = Ks[(size_t)b * 2048 + t];
        Vl[t] = Vs[(size_t)b * 2048 + t];
    }
    if (tid < 256) qr[tid] = Qs[(size_t)row * 256 + tid];
    __syncthreads();
    const float scale = 0.17677669529663687f;
    {
        int pair = tid >> 4, part = tid & 15;
        int h = pair >> 3, k = pair & 7;
        int d = part * 2;
        float dot = qr[h * 32 + d] * Kl[k * 256 + h * 32 + d]
                  + qr[h * 32 + d + 1] * Kl[k * 256 + h * 32 + d + 1];
        dot += __shfl_xor(dot, 1);
        dot += __shfl_xor(dot, 2);
        dot += __shfl_xor(dot, 4);
        dot += __shfl_xor(dot, 8);
        if (part == 0) sc[pair] = dot * scale;
    }
    __syncthreads();
    if (tid < 64) {
        float v = sc[tid];
        float m = v;
        #pragma unroll
        for (int off = 1; off < 8; off <<= 1) m = fmaxf(m, __shfl_xor(m, off));
        float e = __expf(v - m);
        float s = e;
        #pragma unroll
        for (int off = 1; off < 8; off <<= 1) s += __shfl_xor(s, off);
        sc[tid] = e / s;
    }
    __syncthreads();
    if (tid < 256) {
        int h = tid >> 5;
        float acc = 0.f;
        #pragma unroll
        for (int k = 0; k < 8; ++k) acc += sc[h * 8 + k] * Vl[k * 256 + tid];
        r[tid] = acc;
    }
    __syncthreads();
    int o4 = tid >> 2, p4 = tid & 3;
    float v;
    {
        float acc = gemv_dot(WoB + (size_t)o4 * 256 + p4 * 64, r + p4 * 64, 8);
        acc += __shfl_xor(acc, 1);
        acc += __shfl_xor(acc, 2);
        v = (p4 == 0) ? (bo[o4] + acc + res[(size_t)row * 256 + o4]) : 0.f;
    }
    red[tid] = v; __syncthreads();
    for (int s = 512; s; s >>= 1) { if (tid < s) red[tid] += red[tid + s]; __syncthreads(); }
    float mean = red[0] * (1.0f / 256.0f);
    __syncthreads();
    float dv = (p4 == 0) ? v - mean : 0.f;
    red[tid] = dv * dv; __syncthreads();
    for (int s = 512; s; s >>= 1) { if (tid < s) red[tid] += red[tid + s]; __syncthreads(); }
    float var = red[0] * (1.0f / 256.0f);
    if (p4 == 0) {
        float oln = g[o4] * dv * rsqrtf(var + 1e-5f) + bt[o4];
        out[(size_t)row * 256 + o4] = oln;
        aout[o4] = oln;
    }
    __syncthreads();
    {
        float qacc = gemv_dot(Wq1B + (size_t)o4 * 256 + p4 * 64, aout + p4 * 64, 8);
        qacc += __shfl_xor(qacc, 1);
        qacc += __shfl_xor(qacc, 2);
        if (p4 == 0) Qc[(size_t)row * 256 + o4] = bq1[o4] + qacc;
    }
}

// ---------------------------------------------------------------- cross-attn pass 1: 16 key-blocks of 128
__global__ __launch_bounds__(256) void ca_part_kernel(const float* __restrict__ Qc,
                                                      const unsigned short* __restrict__ KVl,
                                                      float* __restrict__ part) {
    int kb = blockIdx.x, h = blockIdx.y, b = blockIdx.z;
    int tid = threadIdx.x;
    __shared__ float q[8][32];
    __shared__ __align__(16) float S[8][128];
    __shared__ float om[8][8][32];
    const float scale = 0.17677669529663687f;
    {
        int i = tid >> 5, d = tid & 31;
        q[i][d] = Qc[(size_t)(b * 8 + i) * 256 + h * 32 + d];
    }
    __syncthreads();
    {
        int kk = tid & 127, half = tid >> 7;
        int k = kb * 128 + kk;
        const unsigned short* kp = KVl + ((size_t)b * NP + k) * 512 + h * 32;
        float kd[32];
        #pragma unroll
        for (int u = 0; u < 4; ++u) {
            uint4 raw = *(const uint4*)(kp + u * 8);
            unsigned w0 = raw.x, w1 = raw.y, w2 = raw.z, w3 = raw.w;
            kd[u * 8 + 0] = __uint_as_float(w0 << 16); kd[u * 8 + 1] = __uint_as_float(w0 & 0xFFFF0000u);
            kd[u * 8 + 2] = __uint_as_float(w1 << 16); kd[u * 8 + 3] = __uint_as_float(w1 & 0xFFFF0000u);
            kd[u * 8 + 4] = __uint_as_float(w2 << 16); kd[u * 8 + 5] = __uint_as_float(w2 & 0xFFFF0000u);
            kd[u * 8 + 6] = __uint_as_float(w3 << 16); kd[u * 8 + 7] = __uint_as_float(w3 & 0xFFFF0000u);
        }
        #pragma unroll
        for (int i = 0; i < 4; ++i) {
            int ri = half * 4 + i;
            float dot = 0.f;
            #pragma unroll
            for (int d = 0; d < 32; ++d) dot += q[ri][d] * kd[d];
            S[ri][kk] = dot * scale;
        }
    }
    __syncthreads();
    float* pout = part + (((size_t)(b * NH + h)) * 16 + kb) * 288;
    {
        int i = tid >> 5, l32 = tid & 31;
        float m = -3.4e38f;
        #pragma unroll
        for (int t = 0; t < 4; ++t) m = fmaxf(m, S[i][l32 + t * 32]);
        #pragma unroll
        for (int off = 16; off; off >>= 1) m = fmaxf(m, __shfl_xor(m, off));
        float s = 0.f;
        #pragma unroll
        for (int t = 0; t < 4; ++t) {
            float e = __expf(S[i][l32 + t * 32] - m);
            S[i][l32 + t * 32] = e;
            s += e;
        }
        #pragma unroll
        for (int off = 16; off; off >>= 1) s += __shfl_xor(s, off);
        if (l32 == 0) { pout[i] = m; pout[8 + i] = s; }
    }
    __syncthreads();
    {
        int d = tid & 31, grp = tid >> 5;
        const unsigned short* Vb = KVl + ((size_t)b * NP + kb * 128) * 512 + 256 + h * 32 + d;
        float acc[8] = {};
        #pragma unroll 4
        for (int t = 0; t < 16; ++t) {
            int kk = grp * 16 + t;
            float v = bf2f(Vb[(size_t)kk * 512]);
            #pragma unroll
            for (int i = 0; i < 8; ++i) acc[i] += S[i][kk] * v;
        }
        #pragma unroll
        for (int i = 0; i < 8; ++i) om[grp][i][d] = acc[i];
    }
    __syncthreads();
    {
        int i = tid >> 5, d = tid & 31;
        float sum = 0.f;
        #pragma unroll
        for (int g = 0; g < 8; ++g) sum += om[g][i][d];
        pout[16 + i * 32 + d] = sum;
    }
}

// ---------------------------------------------------------------- combine + O-proj + LN + FF + LN [+ next-layer QKV | final LN+Wcm]
// int8 per-row-scaled weights (1024 thr)
__global__ __launch_bounds__(1024) void combine_ff_kernel(const float* __restrict__ part,
                                                          const char* __restrict__ WoI, const float* __restrict__ sWo,
                                                          const float* __restrict__ bo, const float* __restrict__ res,
                                                          const float* __restrict__ g2, const float* __restrict__ b2t,
                                                          const char* __restrict__ W1I, const float* __restrict__ sW1,
                                                          const float* __restrict__ b1,
                                                          const char* __restrict__ W2I, const float* __restrict__ sW2,
                                                          const float* __restrict__ b2,
                                                          const float* __restrict__ g3, const float* __restrict__ b3t,
                                                          float* __restrict__ out,
                                                          int is_last, const float* __restrict__ lnfg,
                                                          const float* __restrict__ lnfb, const float* __restrict__ Wcm,
                                                          const float* __restrict__ bcm, float* __restrict__ finout,
                                                          const char* __restrict__ WqkvnI, const float* __restrict__ sQn,
                                                          const float* __restrict__ bqn, const float* __restrict__ bkn,
                                                          const float* __restrict__ bvn,
                                                          float* __restrict__ Qs, float* __restrict__ Ks,
                                                          float* __restrict__ Vs) {
    int row = blockIdx.x, tid = threadIdx.x;
    int b = row >> 3, i = row & 7;
    __shared__ __align__(16) float r[256];
    __shared__ __align__(16) float a[256];
    __shared__ __align__(16) float hbuf[512];
    __shared__ float red[1024];
    // phase 1: combine cross-attn partials (4 threads per (h,d), each 4 key-blocks)
    {
        int h = tid >> 7, rem = tid & 127, d = rem >> 2, g = rem & 3;
        const float* pb = part + (size_t)(b * NH + h) * 16 * 288;
        float M = -3.4e38f;
        #pragma unroll
        for (int t = 0; t < 4; ++t) M = fmaxf(M, pb[(g * 4 + t) * 288 + i]);
        M = fmaxf(M, __shfl_xor(M, 1));
        M = fmaxf(M, __shfl_xor(M, 2));
        float L = 0.f, O = 0.f;
        #pragma unroll
        for (int t = 0; t < 4; ++t) {
            int kb = g * 4 + t;
            float w = __expf(pb[kb * 288 + i] - M);
            L += pb[kb * 288 + 8 + i] * w;
            O += pb[kb * 288 + 16 + i * 32 + d] * w;
        }
        L += __shfl_xor(L, 1); L += __shfl_xor(L, 2);
        O += __shfl_xor(O, 1); O += __shfl_xor(O, 2);
        if (g == 0) r[h * 32 + d] = O / L;
    }
    __syncthreads();
    int o4 = tid >> 2, p4 = tid & 3;
    // phase 2: O-proj (4 thr/out, int8) + residual + LN
    float v;
    {
        float acc = gemv_i8(WoI + (size_t)o4 * 256 + p4 * 64, r + p4 * 64, 4);
        acc += __shfl_xor(acc, 1);
        acc += __shfl_xor(acc, 2);
        v = (p4 == 0) ? (bo[o4] + sWo[o4] * acc + res[(size_t)row * 256 + o4]) : 0.f;
    }
    red[tid] = v; __syncthreads();
    for (int s = 512; s; s >>= 1) { if (tid < s) red[tid] += red[tid + s]; __syncthreads(); }
    float mean = red[0] * (1.0f / 256.0f);
    __syncthreads();
    float dv = (p4 == 0) ? v - mean : 0.f;
    red[tid] = dv * dv; __syncthreads();
    for (int s = 512; s; s >>= 1) { if (tid < s) red[tid] += red[tid + s]; __syncthreads(); }
    float var = red[0] * (1.0f / 256.0f);
    if (p4 == 0) a[o4] = g2[o4] * dv * rsqrtf(var + 1e-5f) + b2t[o4];
    __syncthreads();
    // phase 3: FF1 (2 thr/out, int8, 128-elem partials)
    {
        int o = tid >> 1, p = tid & 1;
        float acc = gemv_i8(W1I + (size_t)o * 256 + p * 128, a + p * 128, 8);
        acc += __shfl_xor(acc, 1);
        if (p == 0) { float t = b1[o] + sW1[o] * acc; hbuf[o] = t > 0.f ? t : 0.2f * t; }
    }
    __syncthreads();
    // phase 4: FF2 (4 thr/out, int8, K=512) + residual + LN
    float vF;
    {
        float acc = gemv_i8(W2I + (size_t)o4 * 512 + p4 * 128, hbuf + p4 * 128, 8);
        acc += __shfl_xor(acc, 1);
        acc += __shfl_xor(acc, 2);
        vF = (p4 == 0) ? (b2[o4] + sW2[o4] * acc + a[o4]) : 0.f;
    }
    red[tid] = vF; __syncthreads();
    for (int s = 512; s; s >>= 1) { if (tid < s) red[tid] += red[tid + s]; __syncthreads(); }
    float mean2 = red[0] * (1.0f / 256.0f);
    __syncthreads();
    float dv2 = (p4 == 0) ? vF - mean2 : 0.f;
    red[tid] = dv2 * dv2; __syncthreads();
    for (int s = 512; s; s >>= 1) { if (tid < s) red[tid] += red[tid + s]; __syncthreads(); }
    float var2 = red[0] * (1.0f / 256.0f);
    float tln = 0.f;
    if (p4 == 0) {
        tln = g3[o4] * dv2 * rsqrtf(var2 + 1e-5f) + b3t[o4];
        r[o4] = tln;
    }
    __syncthreads();
    if (!is_last) {
        if (p4 == 0) out[(size_t)row * 256 + o4] = tln;
        // next-layer QKV from tln row in r[]: 768 full-dot threads (int8)
        if (tid < 768) {
            int which = tid >> 8, o = tid & 255;
            float acc = gemv_i8(WqkvnI + (size_t)which * 65536 + (size_t)o * 256, r, 16);
            float bb = (which == 0) ? bqn[o] : (which == 1) ? bkn[o] : bvn[o];
            float* dst = (which == 0) ? Qs : (which == 1) ? Ks : Vs;
            dst[(size_t)row * 256 + o] = bb + sQn[which * 256 + o] * acc;
        }
        return;
    }
    // final LN + Wcm
    float tf = (tid < 256) ? r[tid] : 0.f;
    red[tid] = tf; __syncthreads();
    for (int s = 512; s; s >>= 1) { if (tid < s) red[tid] += red[tid + s]; __syncthreads(); }
    float mean3 = red[0] * (1.0f / 256.0f);
    __syncthreads();
    float d3 = (tid < 256) ? tf - mean3 : 0.f;
    red[tid] = d3 * d3; __syncthreads();
    for (int s = 512; s; s >>= 1) { if (tid < s) red[tid] += red[tid + s]; __syncthreads(); }
    float var3 = red[0] * (1.0f / 256.0f);
    if (tid < 256) a[tid] = lnfg[tid] * d3 * rsqrtf(var3 + 1e-5f) + lnfb[tid];
    __syncthreads();
    if (tid < 64) {
        const float4* w4 = (const float4*)(Wcm + (size_t)tid * 256);
        const float4* a4 = (const float4*)a;
        float acc = bcm[tid];
        #pragma unroll 8
        for (int c = 0; c < 64; ++c) {
            float4 av = a4[c], wv = w4[c];
            acc += av.x * wv.x + av.y * wv.y + av.z * wv.z + av.w * wv.w;
        }
        finout[(size_t)b * 512 + i * 64 + tid] = acc;
    }
}

// ================================================================ host
extern "C" void kernel_launch(void* const* d_in, const int* in_sizes, int n_in,
                              void* d_out, int out_size, void* d_ws, size_t ws_size,
                              hipStream_t stream) {
    const float* x    = (const float*)d_in[0];
    const float* Wec  = (const float*)d_in[1];
    const float* bec  = (const float*)d_in[2];
    const float* Wc1  = (const float*)d_in[3];
    const float* bc1  = (const float*)d_in[4];
    const float* Wc2  = (const float*)d_in[5];
    const float* bc2  = (const float*)d_in[6];
    const float* Wc3  = (const float*)d_in[7];
    const float* bc3  = (const float*)d_in[8];
    const float* Wf   = (const float*)d_in[9];
    const float* bf   = (const float*)d_in[10];
    const float* Wpc  = (const float*)d_in[11];
    const float* bpc  = (const float*)d_in[12];
    const float* Wpi  = (const float*)d_in[13];
    const float* bpi  = (const float*)d_in[14];
    const float* Wq   = (const float*)d_in[15];
    const float* bq   = (const float*)d_in[16];
    const float* Wk   = (const float*)d_in[17];
    const float* bk   = (const float*)d_in[18];
    const float* Wv   = (const float*)d_in[19];
    const float* bv   = (const float*)d_in[20];
    const float* Wo   = (const float*)d_in[21];
    const float* bo   = (const float*)d_in[22];
    const float* ln1g = (const float*)d_in[23];
    const float* ln1b = (const float*)d_in[24];
    const float* ln2g = (const float*)d_in[25];
    const float* ln2b = (const float*)d_in[26];
    const float* Wff1 = (const float*)d_in[27];
    const float* bff1 = (const float*)d_in[28];
    const float* Wff2 = (const float*)d_in[29];
    const float* bff2 = (const float*)d_in[30];
    const float* ln3g = (const float*)d_in[31];
    const float* ln3b = (const float*)d_in[32];
    const float* lnfg = (const float*)d_in[33];
    const float* lnfb = (const float*)d_in[34];
    const float* Wcm  = (const float*)d_in[35];
    const float* bcm  = (const float*)d_in[36];
    float* out = (float*)d_out;

    float* ws = (float*)d_ws;
    size_t off = 0;
    auto alloc = [&](size_t n) { float* p = ws + off; off += (n + 3) & ~(size_t)3; return p; };
    int*            idx   = (int*)alloc((size_t)BN * NP * KNN);
    unsigned short* hcatT = (unsigned short*)alloc((size_t)BN * NP * 512 / 2);
    unsigned short* poolT = (unsigned short*)alloc((size_t)BN * NP * 128 / 2);
    unsigned short* WfB   = (unsigned short*)alloc(262144 / 2);
    unsigned short* Wc1B  = (unsigned short*)alloc(4096 / 2);
    unsigned short* Wc2B  = (unsigned short*)alloc(8192 / 2);
    unsigned short* Wc3B  = (unsigned short*)alloc(32768 / 2);
    unsigned short* WkvB  = (unsigned short*)alloc(524288 / 2);
    float*          bkv   = alloc(2048);
    unsigned short* memB  = (unsigned short*)alloc((size_t)BN * NP * 256 / 2);
    unsigned short* KVall = (unsigned short*)alloc((size_t)NL * BN * NP * 512 / 2);
    unsigned*       xmk   = (unsigned*)alloc((size_t)BN * 512);
    unsigned short* WtB   = (unsigned short*)alloc(1572864 / 2);
    unsigned short* Wff1B = (unsigned short*)alloc(524288 / 2);
    unsigned short* Wff2B = (unsigned short*)alloc(524288 / 2);
    char*           WtI   = (char*)alloc(1572864 / 4);
    float*          StW   = alloc(6144);
    char*           FF1I  = (char*)alloc(524288 / 4);
    float*          SF1   = alloc(2048);
    char*           FF2I  = (char*)alloc(524288 / 4);
    float*          SF2   = alloc(1024);
    float*          qa    = alloc((size_t)BN * 8 * 256);
    float*          qb    = alloc((size_t)BN * 8 * 256);
    float*          Qs    = alloc((size_t)BN * 8 * 256);
    float*          Ks    = alloc((size_t)BN * 8 * 256);
    float*          Vs    = alloc((size_t)BN * 8 * 256);
    float*          Qc    = alloc((size_t)BN * 8 * 256);
    float*          part  = alloc((size_t)BN * NH * 16 * 288);

    // ---- weight casts + xm-key init, then int8 row-quant of tail weights ----
    wcast_kernel<<<13512, 256, 0, stream>>>(Wf, Wc3, Wk, Wv, bk, bv, Wc1, Wc2, Wq, Wo, Wff1, Wff2,
                                            WfB, Wc3B, WkvB, bkv, Wc1B, Wc2B, WtB, Wff1B, Wff2B, xmk);
    wquant_kernel<<<2304, 256, 0, stream>>>(WtB, Wff1B, Wff2B, WtI, StW, FF1I, SF1, FF2I, SF2);

    // ---- point-cloud encoder (all-bf16 [pt][ch] chain) ----
    knn_kernel<<<BN * NP / 4, 256, 0, stream>>>(x, idx);
    edge_conv_kernel<<<BN * NP / 4, 256, 0, stream>>>(x, idx, Wec, bec, hcatT);

    pool_bf16_kernel<<<BN * NP / 4, 256, 0, stream>>>(hcatT, 0, idx, poolT, 64);
    mfma_conv64_kernel<<<dim3(NP / 128, 1, BN), 256, 0, stream>>>(poolT, Wc1B, bc1, hcatT, 64);
    pool_bf16_kernel<<<BN * NP / 4, 256, 0, stream>>>(hcatT, 64, idx, poolT, 64);
    mfma_gemm_kernel<<<dim3(NP / 128, 1, BN), 256, 0, stream>>>(poolT, (size_t)NP * 64, Wc2B, 0,
                                                                bc2, 0, (void*)(hcatT + 128), (size_t)NP * 512, 512,
                                                                64, 1, 1, nullptr, 0);
    pool_bf16_kernel<<<BN * NP / 4, 256, 0, stream>>>(hcatT, 128, idx, poolT, 128);
    mfma_gemm_kernel<<<dim3(NP / 128, 2, BN), 256, 0, stream>>>(poolT, (size_t)NP * 128, Wc3B, 0,
                                                                bc3, 0, (void*)(hcatT + 256), (size_t)NP * 512, 512,
                                                                128, 1, 1, nullptr, 0);
    mfma_gemm_kernel<<<dim3(4, NP / 128, BN), 256, 0, stream>>>(WfB, 0, hcatT, (size_t)NP * 512,
                                                                bf, 1, nullptr, 0, 0,
                                                                512, 0, 0, xmk, 1);
    pc_kernel<<<BN * 8, 256, 0, stream>>>(xmk, Wpc, bpc, WtB, bq, bk, bv, qa, Qs, Ks, Vs);
    mem_kernel<<<BN * NP, 256, 0, stream>>>(x, Wpi, bpi, memB);
    mfma_kv_all_kernel<<<dim3(NP / 128, 4 * NL, BN), 256, 0, stream>>>(memB, WkvB, bkv, KVall);

    // ---- transformer layers (3 launches/layer; QKV folded into producer) ----
    for (int l = 0; l < NL; ++l) {
        const unsigned short* Wl = WtB + (size_t)l * 393216;
        const float* bo0 = bo + (l * 2 + 0) * 256;
        const float* bq1 = bq + (l * 2 + 1) * 256;
        const float* bo1 = bo + (l * 2 + 1) * 256;
        int last = (l == NL - 1);

        attn_ln_kernel<<<BN * 8, 1024, 0, stream>>>(Qs, Ks, Vs, Wl + 3 * 65536, bo0, qa,
                                                    ln1g + l * 256, ln1b + l * 256, Wl + 4 * 65536, bq1, qb, Qc);
        ca_part_kernel<<<dim3(16, NH, BN), 256, 0, stream>>>(Qc, KVall + (size_t)l * BN * NP * 512, part);
        combine_ff_kernel<<<BN * 8, 1024, 0, stream>>>(part,
                                                       WtI + (size_t)l * 393216 + 5 * 65536, StW + l * 1536 + 5 * 256,
                                                       bo1, qb,
                                                       ln2g + l * 256, ln2b + l * 256,
                                                       FF1I + (size_t)l * 131072, SF1 + l * 512, bff1 + l * 512,
                                                       FF2I + (size_t)l * 131072, SF2 + l * 256, bff2 + l * 256,
                                                       ln3g + l * 256, ln3b + l * 256, qa,
                                                       last, lnfg, lnfb, Wcm, bcm, out,
                                                       last ? nullptr : WtI + (size_t)(l + 1) * 393216,
                                                       last ? nullptr : StW + (l + 1) * 1536,
                                                       bq + ((l + 1) * 2) * 256, bk + ((l + 1) * 2) * 256,
                                                       bv + ((l + 1) * 2) * 256,
                                                       Qs, Ks, Vs);
    }

    (void)in_sizes; (void)n_in; (void)out_size; (void)ws_size;
}

// Round 12
// 495.893 us; speedup vs baseline: 1.1904x; 1.0431x over previous
//
#include <hip/hip_runtime.h>
#include <math.h>

#define BN 8
#define NP 2048
#define KNN 16
#define NL 4
#define NH 8

typedef __attribute__((ext_vector_type(8))) short bf16x8;
typedef __attribute__((ext_vector_type(4))) float f32x4;

__device__ __forceinline__ unsigned short f2bf(float f) {
    unsigned u = __float_as_uint(f);
    unsigned r = (u + 0x7FFFu + ((u >> 16) & 1u)) >> 16;
    return (unsigned short)r;
}
__device__ __forceinline__ float bf2f(unsigned short s) {
    return __uint_as_float(((unsigned)s) << 16);
}
__device__ __forceinline__ unsigned fmono(float f) {
    unsigned u = __float_as_uint(f);
    return (u & 0x80000000u) ? ~u : (u | 0x80000000u);
}
__device__ __forceinline__ float funmono(unsigned k) {
    return (k & 0x80000000u) ? __uint_as_float(k ^ 0x80000000u) : __uint_as_float(~k);
}

// bf16 weight-row dot (K8 groups of 8) vs fp32 vector in LDS; 4 accumulator chains.
__device__ __forceinline__ float gemv_dot(const unsigned short* __restrict__ wrow, const float* sm, int K8) {
    const uint4* w8 = (const uint4*)wrow;
    const float4* r4 = (const float4*)sm;
    float a0 = 0.f, a1 = 0.f, a2 = 0.f, a3 = 0.f;
    #pragma unroll 8
    for (int c = 0; c < K8; ++c) {
        uint4 wv = w8[c];
        float4 x0 = r4[c * 2], x1 = r4[c * 2 + 1];
        a0 += x0.x * __uint_as_float(wv.x << 16) + x0.y * __uint_as_float(wv.x & 0xFFFF0000u);
        a1 += x0.z * __uint_as_float(wv.y << 16) + x0.w * __uint_as_float(wv.y & 0xFFFF0000u);
        a2 += x1.x * __uint_as_float(wv.z << 16) + x1.y * __uint_as_float(wv.z & 0xFFFF0000u);
        a3 += x1.z * __uint_as_float(wv.w << 16) + x1.w * __uint_as_float(wv.w & 0xFFFF0000u);
    }
    return (a0 + a1) + (a2 + a3);
}

// int8 weight-row dot (K16 groups of 16) vs fp32 vector in LDS; caller applies row scale.
__device__ __forceinline__ float gemv_i8(const char* __restrict__ wrow, const float* sm, int K16) {
    const uint4* w16 = (const uint4*)wrow;
    const float4* r4 = (const float4*)sm;
    float a0 = 0.f, a1 = 0.f, a2 = 0.f, a3 = 0.f;
    #pragma unroll 4
    for (int c = 0; c < K16; ++c) {
        uint4 wv = w16[c];
        float4 x0 = r4[c * 4], x1 = r4[c * 4 + 1], x2 = r4[c * 4 + 2], x3 = r4[c * 4 + 3];
        a0 += x0.x * (float)(signed char)(wv.x) + x0.y * (float)(signed char)(wv.x >> 8)
            + x0.z * (float)(signed char)(wv.x >> 16) + x0.w * (float)(signed char)(wv.x >> 24);
        a1 += x1.x * (float)(signed char)(wv.y) + x1.y * (float)(signed char)(wv.y >> 8)
            + x1.z * (float)(signed char)(wv.y >> 16) + x1.w * (float)(signed char)(wv.y >> 24);
        a2 += x2.x * (float)(signed char)(wv.z) + x2.y * (float)(signed char)(wv.z >> 8)
            + x2.z * (float)(signed char)(wv.z >> 16) + x2.w * (float)(signed char)(wv.z >> 24);
        a3 += x3.x * (float)(signed char)(wv.w) + x3.y * (float)(signed char)(wv.w >> 8)
            + x3.z * (float)(signed char)(wv.w >> 16) + x3.w * (float)(signed char)(wv.w >> 24);
    }
    return (a0 + a1) + (a2 + a3);
}

// ---------------------------------------------------------------- knn v9: 16 queries/block, LDS-staged points
__device__ __forceinline__ unsigned long long shflx_u64(unsigned long long v, int j) {
    int lo = __shfl_xor((int)(unsigned)(v & 0xFFFFFFFFull), j);
    int hi = __shfl_xor((int)(unsigned)(v >> 32), j);
    return ((unsigned long long)(unsigned)hi << 32) | (unsigned)lo;
}

__device__ __forceinline__ unsigned sort64_u32(unsigned v, int lane) {
    #pragma unroll
    for (int k = 2; k <= 64; k <<= 1) {
        #pragma unroll
        for (int j = k >> 1; j > 0; j >>= 1) {
            unsigned o = (unsigned)__shfl_xor((int)v, j);
            bool up = ((lane & k) == 0);
            bool lower = ((lane & j) == 0);
            unsigned mn = v < o ? v : o;
            unsigned mx = v < o ? o : v;
            v = (up == lower) ? mn : mx;
        }
    }
    return v;
}

__device__ __forceinline__ unsigned long long sort64_u64(unsigned long long v, int lane) {
    #pragma unroll
    for (int k = 2; k <= 64; k <<= 1) {
        #pragma unroll
        for (int j = k >> 1; j > 0; j >>= 1) {
            unsigned long long o = shflx_u64(v, j);
            bool up = ((lane & k) == 0);
            bool lower = ((lane & j) == 0);
            unsigned long long mn = v < o ? v : o;
            unsigned long long mx = v < o ? o : v;
            v = (up == lower) ? mn : mx;
        }
    }
    return v;
}

__global__ __launch_bounds__(1024) void knn_kernel(const float* __restrict__ x, int* __restrict__ idxout) {
    __shared__ float xs[2048], ys[2048], zs[2048], ns[2048];
    __shared__ unsigned long long cand[16][64];
    int tid = threadIdx.x;
    int wv = tid >> 6, lane = tid & 63;
    int p = blockIdx.x * 16 + wv;
    int b = p >> 11, n = p & 2047;
    const float* xb = x + (size_t)b * NP * 3;
    for (int t = tid; t < 2048; t += 1024) {
        float mx = xb[t * 3 + 0], my = xb[t * 3 + 1], mz = xb[t * 3 + 2];
        xs[t] = mx; ys[t] = my; zs[t] = mz;
        ns[t] = mx * mx + my * my + mz * mz;
    }
    __syncthreads();
    float cx = xs[n], cy = ys[n], cz = zs[n], xn = ns[n];
    unsigned key[32];
    unsigned lmax = 0u;
    #pragma unroll
    for (int t = 0; t < 32; ++t) {
        int m = (t << 6) | lane;
        float dd = 2.0f * (cx * xs[m] + cy * ys[m] + cz * zs[m]) - xn - ns[m];
        unsigned u = __float_as_uint(dd);
        u = (u & 0x80000000u) ? ~u : (u | 0x80000000u);
        key[t] = u;
        lmax = lmax > u ? lmax : u;
    }
    unsigned sorted = sort64_u32(lmax, lane);
    unsigned S = (unsigned)__shfl((int)sorted, 48);
    int c = 0;
    #pragma unroll
    for (int t = 0; t < 32; ++t) c += (key[t] >= S) ? 1 : 0;
    int inc = c;
    #pragma unroll
    for (int d = 1; d < 64; d <<= 1) {
        int tsh = __shfl_up(inc, d);
        if (lane >= d) inc += tsh;
    }
    int C = __shfl(inc, 63);
    int* op = idxout + (size_t)p * KNN;
    if (C <= 64) {
        int off = inc - c;
        #pragma unroll
        for (int t = 0; t < 32; ++t) {
            if (key[t] >= S) {
                int m = (t << 6) | lane;
                cand[wv][off++] = ((unsigned long long)key[t] << 16) | (unsigned)(2047 - m);
            }
        }
        asm volatile("s_waitcnt lgkmcnt(0)" ::: "memory");
        unsigned long long ck = (lane < C) ? cand[wv][lane] : 0ull;
        ck = sort64_u64(ck, lane);
        if (lane >= 48) op[63 - lane] = 2047 - (int)(unsigned)(ck & 0xFFFFull);
    } else {
        unsigned taken = 0u;
        for (int r = 0; r < KNN; ++r) {
            unsigned long long best = 0ull;
            #pragma unroll
            for (int t = 0; t < 32; ++t) {
                if (!((taken >> t) & 1u)) {
                    int m = (t << 6) | lane;
                    unsigned long long ck = ((unsigned long long)key[t] << 16) | (unsigned)(2047 - m);
                    if (ck > best) best = ck;
                }
            }
            #pragma unroll
            for (int d = 1; d < 64; d <<= 1) {
                unsigned long long o = shflx_u64(best, d);
                if (o > best) best = o;
            }
            int m = 2047 - (int)(unsigned)(best & 0xFFFFull);
            if (lane == 0) op[r] = m;
            if ((m & 63) == lane) taken |= 1u << (m >> 6);
        }
    }
}

// ---------------------------------------------------------------- edge conv + max over k -> hcatT[:,0:64] bf16
__global__ __launch_bounds__(256) void edge_conv_kernel(const float* __restrict__ x, const int* __restrict__ idx,
                                                        const float* __restrict__ Wec, const float* __restrict__ bec,
                                                        unsigned short* __restrict__ hcatT) {
    int tid = threadIdx.x;
    int g = tid >> 6, o = tid & 63;
    int p = blockIdx.x * 4 + g;
    int b = p >> 11;
    __shared__ float nb[4][KNN][3];
    __shared__ float ctr[4][3];
    if (o < KNN) {
        int j = idx[(size_t)p * KNN + o];
        const float* xp = x + ((size_t)b * NP + j) * 3;
        nb[g][o][0] = xp[0]; nb[g][o][1] = xp[1]; nb[g][o][2] = xp[2];
    }
    if (o >= KNN && o < KNN + 3) ctr[g][o - KNN] = x[(size_t)p * 3 + (o - KNN)];
    __syncthreads();
    float w0 = Wec[o * 6 + 0], w1 = Wec[o * 6 + 1], w2 = Wec[o * 6 + 2];
    float w3 = Wec[o * 6 + 3], w4 = Wec[o * 6 + 4], w5 = Wec[o * 6 + 5];
    float c0 = ctr[g][0], c1 = ctr[g][1], c2 = ctr[g][2];
    float base = bec[o] + w3 * c0 + w4 * c1 + w5 * c2;
    float m = -3.4e38f;
    #pragma unroll
    for (int k = 0; k < KNN; ++k) {
        float v = base + w0 * (nb[g][k][0] - c0) + w1 * (nb[g][k][1] - c1) + w2 * (nb[g][k][2] - c2);
        v = v > 0.f ? v : 0.2f * v;
        m = fmaxf(m, v);
    }
    hcatT[(size_t)p * 512 + o] = f2bf(m);
}

// ---------------------------------------------------------------- graph max pool, bf16 [pt][ch] -> bf16 [pt][C]
__global__ __launch_bounds__(256) void pool_bf16_kernel(const unsigned short* __restrict__ src, int s_coff,
                                                        const int* __restrict__ idx,
                                                        unsigned short* __restrict__ dst, int C) {
    int tid = threadIdx.x, wv = tid >> 6, lane = tid & 63;
    int p = blockIdx.x * 4 + wv;
    int b = p >> 11;
    const int* ip = idx + (size_t)p * KNN;
    const unsigned short* sb = src + (size_t)b * NP * 512 + s_coff;
    for (int c0 = 0; c0 < C; c0 += 64) {
        int ch = c0 + lane;
        float m = -3.4e38f;
        #pragma unroll
        for (int k = 0; k < KNN; ++k) {
            int j = ip[k];
            m = fmaxf(m, bf2f(sb[(size_t)j * 512 + ch]));
        }
        dst[(size_t)p * C + ch] = f2bf(m);
    }
}

// ---------------------------------------------------------------- conv1 MFMA: 128pts x 64ch, K=64
__global__ __launch_bounds__(256) void mfma_conv64_kernel(const unsigned short* __restrict__ A,
                                                          const unsigned short* __restrict__ W,
                                                          const float* __restrict__ bias,
                                                          unsigned short* __restrict__ hcatT, int coff) {
    __shared__ unsigned short As[128][72];
    __shared__ unsigned short Bs[64][72];
    int m0 = blockIdx.x * 128, b = blockIdx.z;
    int tid = threadIdx.x;
    int lane = tid & 63, wave = tid >> 6;
    int wr = wave >> 1, wc = wave & 1;
    int quad = lane >> 4, l16 = lane & 15;
    {
        int r = tid >> 1, s = (tid & 1) * 32;
        const unsigned short* ap = A + (size_t)b * NP * 64 + (size_t)(m0 + r) * 64 + s;
        uint4 v0 = *(const uint4*)(ap);
        uint4 v1 = *(const uint4*)(ap + 8);
        uint4 v2 = *(const uint4*)(ap + 16);
        uint4 v3 = *(const uint4*)(ap + 24);
        *(uint4*)&As[r][s] = v0; *(uint4*)&As[r][s + 8] = v1;
        *(uint4*)&As[r][s + 16] = v2; *(uint4*)&As[r][s + 24] = v3;
    }
    {
        int r = tid >> 2, s = (tid & 3) * 16;
        const unsigned short* wp = W + r * 64 + s;
        *(uint4*)&Bs[r][s] = *(const uint4*)wp;
        *(uint4*)&Bs[r][s + 8] = *(const uint4*)(wp + 8);
    }
    __syncthreads();
    f32x4 acc[4][2] = {};
    #pragma unroll
    for (int k0 = 0; k0 < 64; k0 += 32) {
        bf16x8 af[4], bfv[2];
        #pragma unroll
        for (int i = 0; i < 4; ++i) af[i] = *(const bf16x8*)&As[wr * 64 + i * 16 + l16][k0 + quad * 8];
        #pragma unroll
        for (int j = 0; j < 2; ++j) bfv[j] = *(const bf16x8*)&Bs[wc * 32 + j * 16 + l16][k0 + quad * 8];
        #pragma unroll
        for (int i = 0; i < 4; ++i)
            #pragma unroll
            for (int j = 0; j < 2; ++j)
                acc[i][j] = __builtin_amdgcn_mfma_f32_16x16x32_bf16(af[i], bfv[j], acc[i][j], 0, 0, 0);
    }
    #pragma unroll
    for (int i = 0; i < 4; ++i) {
        #pragma unroll
        for (int r = 0; r < 4; ++r) {
            int pt = m0 + wr * 64 + i * 16 + quad * 4 + r;
            #pragma unroll
            for (int j = 0; j < 2; ++j) {
                int ch = wc * 32 + j * 16 + l16;
                float v = acc[i][j][r] + bias[ch];
                v = v > 0.f ? v : 0.2f * v;
                hcatT[((size_t)b * NP + pt) * 512 + coff + ch] = f2bf(v);
            }
        }
    }
}

// ---------------------------------------------------------------- weight/bias cast + xm init (one launch)
__global__ __launch_bounds__(256) void wcast_kernel(const float* __restrict__ Wf, const float* __restrict__ Wc3,
                                                    const float* __restrict__ Wk, const float* __restrict__ Wv,
                                                    const float* __restrict__ bk, const float* __restrict__ bv,
                                                    const float* __restrict__ Wc1, const float* __restrict__ Wc2,
                                                    const float* __restrict__ Wq, const float* __restrict__ Wo,
                                                    const float* __restrict__ Wff1, const float* __restrict__ Wff2,
                                                    unsigned short* __restrict__ WfB, unsigned short* __restrict__ Wc3B,
                                                    unsigned short* __restrict__ WkvB, float* __restrict__ bkv,
                                                    unsigned short* __restrict__ Wc1B, unsigned short* __restrict__ Wc2B,
                                                    unsigned short* __restrict__ WtB, unsigned short* __restrict__ Wff1B,
                                                    unsigned short* __restrict__ Wff2B,
                                                    unsigned* __restrict__ xmk) {
    int id = blockIdx.x * 256 + threadIdx.x;
    if (id < 262144) { WfB[id] = f2bf(Wf[id]); return; }
    int j = id - 262144;
    if (j < 32768) { Wc3B[j] = f2bf(Wc3[j]); return; }
    j -= 32768;
    if (j < 524288) {
        int l = j >> 17, r = j & 131071;
        float v = (r < 65536) ? Wk[(size_t)(l * 2 + 1) * 65536 + r]
                              : Wv[(size_t)(l * 2 + 1) * 65536 + (r - 65536)];
        WkvB[j] = f2bf(v);
        return;
    }
    j -= 524288;
    if (j < 2048) {
        int l = j >> 9, r = j & 511;
        bkv[j] = (r < 256) ? bk[(l * 2 + 1) * 256 + r] : bv[(l * 2 + 1) * 256 + (r - 256)];
        return;
    }
    j -= 2048;
    if (j < 4096) { Wc1B[j] = f2bf(Wc1[j]); return; }
    j -= 4096;
    if (j < 8192) { Wc2B[j] = f2bf(Wc2[j]); return; }
    j -= 8192;
    if (j < 4096) { xmk[j] = 0u; return; }
    j -= 4096;
    if (j < 1572864) {
        int l = j / 393216;
        int r = j - l * 393216;
        int m = r >> 16, c = r & 65535;
        float v;
        if (m == 0)      v = Wq[(size_t)(l * 2 + 0) * 65536 + c];
        else if (m == 1) v = Wk[(size_t)(l * 2 + 0) * 65536 + c];
        else if (m == 2) v = Wv[(size_t)(l * 2 + 0) * 65536 + c];
        else if (m == 3) v = Wo[(size_t)(l * 2 + 0) * 65536 + c];
        else if (m == 4) v = Wq[(size_t)(l * 2 + 1) * 65536 + c];
        else             v = Wo[(size_t)(l * 2 + 1) * 65536 + c];
        WtB[j] = f2bf(v);
        return;
    }
    j -= 1572864;
    if (j < 524288) { Wff1B[j] = f2bf(Wff1[j]); return; }
    j -= 524288;
    if (j < 524288) { Wff2B[j] = f2bf(Wff2[j]); return; }
}

// ---------------------------------------------------------------- int8 per-row quantization of tail weights
// rows: [0,6144) WtB (K=256), [6144,8192) Wff1B (K=256), [8192,9216) Wff2B (K=512)
__global__ __launch_bounds__(256) void wquant_kernel(const unsigned short* __restrict__ WtB,
                                                     const unsigned short* __restrict__ Wff1B,
                                                     const unsigned short* __restrict__ Wff2B,
                                                     char* __restrict__ WtI, float* __restrict__ StW,
                                                     char* __restrict__ FF1I, float* __restrict__ SF1,
                                                     char* __restrict__ FF2I, float* __restrict__ SF2) {
    int tid = threadIdx.x, wv = tid >> 6, lane = tid & 63;
    int row = blockIdx.x * 4 + wv;
    const unsigned short* src;
    char* dst;
    float* sc;
    int K;
    if (row < 6144)      { src = WtB + (size_t)row * 256; dst = WtI + (size_t)row * 256; sc = StW + row; K = 256; }
    else if (row < 8192) { int r = row - 6144; src = Wff1B + (size_t)r * 256; dst = FF1I + (size_t)r * 256; sc = SF1 + r; K = 256; }
    else                 { int r = row - 8192; src = Wff2B + (size_t)r * 512; dst = FF2I + (size_t)r * 512; sc = SF2 + r; K = 512; }
    int per = K >> 6;
    float w[8];
    float mx = 0.f;
    for (int e = 0; e < per; ++e) { w[e] = bf2f(src[lane * per + e]); mx = fmaxf(mx, fabsf(w[e])); }
    #pragma unroll
    for (int off = 1; off < 64; off <<= 1) mx = fmaxf(mx, __shfl_xor(mx, off));
    float s = fmaxf(mx, 1e-30f) * (1.0f / 127.0f);
    float inv = 1.0f / s;
    unsigned pk[2] = {0u, 0u};
    for (int e = 0; e < per; ++e) {
        int q = (int)rintf(w[e] * inv);
        q = q > 127 ? 127 : (q < -127 ? -127 : q);
        pk[e >> 2] |= ((unsigned)(q & 255)) << (8 * (e & 3));
    }
    ((unsigned*)dst)[lane * (per >> 2)] = pk[0];
    if (per == 8) ((unsigned*)dst)[lane * 2 + 1] = pk[1];
    if (lane == 0) *sc = s;
}

// ---------------------------------------------------------------- generic bf16 MFMA GEMM (encoder)
__global__ __launch_bounds__(256) void mfma_gemm_kernel(const unsigned short* __restrict__ A, size_t a_bstride,
                                                        const unsigned short* __restrict__ B, size_t b_bstride,
                                                        const float* __restrict__ bias, int bias_per_m,
                                                        void* __restrict__ C, size_t c_bstride, int c_rstride,
                                                        int K, int act, int out_bf16,
                                                        unsigned* __restrict__ xmk, int domax) {
    __shared__ unsigned short As[128][40];
    __shared__ unsigned short Bs[128][40];
    int m0 = blockIdx.x * 128, n0 = blockIdx.y * 128, b = blockIdx.z;
    int tid = threadIdx.x;
    int lane = tid & 63, wave = tid >> 6;
    int wr = wave >> 1, wc = wave & 1;
    int quad = lane >> 4, l16 = lane & 15;
    int r0 = tid >> 2, kc0 = (tid & 3) * 8;
    f32x4 acc[4][4] = {};
    const unsigned short* Ab = A + (size_t)b * a_bstride;
    const unsigned short* Bb = B + (size_t)b * b_bstride;
    for (int k0 = 0; k0 < K; k0 += 32) {
        uint4 a0 = *(const uint4*)(Ab + (size_t)(m0 + r0) * K + k0 + kc0);
        uint4 a1 = *(const uint4*)(Ab + (size_t)(m0 + r0 + 64) * K + k0 + kc0);
        uint4 b0 = *(const uint4*)(Bb + (size_t)(n0 + r0) * K + k0 + kc0);
        uint4 b1 = *(const uint4*)(Bb + (size_t)(n0 + r0 + 64) * K + k0 + kc0);
        __syncthreads();
        *(uint4*)&As[r0][kc0] = a0;
        *(uint4*)&As[r0 + 64][kc0] = a1;
        *(uint4*)&Bs[r0][kc0] = b0;
        *(uint4*)&Bs[r0 + 64][kc0] = b1;
        __syncthreads();
        bf16x8 af[4], bfv[4];
        #pragma unroll
        for (int i = 0; i < 4; ++i) af[i] = *(const bf16x8*)&As[wr * 64 + i * 16 + l16][quad * 8];
        #pragma unroll
        for (int j = 0; j < 4; ++j) bfv[j] = *(const bf16x8*)&Bs[wc * 64 + j * 16 + l16][quad * 8];
        #pragma unroll
        for (int i = 0; i < 4; ++i)
            #pragma unroll
            for (int j = 0; j < 4; ++j)
                acc[i][j] = __builtin_amdgcn_mfma_f32_16x16x32_bf16(af[i], bfv[j], acc[i][j], 0, 0, 0);
    }
    if (domax) {
        #pragma unroll
        for (int i = 0; i < 4; ++i) {
            #pragma unroll
            for (int r = 0; r < 4; ++r) {
                int m = m0 + wr * 64 + i * 16 + quad * 4 + r;
                float v = fmaxf(fmaxf(acc[i][0][r], acc[i][1][r]), fmaxf(acc[i][2][r], acc[i][3][r]));
                v += bias[m];
                #pragma unroll
                for (int off = 1; off <= 8; off <<= 1) v = fmaxf(v, __shfl_xor(v, off));
                if (l16 == 0) atomicMax(&xmk[(size_t)b * 512 + m], fmono(v));
            }
        }
        return;
    }
    #pragma unroll
    for (int i = 0; i < 4; ++i) {
        #pragma unroll
        for (int r = 0; r < 4; ++r) {
            int m = m0 + wr * 64 + i * 16 + quad * 4 + r;
            float bm = bias_per_m ? bias[m] : 0.f;
            #pragma unroll
            for (int j = 0; j < 4; ++j) {
                int n = n0 + wc * 64 + j * 16 + l16;
                float v = acc[i][j][r] + (bias_per_m ? bm : bias[n]);
                if (act) v = v > 0.f ? v : 0.2f * v;
                size_t off = (size_t)b * c_bstride + (size_t)m * c_rstride + n;
                if (out_bf16) ((unsigned short*)C)[off] = f2bf(v);
                else          ((float*)C)[off] = v;
            }
        }
    }
}

// ---------------------------------------------------------------- KV for ALL layers
__global__ __launch_bounds__(256) void mfma_kv_all_kernel(const unsigned short* __restrict__ A,
                                                          const unsigned short* __restrict__ W,
                                                          const float* __restrict__ bkv,
                                                          unsigned short* __restrict__ KVall) {
    __shared__ unsigned short As[128][40];
    __shared__ unsigned short Bs[128][40];
    int m0 = blockIdx.x * 128;
    int nb = blockIdx.y & 3, l = blockIdx.y >> 2;
    int n0 = nb * 128;
    int b = blockIdx.z;
    int tid = threadIdx.x;
    int lane = tid & 63, wave = tid >> 6;
    int wr = wave >> 1, wc = wave & 1;
    int quad = lane >> 4, l16 = lane & 15;
    int r0 = tid >> 2, kc0 = (tid & 3) * 8;
    f32x4 acc[4][4] = {};
    const unsigned short* Ab = A + (size_t)b * NP * 256;
    const unsigned short* Bb = W + (size_t)l * 131072;
    const float* bias = bkv + l * 512;
    for (int k0 = 0; k0 < 256; k0 += 32) {
        uint4 a0 = *(const uint4*)(Ab + (size_t)(m0 + r0) * 256 + k0 + kc0);
        uint4 a1 = *(const uint4*)(Ab + (size_t)(m0 + r0 + 64) * 256 + k0 + kc0);
        uint4 b0 = *(const uint4*)(Bb + (size_t)(n0 + r0) * 256 + k0 + kc0);
        uint4 b1 = *(const uint4*)(Bb + (size_t)(n0 + r0 + 64) * 256 + k0 + kc0);
        __syncthreads();
        *(uint4*)&As[r0][kc0] = a0;
        *(uint4*)&As[r0 + 64][kc0] = a1;
        *(uint4*)&Bs[r0][kc0] = b0;
        *(uint4*)&Bs[r0 + 64][kc0] = b1;
        __syncthreads();
        bf16x8 af[4], bfv[4];
        #pragma unroll
        for (int i = 0; i < 4; ++i) af[i] = *(const bf16x8*)&As[wr * 64 + i * 16 + l16][quad * 8];
        #pragma unroll
        for (int j = 0; j < 4; ++j) bfv[j] = *(const bf16x8*)&Bs[wc * 64 + j * 16 + l16][quad * 8];
        #pragma unroll
        for (int i = 0; i < 4; ++i)
            #pragma unroll
            for (int j = 0; j < 4; ++j)
                acc[i][j] = __builtin_amdgcn_mfma_f32_16x16x32_bf16(af[i], bfv[j], acc[i][j], 0, 0, 0);
    }
    unsigned short* Cb = KVall + ((size_t)l * BN + b) * NP * 512;
    #pragma unroll
    for (int i = 0; i < 4; ++i) {
        #pragma unroll
        for (int r = 0; r < 4; ++r) {
            int m = m0 + wr * 64 + i * 16 + quad * 4 + r;
            #pragma unroll
            for (int j = 0; j < 4; ++j) {
                int n = n0 + wc * 64 + j * 16 + l16;
                Cb[(size_t)m * 512 + n] = f2bf(acc[i][j][r] + bias[n]);
            }
        }
    }
}

// ---------------------------------------------------------------- q0 row + fold layer-0 QKV projection (int8)
__global__ __launch_bounds__(256) void pc_kernel(const unsigned* __restrict__ xmk, const float* __restrict__ Wpc,
                                                 const float* __restrict__ bpc,
                                                 const char* __restrict__ WqkvI, const float* __restrict__ sQ,
                                                 const float* __restrict__ bq0, const float* __restrict__ bk0,
                                                 const float* __restrict__ bv0,
                                                 float* __restrict__ q, float* __restrict__ Qs,
                                                 float* __restrict__ Ks, float* __restrict__ Vs) {
    int row = blockIdx.x, tid = threadIdx.x;
    int id = row * 256 + tid;
    int b = row >> 3, i = row & 7;
    const unsigned* xr = xmk + b * 512 + i * 64;
    const float* w = Wpc + (size_t)tid * 64;
    float acc = bpc[tid];
    #pragma unroll
    for (int e = 0; e < 64; ++e) acc += funmono(xr[e]) * w[e];
    float qv = acc > 0.f ? acc : 0.2f * acc;
    q[id] = qv;
    __shared__ __align__(16) float a[256];
    a[tid] = qv;
    __syncthreads();
    Qs[id] = bq0[tid] + sQ[tid] * gemv_i8(WqkvI + (size_t)tid * 256, a, 16);
    Ks[id] = bk0[tid] + sQ[256 + tid] * gemv_i8(WqkvI + 65536 + (size_t)tid * 256, a, 16);
    Vs[id] = bv0[tid] + sQ[512 + tid] * gemv_i8(WqkvI + 131072 + (size_t)tid * 256, a, 16);
}

// ---------------------------------------------------------------- memB = bf16(act(x @ Wpi.T + bpi))
__global__ __launch_bounds__(256) void mem_kernel(const float* __restrict__ x, const float* __restrict__ Wpi,
                                                  const float* __restrict__ bpi, unsigned short* __restrict__ memB) {
    size_t id = (size_t)blockIdx.x * 256 + threadIdx.x;
    int p = (int)(id & 255);
    size_t pt = id >> 8;
    float x0 = x[pt * 3 + 0], x1 = x[pt * 3 + 1], x2 = x[pt * 3 + 2];
    float v = bpi[p] + x0 * Wpi[p * 3 + 0] + x1 * Wpi[p * 3 + 1] + x2 * Wpi[p * 3 + 2];
    v = v > 0.f ? v : 0.2f * v;
    memB[id] = f2bf(v);
}

// ---------------------------------------------------------------- self-attn + O-proj + res + LN + cross-Q-proj (1024 thr, int8)
__global__ __launch_bounds__(1024) void attn_ln_kernel(const float* __restrict__ Qs, const float* __restrict__ Ks,
                                                       const float* __restrict__ Vs,
                                                       const char* __restrict__ WoI, const float* __restrict__ sWo,
                                                       const float* __restrict__ bo, const float* __restrict__ res,
                                                       const float* __restrict__ g, const float* __restrict__ bt,
                                                       const char* __restrict__ Wq1I, const float* __restrict__ sWq1,
                                                       const float* __restrict__ bq1,
                                                       float* __restrict__ out, float* __restrict__ Qc) {
    int row = blockIdx.x, tid = threadIdx.x;
    int b = row >> 3;
    __shared__ float Kl[2048], Vl[2048];
    __shared__ __align__(16) float qr[256];
    __shared__ float sc[64];
    __shared__ __align__(16) float r[256];
    __shared__ __align__(16) float aout[256];
    __shared__ float red[1024];
    for (int t = tid; t < 2048; t += 1024) {
        Kl[t] = Ks[(size_t)b * 2048 + t];
        Vl[t] = Vs[(size_t)b * 2048 + t];
    }
    if (tid < 256) qr[tid] = Qs[(size_t)row * 256 + tid];
    __syncthreads();
    const float scale = 0.17677669529663687f;
    {
        int pair = tid >> 4, part = tid & 15;
        int h = pair >> 3, k = pair & 7;
        int d = part * 2;
        float dot = qr[h * 32 + d] * Kl[k * 256 + h * 32 + d]
                  + qr[h * 32 + d + 1] * Kl[k * 256 + h * 32 + d + 1];
        dot += __shfl_xor(dot, 1);
        dot += __shfl_xor(dot, 2);
        dot += __shfl_xor(dot, 4);
        dot += __shfl_xor(dot, 8);
        if (part == 0) sc[pair] = dot * scale;
    }
    __syncthreads();
    if (tid < 64) {
        float v = sc[tid];
        float m = v;
        #pragma unroll
        for (int off = 1; off < 8; off <<= 1) m = fmaxf(m, __shfl_xor(m, off));
        float e = __expf(v - m);
        float s = e;
        #pragma unroll
        for (int off = 1; off < 8; off <<= 1) s += __shfl_xor(s, off);
        sc[tid] = e / s;
    }
    __syncthreads();
    if (tid < 256) {
        int h = tid >> 5;
        float acc = 0.f;
        #pragma unroll
        for (int k = 0; k < 8; ++k) acc += sc[h * 8 + k] * Vl[k * 256 + tid];
        r[tid] = acc;
    }
    __syncthreads();
    int o4 = tid >> 2, p4 = tid & 3;
    float v;
    {
        float acc = gemv_i8(WoI + (size_t)o4 * 256 + p4 * 64, r + p4 * 64, 4);
        acc += __shfl_xor(acc, 1);
        acc += __shfl_xor(acc, 2);
        v = (p4 == 0) ? (bo[o4] + sWo[o4] * acc + res[(size_t)row * 256 + o4]) : 0.f;
    }
    red[tid] = v; __syncthreads();
    for (int s = 512; s; s >>= 1) { if (tid < s) red[tid] += red[tid + s]; __syncthreads(); }
    float mean = red[0] * (1.0f / 256.0f);
    __syncthreads();
    float dv = (p4 == 0) ? v - mean : 0.f;
    red[tid] = dv * dv; __syncthreads();
    for (int s = 512; s; s >>= 1) { if (tid < s) red[tid] += red[tid + s]; __syncthreads(); }
    float var = red[0] * (1.0f / 256.0f);
    if (p4 == 0) {
        float oln = g[o4] * dv * rsqrtf(var + 1e-5f) + bt[o4];
        out[(size_t)row * 256 + o4] = oln;
        aout[o4] = oln;
    }
    __syncthreads();
    {
        float qacc = gemv_i8(Wq1I + (size_t)o4 * 256 + p4 * 64, aout + p4 * 64, 4);
        qacc += __shfl_xor(qacc, 1);
        qacc += __shfl_xor(qacc, 2);
        if (p4 == 0) Qc[(size_t)row * 256 + o4] = bq1[o4] + sWq1[o4] * qacc;
    }
}

// ---------------------------------------------------------------- cross-attn pass 1: 16 key-blocks of 128
__global__ __launch_bounds__(256) void ca_part_kernel(const float* __restrict__ Qc,
                                                      const unsigned short* __restrict__ KVl,
                                                      float* __restrict__ part) {
    int kb = blockIdx.x, h = blockIdx.y, b = blockIdx.z;
    int tid = threadIdx.x;
    __shared__ float q[8][32];
    __shared__ __align__(16) float S[8][128];
    __shared__ float om[8][8][32];
    const float scale = 0.17677669529663687f;
    {
        int i = tid >> 5, d = tid & 31;
        q[i][d] = Qc[(size_t)(b * 8 + i) * 256 + h * 32 + d];
    }
    __syncthreads();
    {
        int kk = tid & 127, half = tid >> 7;
        int k = kb * 128 + kk;
        const unsigned short* kp = KVl + ((size_t)b * NP + k) * 512 + h * 32;
        float kd[32];
        #pragma unroll
        for (int u = 0; u < 4; ++u) {
            uint4 raw = *(const uint4*)(kp + u * 8);
            unsigned w0 = raw.x, w1 = raw.y, w2 = raw.z, w3 = raw.w;
            kd[u * 8 + 0] = __uint_as_float(w0 << 16); kd[u * 8 + 1] = __uint_as_float(w0 & 0xFFFF0000u);
            kd[u * 8 + 2] = __uint_as_float(w1 << 16); kd[u * 8 + 3] = __uint_as_float(w1 & 0xFFFF0000u);
            kd[u * 8 + 4] = __uint_as_float(w2 << 16); kd[u * 8 + 5] = __uint_as_float(w2 & 0xFFFF0000u);
            kd[u * 8 + 6] = __uint_as_float(w3 << 16); kd[u * 8 + 7] = __uint_as_float(w3 & 0xFFFF0000u);
        }
        #pragma unroll
        for (int i = 0; i < 4; ++i) {
            int ri = half * 4 + i;
            float dot = 0.f;
            #pragma unroll
            for (int d = 0; d < 32; ++d) dot += q[ri][d] * kd[d];
            S[ri][kk] = dot * scale;
        }
    }
    __syncthreads();
    float* pout = part + (((size_t)(b * NH + h)) * 16 + kb) * 288;
    {
        int i = tid >> 5, l32 = tid & 31;
        float m = -3.4e38f;
        #pragma unroll
        for (int t = 0; t < 4; ++t) m = fmaxf(m, S[i][l32 + t * 32]);
        #pragma unroll
        for (int off = 16; off; off >>= 1) m = fmaxf(m, __shfl_xor(m, off));
        float s = 0.f;
        #pragma unroll
        for (int t = 0; t < 4; ++t) {
            float e = __expf(S[i][l32 + t * 32] - m);
            S[i][l32 + t * 32] = e;
            s += e;
        }
        #pragma unroll
        for (int off = 16; off; off >>= 1) s += __shfl_xor(s, off);
        if (l32 == 0) { pout[i] = m; pout[8 + i] = s; }
    }
    __syncthreads();
    {
        int d = tid & 31, grp = tid >> 5;
        const unsigned short* Vb = KVl + ((size_t)b * NP + kb * 128) * 512 + 256 + h * 32 + d;
        float acc[8] = {};
        #pragma unroll 4
        for (int t = 0; t < 16; ++t) {
            int kk = grp * 16 + t;
            float v = bf2f(Vb[(size_t)kk * 512]);
            #pragma unroll
            for (int i = 0; i < 8; ++i) acc[i] += S[i][kk] * v;
        }
        #pragma unroll
        for (int i = 0; i < 8; ++i) om[grp][i][d] = acc[i];
    }
    __syncthreads();
    {
        int i = tid >> 5, d = tid & 31;
        float sum = 0.f;
        #pragma unroll
        for (int g = 0; g < 8; ++g) sum += om[g][i][d];
        pout[16 + i * 32 + d] = sum;
    }
}

// ---------------------------------------------------------------- combine + O-proj + LN + FF + LN [+ next-layer QKV | final LN+Wcm]
// int8 per-row-scaled weights (1024 thr)
__global__ __launch_bounds__(1024) void combine_ff_kernel(const float* __restrict__ part,
                                                          const char* __restrict__ WoI, const float* __restrict__ sWo,
                                                          const float* __restrict__ bo, const float* __restrict__ res,
                                                          const float* __restrict__ g2, const float* __restrict__ b2t,
                                                          const char* __restrict__ W1I, const float* __restrict__ sW1,
                                                          const float* __restrict__ b1,
                                                          const char* __restrict__ W2I, const float* __restrict__ sW2,
                                                          const float* __restrict__ b2,
                                                          const float* __restrict__ g3, const float* __restrict__ b3t,
                                                          float* __restrict__ out,
                                                          int is_last, const float* __restrict__ lnfg,
                                                          const float* __restrict__ lnfb, const float* __restrict__ Wcm,
                                                          const float* __restrict__ bcm, float* __restrict__ finout,
                                                          const char* __restrict__ WqkvnI, const float* __restrict__ sQn,
                                                          const float* __restrict__ bqn, const float* __restrict__ bkn,
                                                          const float* __restrict__ bvn,
                                                          float* __restrict__ Qs, float* __restrict__ Ks,
                                                          float* __restrict__ Vs) {
    int row = blockIdx.x, tid = threadIdx.x;
    int b = row >> 3, i = row & 7;
    __shared__ __align__(16) float r[256];
    __shared__ __align__(16) float a[256];
    __shared__ __align__(16) float hbuf[512];
    __shared__ float red[1024];
    // phase 1: combine cross-attn partials (4 threads per (h,d), each 4 key-blocks)
    {
        int h = tid >> 7, rem = tid & 127, d = rem >> 2, g = rem & 3;
        const float* pb = part + (size_t)(b * NH + h) * 16 * 288;
        float M = -3.4e38f;
        #pragma unroll
        for (int t = 0; t < 4; ++t) M = fmaxf(M, pb[(g * 4 + t) * 288 + i]);
        M = fmaxf(M, __shfl_xor(M, 1));
        M = fmaxf(M, __shfl_xor(M, 2));
        float L = 0.f, O = 0.f;
        #pragma unroll
        for (int t = 0; t < 4; ++t) {
            int kb = g * 4 + t;
            float w = __expf(pb[kb * 288 + i] - M);
            L += pb[kb * 288 + 8 + i] * w;
            O += pb[kb * 288 + 16 + i * 32 + d] * w;
        }
        L += __shfl_xor(L, 1); L += __shfl_xor(L, 2);
        O += __shfl_xor(O, 1); O += __shfl_xor(O, 2);
        if (g == 0) r[h * 32 + d] = O / L;
    }
    __syncthreads();
    int o4 = tid >> 2, p4 = tid & 3;
    // phase 2: O-proj (4 thr/out, int8) + residual + LN
    float v;
    {
        float acc = gemv_i8(WoI + (size_t)o4 * 256 + p4 * 64, r + p4 * 64, 4);
        acc += __shfl_xor(acc, 1);
        acc += __shfl_xor(acc, 2);
        v = (p4 == 0) ? (bo[o4] + sWo[o4] * acc + res[(size_t)row * 256 + o4]) : 0.f;
    }
    red[tid] = v; __syncthreads();
    for (int s = 512; s; s >>= 1) { if (tid < s) red[tid] += red[tid + s]; __syncthreads(); }
    float mean = red[0] * (1.0f / 256.0f);
    __syncthreads();
    float dv = (p4 == 0) ? v - mean : 0.f;
    red[tid] = dv * dv; __syncthreads();
    for (int s = 512; s; s >>= 1) { if (tid < s) red[tid] += red[tid + s]; __syncthreads(); }
    float var = red[0] * (1.0f / 256.0f);
    if (p4 == 0) a[o4] = g2[o4] * dv * rsqrtf(var + 1e-5f) + b2t[o4];
    __syncthreads();
    // phase 3: FF1 (2 thr/out, int8, 128-elem partials)
    {
        int o = tid >> 1, p = tid & 1;
        float acc = gemv_i8(W1I + (size_t)o * 256 + p * 128, a + p * 128, 8);
        acc += __shfl_xor(acc, 1);
        if (p == 0) { float t = b1[o] + sW1[o] * acc; hbuf[o] = t > 0.f ? t : 0.2f * t; }
    }
    __syncthreads();
    // phase 4: FF2 (4 thr/out, int8, K=512) + residual + LN
    float vF;
    {
        float acc = gemv_i8(W2I + (size_t)o4 * 512 + p4 * 128, hbuf + p4 * 128, 8);
        acc += __shfl_xor(acc, 1);
        acc += __shfl_xor(acc, 2);
        vF = (p4 == 0) ? (b2[o4] + sW2[o4] * acc + a[o4]) : 0.f;
    }
    red[tid] = vF; __syncthreads();
    for (int s = 512; s; s >>= 1) { if (tid < s) red[tid] += red[tid + s]; __syncthreads(); }
    float mean2 = red[0] * (1.0f / 256.0f);
    __syncthreads();
    float dv2 = (p4 == 0) ? vF - mean2 : 0.f;
    red[tid] = dv2 * dv2; __syncthreads();
    for (int s = 512; s; s >>= 1) { if (tid < s) red[tid] += red[tid + s]; __syncthreads(); }
    float var2 = red[0] * (1.0f / 256.0f);
    float tln = 0.f;
    if (p4 == 0) {
        tln = g3[o4] * dv2 * rsqrtf(var2 + 1e-5f) + b3t[o4];
        r[o4] = tln;
    }
    __syncthreads();
    if (!is_last) {
        if (p4 == 0) out[(size_t)row * 256 + o4] = tln;
        // next-layer QKV from tln row in r[]: 768 full-dot threads (int8)
        if (tid < 768) {
            int which = tid >> 8, o = tid & 255;
            float acc = gemv_i8(WqkvnI + (size_t)which * 65536 + (size_t)o * 256, r, 16);
            float bb = (which == 0) ? bqn[o] : (which == 1) ? bkn[o] : bvn[o];
            float* dst = (which == 0) ? Qs : (which == 1) ? Ks : Vs;
            dst[(size_t)row * 256 + o] = bb + sQn[which * 256 + o] * acc;
        }
        return;
    }
    // final LN + Wcm
    float tf = (tid < 256) ? r[tid] : 0.f;
    red[tid] = tf; __syncthreads();
    for (int s = 512; s; s >>= 1) { if (tid < s) red[tid] += red[tid + s]; __syncthreads(); }
    float mean3 = red[0] * (1.0f / 256.0f);
    __syncthreads();
    float d3 = (tid < 256) ? tf - mean3 : 0.f;
    red[tid] = d3 * d3; __syncthreads();
    for (int s = 512; s; s >>= 1) { if (tid < s) red[tid] += red[tid + s]; __syncthreads(); }
    float var3 = red[0] * (1.0f / 256.0f);
    if (tid < 256) a[tid] = lnfg[tid] * d3 * rsqrtf(var3 + 1e-5f) + lnfb[tid];
    __syncthreads();
    if (tid < 64) {
        const float4* w4 = (const float4*)(Wcm + (size_t)tid * 256);
        const float4* a4 = (const float4*)a;
        float acc = bcm[tid];
        #pragma unroll 8
        for (int c = 0; c < 64; ++c) {
            float4 av = a4[c], wv = w4[c];
            acc += av.x * wv.x + av.y * wv.y + av.z * wv.z + av.w * wv.w;
        }
        finout[(size_t)b * 512 + i * 64 + tid] = acc;
    }
}

// ================================================================ host
extern "C" void kernel_launch(void* const* d_in, const int* in_sizes, int n_in,
                              void* d_out, int out_size, void* d_ws, size_t ws_size,
                              hipStream_t stream) {
    const float* x    = (const float*)d_in[0];
    const float* Wec  = (const float*)d_in[1];
    const float* bec  = (const float*)d_in[2];
    const float* Wc1  = (const float*)d_in[3];
    const float* bc1  = (const float*)d_in[4];
    const float* Wc2  = (const float*)d_in[5];
    const float* bc2  = (const float*)d_in[6];
    const float* Wc3  = (const float*)d_in[7];
    const float* bc3  = (const float*)d_in[8];
    const float* Wf   = (const float*)d_in[9];
    const float* bf   = (const float*)d_in[10];
    const float* Wpc  = (const float*)d_in[11];
    const float* bpc  = (const float*)d_in[12];
    const float* Wpi  = (const float*)d_in[13];
    const float* bpi  = (const float*)d_in[14];
    const float* Wq   = (const float*)d_in[15];
    const float* bq   = (const float*)d_in[16];
    const float* Wk   = (const float*)d_in[17];
    const float* bk   = (const float*)d_in[18];
    const float* Wv   = (const float*)d_in[19];
    const float* bv   = (const float*)d_in[20];
    const float* Wo   = (const float*)d_in[21];
    const float* bo   = (const float*)d_in[22];
    const float* ln1g = (const float*)d_in[23];
    const float* ln1b = (const float*)d_in[24];
    const float* ln2g = (const float*)d_in[25];
    const float* ln2b = (const float*)d_in[26];
    const float* Wff1 = (const float*)d_in[27];
    const float* bff1 = (const float*)d_in[28];
    const float* Wff2 = (const float*)d_in[29];
    const float* bff2 = (const float*)d_in[30];
    const float* ln3g = (const float*)d_in[31];
    const float* ln3b = (const float*)d_in[32];
    const float* lnfg = (const float*)d_in[33];
    const float* lnfb = (const float*)d_in[34];
    const float* Wcm  = (const float*)d_in[35];
    const float* bcm  = (const float*)d_in[36];
    float* out = (float*)d_out;

    float* ws = (float*)d_ws;
    size_t off = 0;
    auto alloc = [&](size_t n) { float* p = ws + off; off += (n + 3) & ~(size_t)3; return p; };
    int*            idx   = (int*)alloc((size_t)BN * NP * KNN);
    unsigned short* hcatT = (unsigned short*)alloc((size_t)BN * NP * 512 / 2);
    unsigned short* poolT = (unsigned short*)alloc((size_t)BN * NP * 128 / 2);
    unsigned short* WfB   = (unsigned short*)alloc(262144 / 2);
    unsigned short* Wc1B  = (unsigned short*)alloc(4096 / 2);
    unsigned short* Wc2B  = (unsigned short*)alloc(8192 / 2);
    unsigned short* Wc3B  = (unsigned short*)alloc(32768 / 2);
    unsigned short* WkvB  = (unsigned short*)alloc(524288 / 2);
    float*          bkv   = alloc(2048);
    unsigned short* memB  = (unsigned short*)alloc((size_t)BN * NP * 256 / 2);
    unsigned short* KVall = (unsigned short*)alloc((size_t)NL * BN * NP * 512 / 2);
    unsigned*       xmk   = (unsigned*)alloc((size_t)BN * 512);
    unsigned short* WtB   = (unsigned short*)alloc(1572864 / 2);
    unsigned short* Wff1B = (unsigned short*)alloc(524288 / 2);
    unsigned short* Wff2B = (unsigned short*)alloc(524288 / 2);
    char*           WtI   = (char*)alloc(1572864 / 4);
    float*          StW   = alloc(6144);
    char*           FF1I  = (char*)alloc(524288 / 4);
    float*          SF1   = alloc(2048);
    char*           FF2I  = (char*)alloc(524288 / 4);
    float*          SF2   = alloc(1024);
    float*          qa    = alloc((size_t)BN * 8 * 256);
    float*          qb    = alloc((size_t)BN * 8 * 256);
    float*          Qs    = alloc((size_t)BN * 8 * 256);
    float*          Ks    = alloc((size_t)BN * 8 * 256);
    float*          Vs    = alloc((size_t)BN * 8 * 256);
    float*          Qc    = alloc((size_t)BN * 8 * 256);
    float*          part  = alloc((size_t)BN * NH * 16 * 288);

    // ---- weight casts + xm-key init, then int8 row-quant of tail weights ----
    wcast_kernel<<<13512, 256, 0, stream>>>(Wf, Wc3, Wk, Wv, bk, bv, Wc1, Wc2, Wq, Wo, Wff1, Wff2,
                                            WfB, Wc3B, WkvB, bkv, Wc1B, Wc2B, WtB, Wff1B, Wff2B, xmk);
    wquant_kernel<<<2304, 256, 0, stream>>>(WtB, Wff1B, Wff2B, WtI, StW, FF1I, SF1, FF2I, SF2);

    // ---- point-cloud encoder (all-bf16 [pt][ch] chain) ----
    knn_kernel<<<BN * NP / 16, 1024, 0, stream>>>(x, idx);
    edge_conv_kernel<<<BN * NP / 4, 256, 0, stream>>>(x, idx, Wec, bec, hcatT);

    pool_bf16_kernel<<<BN * NP / 4, 256, 0, stream>>>(hcatT, 0, idx, poolT, 64);
    mfma_conv64_kernel<<<dim3(NP / 128, 1, BN), 256, 0, stream>>>(poolT, Wc1B, bc1, hcatT, 64);
    pool_bf16_kernel<<<BN * NP / 4, 256, 0, stream>>>(hcatT, 64, idx, poolT, 64);
    mfma_gemm_kernel<<<dim3(NP / 128, 1, BN), 256, 0, stream>>>(poolT, (size_t)NP * 64, Wc2B, 0,
                                                                bc2, 0, (void*)(hcatT + 128), (size_t)NP * 512, 512,
                                                                64, 1, 1, nullptr, 0);
    pool_bf16_kernel<<<BN * NP / 4, 256, 0, stream>>>(hcatT, 128, idx, poolT, 128);
    mfma_gemm_kernel<<<dim3(NP / 128, 2, BN), 256, 0, stream>>>(poolT, (size_t)NP * 128, Wc3B, 0,
                                                                bc3, 0, (void*)(hcatT + 256), (size_t)NP * 512, 512,
                                                                128, 1, 1, nullptr, 0);
    mfma_gemm_kernel<<<dim3(4, NP / 128, BN), 256, 0, stream>>>(WfB, 0, hcatT, (size_t)NP * 512,
                                                                bf, 1, nullptr, 0, 0,
                                                                512, 0, 0, xmk, 1);
    pc_kernel<<<BN * 8, 256, 0, stream>>>(xmk, Wpc, bpc, WtI, StW, bq, bk, bv, qa, Qs, Ks, Vs);
    mem_kernel<<<BN * NP, 256, 0, stream>>>(x, Wpi, bpi, memB);
    mfma_kv_all_kernel<<<dim3(NP / 128, 4 * NL, BN), 256, 0, stream>>>(memB, WkvB, bkv, KVall);

    // ---- transformer layers (3 launches/layer; QKV folded into producer) ----
    for (int l = 0; l < NL; ++l) {
        const float* bo0 = bo + (l * 2 + 0) * 256;
        const float* bq1 = bq + (l * 2 + 1) * 256;
        const float* bo1 = bo + (l * 2 + 1) * 256;
        int last = (l == NL - 1);

        attn_ln_kernel<<<BN * 8, 1024, 0, stream>>>(Qs, Ks, Vs,
                                                    WtI + (size_t)l * 393216 + 3 * 65536, StW + l * 1536 + 3 * 256,
                                                    bo0, qa,
                                                    ln1g + l * 256, ln1b + l * 256,
                                                    WtI + (size_t)l * 393216 + 4 * 65536, StW + l * 1536 + 4 * 256,
                                                    bq1, qb, Qc);
        ca_part_kernel<<<dim3(16, NH, BN), 256, 0, stream>>>(Qc, KVall + (size_t)l * BN * NP * 512, part);
        combine_ff_kernel<<<BN * 8, 1024, 0, stream>>>(part,
                                                       WtI + (size_t)l * 393216 + 5 * 65536, StW + l * 1536 + 5 * 256,
                                                       bo1, qb,
                                                       ln2g + l * 256, ln2b + l * 256,
                                                       FF1I + (size_t)l * 131072, SF1 + l * 512, bff1 + l * 512,
                                                       FF2I + (size_t)l * 131072, SF2 + l * 256, bff2 + l * 256,
                                                       ln3g + l * 256, ln3b + l * 256, qa,
                                                       last, lnfg, lnfb, Wcm, bcm, out,
                                                       last ? nullptr : WtI + (size_t)(l + 1) * 393216,
                                                       last ? nullptr : StW + (l + 1) * 1536,
                                                       bq + ((l + 1) * 2) * 256, bk + ((l + 1) * 2) * 256,
                                                       bv + ((l + 1) * 2) * 256,
                                                       Qs, Ks, Vs);
    }

    (void)in_sizes; (void)n_in; (void)out_size; (void)ws_size;
}